// Round 1
// 803.481 us; speedup vs baseline: 1.7938x; 1.7938x over previous
//
#include <hip/hip_runtime.h>

// Problem constants
#define Hh    8
#define DMm   512
#define HDd   64
#define CBc   32
#define SBs   64
#define WINSZ 512
#define TOPKk 16
#define NEGF  (-1e30f)
#define Bb    2
#define Ss    4096
#define NCc   128   // S/CB
#define NSs   64    // S/SB
#define SCALE 0.125f

// Workspace layout (float offsets) — fp32 intermediates + f16 attention operands
#define OFF_Q    ((size_t)0)
#define OFF_K    ((size_t)4194304)
#define OFF_V    ((size_t)8388608)
#define OFF_O    ((size_t)12582912)
#define OFF_G    ((size_t)16777216)   // B*S*3 = 24576
#define OFF_KC   ((size_t)16801792)   // 131072
#define OFF_VC   ((size_t)16932864)   // 131072
#define OFF_IMPB ((size_t)17063936)   // B*H*NS*NS = 65536
#define OFF_SEL  ((size_t)17129472)   // B*H*NS*TOPK ints = 16384
#define OFF_QH   ((size_t)17145856)   // f16 q  [bh][s][d]  : 4194304 halves = 2097152 floats
#define OFF_KH   ((size_t)19243008)   // f16 k  [bh][s][d]
#define OFF_VT   ((size_t)21340160)   // f16 v^T [bh][d][s]
#define WS_FLOATS ((size_t)23437312)

typedef _Float16 f16;
typedef _Float16 f16x4 __attribute__((ext_vector_type(4)));
typedef _Float16 f16x8 __attribute__((ext_vector_type(8)));
typedef float    f32x4 __attribute__((ext_vector_type(4)));

__device__ __forceinline__ int swz(int row, int byteoff) {
    return byteoff ^ ((row & 7) << 4);   // spreads stride-128B rows across banks
}

// -------------------- K1: q/k/v projections (tiled 64x64 fp32 GEMM) -----------
__global__ __launch_bounds__(256) void k_proj(const float* __restrict__ x,
        const float* __restrict__ Wq, const float* __restrict__ Wk,
        const float* __restrict__ Wv, float* __restrict__ ws)
{
    const int zone = blockIdx.z;  // 0=q 1=k 2=v
    const float* W = (zone == 0) ? Wq : ((zone == 1) ? Wk : Wv);
    float* dst = ws + (size_t)zone * 4194304;
    const int m0 = blockIdx.x * 64;
    const int n0 = blockIdx.y * 64;
    __shared__ float As[16][68];  // [k][m]
    __shared__ float Bs[16][68];  // [k][n]
    const int tid = threadIdx.x;
    const int tx = tid & 15, ty = tid >> 4;
    float acc[4][4] = {};
    for (int k0 = 0; k0 < DMm; k0 += 16) {
        {
            int r = tid >> 2;
            int kq = (tid & 3) * 4;
            float4 t4 = *(const float4*)(x + (size_t)(m0 + r) * DMm + k0 + kq);
            As[kq + 0][r] = t4.x;
            As[kq + 1][r] = t4.y;
            As[kq + 2][r] = t4.z;
            As[kq + 3][r] = t4.w;
        }
        {
            int kk = tid >> 4;
            int nq = (tid & 15) * 4;
            float4 t4 = *(const float4*)(W + (size_t)(k0 + kk) * DMm + n0 + nq);
            Bs[kk][nq + 0] = t4.x;
            Bs[kk][nq + 1] = t4.y;
            Bs[kk][nq + 2] = t4.z;
            Bs[kk][nq + 3] = t4.w;
        }
        __syncthreads();
#pragma unroll
        for (int kk = 0; kk < 16; ++kk) {
            float4 av = *(const float4*)&As[kk][ty * 4];
            float4 bv = *(const float4*)&Bs[kk][tx * 4];
            acc[0][0] += av.x * bv.x; acc[0][1] += av.x * bv.y; acc[0][2] += av.x * bv.z; acc[0][3] += av.x * bv.w;
            acc[1][0] += av.y * bv.x; acc[1][1] += av.y * bv.y; acc[1][2] += av.y * bv.z; acc[1][3] += av.y * bv.w;
            acc[2][0] += av.z * bv.x; acc[2][1] += av.z * bv.y; acc[2][2] += av.z * bv.z; acc[2][3] += av.z * bv.w;
            acc[3][0] += av.w * bv.x; acc[3][1] += av.w * bv.y; acc[3][2] += av.w * bv.z; acc[3][3] += av.w * bv.w;
        }
        __syncthreads();
    }
    const int h = n0 >> 6;
#pragma unroll
    for (int i = 0; i < 4; ++i) {
        int m = m0 + ty * 4 + i;
        int b = m >> 12;
        int s = m & 4095;
#pragma unroll
        for (int j = 0; j < 4; ++j) {
            int d = tx * 4 + j;
            dst[(((size_t)(b * Hh + h)) * Ss + s) * HDd + d] = acc[i][j];
        }
    }
}

// -------------------- K2: gate = sigmoid(x @ Wg) ------------------------------
__global__ __launch_bounds__(256) void k_gate(const float* __restrict__ x,
        const float* __restrict__ Wg, float* __restrict__ g)
{
    int row = blockIdx.x * 256 + threadIdx.x;   // 0 .. 8191
    if (row >= Bb * Ss) return;
    const float* xr = x + (size_t)row * DMm;
    float a0 = 0.f, a1 = 0.f, a2 = 0.f;
    for (int d = 0; d < DMm; ++d) {
        float xv = xr[d];
        a0 += xv * Wg[d * 3 + 0];
        a1 += xv * Wg[d * 3 + 1];
        a2 += xv * Wg[d * 3 + 2];
    }
    g[(size_t)row * 3 + 0] = 1.f / (1.f + expf(-a0));
    g[(size_t)row * 3 + 1] = 1.f / (1.f + expf(-a1));
    g[(size_t)row * 3 + 2] = 1.f / (1.f + expf(-a2));
}

// -------------------- K2b: fp32 q,k -> f16 qh,kh (elementwise) ----------------
__global__ __launch_bounds__(256) void k_cvt_qk(const float* __restrict__ q,
        const float* __restrict__ k, f16* __restrict__ qh, f16* __restrict__ kh)
{
    size_t i = ((size_t)blockIdx.x * 256 + threadIdx.x) * 4;   // grid covers 4194304 exactly
    float4 a = *(const float4*)(q + i);
    float4 b = *(const float4*)(k + i);
    f16x4 ah = { (_Float16)a.x, (_Float16)a.y, (_Float16)a.z, (_Float16)a.w };
    f16x4 bh = { (_Float16)b.x, (_Float16)b.y, (_Float16)b.z, (_Float16)b.w };
    *(f16x4*)(qh + i) = ah;
    *(f16x4*)(kh + i) = bh;
}

// -------------------- K2c: fp32 v [bh][s][d] -> f16 vt [bh][d][s] -------------
__global__ __launch_bounds__(256) void k_cvt_vt(const float* __restrict__ v,
        f16* __restrict__ vt)
{
    const int s0 = blockIdx.x * 64;
    const int bh = blockIdx.y;
    __shared__ _Float16 tile[64][72];
    const int tid = threadIdx.x;
    const int r = tid >> 4;            // 0..15
    const int d0 = (tid & 15) * 4;
#pragma unroll
    for (int p = 0; p < 4; ++p) {
        int rr = r + p * 16;
        float4 t4 = *(const float4*)(v + ((size_t)bh * Ss + s0 + rr) * HDd + d0);
        tile[d0 + 0][rr] = (_Float16)t4.x;
        tile[d0 + 1][rr] = (_Float16)t4.y;
        tile[d0 + 2][rr] = (_Float16)t4.z;
        tile[d0 + 3][rr] = (_Float16)t4.w;
    }
    __syncthreads();
    const int d = tid >> 2;
    const int c0 = (tid & 3) * 16;
    f16* dst = vt + ((size_t)bh * HDd + d) * Ss + s0 + c0;
    *(f16x8*)(dst)     = *(const f16x8*)&tile[d][c0];
    *(f16x8*)(dst + 8) = *(const f16x8*)&tile[d][c0 + 8];
}

// -------------------- K3: mean-pool k,v into chunks (fp32 path, unchanged) ----
__global__ __launch_bounds__(256) void k_pool(const float* __restrict__ kk,
        const float* __restrict__ vv, float* __restrict__ kc, float* __restrict__ vc)
{
    int idx = blockIdx.x * 256 + threadIdx.x;  // B*H*NC*HD = 131072
    int d = idx & 63;
    int n = (idx >> 6) & 127;
    int bh = idx >> 13;
    const float* kp = kk + ((size_t)bh * Ss + n * CBc) * HDd + d;
    const float* vp = vv + ((size_t)bh * Ss + n * CBc) * HDd + d;
    float sk = 0.f, sv = 0.f;
    for (int t = 0; t < CBc; ++t) { sk += kp[(size_t)t * HDd]; sv += vp[(size_t)t * HDd]; }
    kc[idx] = sk * (1.f / CBc);
    vc[idx] = sv * (1.f / CBc);
}

// -------------------- K3b: zero impb ------------------------------------------
__global__ __launch_bounds__(256) void k_zero(float* __restrict__ p, int n)
{
    int i = blockIdx.x * 256 + threadIdx.x;
    if (i < n) p[i] = 0.f;
}

// -------------------- K4: compressed attention + importance (known-correct) ---
__global__ __launch_bounds__(64) void k_cmp(const float* __restrict__ q,
        const float* __restrict__ kc, const float* __restrict__ vc,
        const float* __restrict__ g, float* __restrict__ impb, float* __restrict__ o)
{
    const int s = blockIdx.x;            // 0..4095
    const int bh = blockIdx.y;           // 0..15
    const int b = bh >> 3, h = bh & 7;
    const int l = threadIdx.x;           // 0..63
    __shared__ float qsh[64];
    __shared__ float psh[128];
    __shared__ float red[64];
    __shared__ float m_sh, sum_sh;
    qsh[l] = q[((size_t)bh * Ss + s) * HDd + l];
    __syncthreads();
    const float* kcb = kc + (size_t)bh * NCc * HDd;
    const float* vcb = vc + (size_t)bh * NCc * HDd;
    const int nvis = (s + 1) >> 5;       // visible chunks
    if (nvis > 0) {
        float a0 = 0.f, a1 = 0.f;
        const float* kr0 = kcb + (size_t)l * HDd;
        const float* kr1 = kcb + (size_t)(l + 64) * HDd;
        for (int d = 0; d < 64; ++d) {
            float qd = qsh[d];
            a0 += qd * kr0[d];
            a1 += qd * kr1[d];
        }
        float s0 = (l < nvis) ? a0 * SCALE : NEGF;
        float s1 = (l + 64 < nvis) ? a1 * SCALE : NEGF;
        red[l] = fmaxf(s0, s1);
        __syncthreads();
        if (l == 0) {
            float mm = red[0];
            for (int j = 1; j < 64; ++j) mm = fmaxf(mm, red[j]);
            m_sh = mm;
        }
        __syncthreads();
        float mx = m_sh;
        float p0 = (l < nvis) ? expf(s0 - mx) : 0.f;
        float p1 = (l + 64 < nvis) ? expf(s1 - mx) : 0.f;
        red[l] = p0 + p1;
        __syncthreads();
        if (l == 0) {
            float ss = 0.f;
            for (int j = 0; j < 64; ++j) ss += red[j];
            sum_sh = ss;
        }
        __syncthreads();
        float rinv = 1.f / sum_sh;
        psh[l] = p0 * rinv;
        psh[l + 64] = p1 * rinv;
    } else {
        psh[l] = 0.f;
        psh[l + 64] = 0.f;
    }
    __syncthreads();
    float outl = 0.f;
    for (int n = 0; n < nvis; ++n)
        outl += psh[n] * vcb[(size_t)n * HDd + l];
    float g0 = g[((size_t)(b * Ss + s)) * 3 + 0];
    o[((size_t)(b * Ss + s)) * DMm + h * HDd + l] = g0 * outl;
    float c = psh[2 * l] + psh[2 * l + 1];
    atomicAdd(&impb[((size_t)bh * NSs + (s >> 6)) * NSs + l], c);
}

// -------------------- K5: top-k selection -------------------------------------
__global__ __launch_bounds__(256) void k_topk(const float* __restrict__ impb,
        int* __restrict__ sel)
{
    int row = blockIdx.x * 256 + threadIdx.x;  // B*H*NS = 1024 rows
    if (row >= Bb * Hh * NSs) return;
    int qb = row & 63;
    float v[64];
    for (int j = 0; j < 64; ++j) {
        float t = impb[(size_t)row * 64 + j];
        if (j > qb) t = NEGF;
        if (j == qb) t += 1e9f;
        v[j] = t;
    }
    for (int t = 0; t < TOPKk; ++t) {
        int bi = 0; float bv = v[0];
        for (int j = 1; j < 64; ++j) {
            if (v[j] > bv) { bv = v[j]; bi = j; }
        }
        sel[(size_t)row * TOPKk + t] = bi;
        v[bi] = -3e38f;
    }
}

// -------------------- K6: MFMA attention, 64-query tiles ----------------------
// MODE 0 = selected (16 tiles from sel), MODE 1 = window (9 tiles qb-8..qb).
// 4 waves: wave w owns q rows [w*16, w*16+16). QK^T and PV on
// v_mfma_f32_16x16x32_f16; fp32 online softmax fully in registers.
// A/B fragments use one consistent k-mapping (k = 8*(lane>>4)+j) on both
// operands — correctness only depends on the HW-verified C/D layout
// (col = lane&15, row = 4*(lane>>4)+reg).
// LDS: K f16 [key][d] swizzled (8KB) | V f16 [d][key] swizzled (8KB) |
//      P f16 per-wave [row16][key64] swizzled (4x2KB). Epilogue aliases
//      the whole block as fp32 O [64][68].
template <int MODE>
__global__ __launch_bounds__(256) void k_attn(const f16* __restrict__ qh,
        const f16* __restrict__ kh, const f16* __restrict__ vt,
        const int* __restrict__ sel, const float* __restrict__ g,
        float* __restrict__ o)
{
    const int qb = blockIdx.x;    // 0..63
    const int bh = blockIdx.y;
    const int b = bh >> 3, h = bh & 7;
    const int q0 = qb * 64;
    const int tid = threadIdx.x;
    const int w  = tid >> 6;      // wave 0..3
    const int l  = tid & 63;
    const int lr = l & 15;
    const int lg = l >> 4;

    __shared__ __align__(16) char smem[24576];
    char* Ks_base = smem;                         // K tile, swizzled
    char* Vs_base = smem + 8192;                  // V^T tile, swizzled
    char* Ps_base = smem + 16384 + w * 2048;      // per-wave P tile

    // Q fragments (registers, once per block): rows q0 + w*16 + lr
    f16x8 qf0, qf1;
    {
        const f16* qptr = qh + ((size_t)bh * Ss + q0 + w * 16 + lr) * HDd + lg * 8;
        qf0 = *(const f16x8*)(qptr);
        qf1 = *(const f16x8*)(qptr + 32);
    }

    float m_r[4], l_r[4];
    f32x4 oacc[4];
#pragma unroll
    for (int rg = 0; rg < 4; ++rg) { m_r[rg] = NEGF; l_r[rg] = 0.f; }
#pragma unroll
    for (int dt = 0; dt < 4; ++dt) oacc[dt] = (f32x4){0.f, 0.f, 0.f, 0.f};

    const int NT = (MODE == 0) ? TOPKk : 9;
    for (int t = 0; t < NT; ++t) {
        int kb;
        if (MODE == 0) kb = sel[((size_t)bh * NSs + qb) * TOPKk + t];
        else { kb = qb - 8 + t; if (kb < 0) continue; }   // block-uniform
        const int kbase = kb * 64;

        // ---- stage K [key][d] and V^T [d][key] as f16, swizzled -------------
#pragma unroll
        for (int p = 0; p < 2; ++p) {
            int idx = tid + p * 256;      // 0..511
            int row = idx >> 3;           // 0..63
            int c8  = idx & 7;            // 8-half column block
            f16x8 kd = *(const f16x8*)(kh + ((size_t)bh * Ss + kbase + row) * HDd + c8 * 8);
            *(f16x8*)(Ks_base + swz(row, row * 128 + c8 * 16)) = kd;
            f16x8 vd = *(const f16x8*)(vt + ((size_t)bh * HDd + row) * Ss + kbase + c8 * 8);
            *(f16x8*)(Vs_base + swz(row, row * 128 + c8 * 16)) = vd;
        }
        __syncthreads();

        // ---- QK^T: 4 key-subtiles x (2 MFMAs over d) ------------------------
        float sv[4][4];   // [kt][reg]
#pragma unroll
        for (int kt = 0; kt < 4; ++kt) {
            int krow = kt * 16 + lr;
            f16x8 kb0 = *(const f16x8*)(Ks_base + swz(krow, krow * 128 + lg * 16));
            f16x8 kb1 = *(const f16x8*)(Ks_base + swz(krow, krow * 128 + lg * 16 + 64));
            f32x4 c = (f32x4){0.f, 0.f, 0.f, 0.f};
            c = __builtin_amdgcn_mfma_f32_16x16x32_f16(qf0, kb0, c, 0, 0, 0);
            c = __builtin_amdgcn_mfma_f32_16x16x32_f16(qf1, kb1, c, 0, 0, 0);
            int kpos = kbase + kt * 16 + lr;
#pragma unroll
            for (int rg = 0; rg < 4; ++rg) {
                int qpos = q0 + w * 16 + 4 * lg + rg;
                bool valid = (kpos <= qpos);
                if (MODE == 1) valid = valid && (kpos > qpos - WINSZ);
                sv[kt][rg] = valid ? c[rg] * SCALE : NEGF;
            }
        }

        // ---- online softmax (in-register; rows 4*lg+rg, 16 lanes/row) -------
        float al[4], rs[4];
#pragma unroll
        for (int rg = 0; rg < 4; ++rg) {
            float m = fmaxf(fmaxf(sv[0][rg], sv[1][rg]), fmaxf(sv[2][rg], sv[3][rg]));
            m = fmaxf(m, __shfl_xor(m, 1));
            m = fmaxf(m, __shfl_xor(m, 2));
            m = fmaxf(m, __shfl_xor(m, 4));
            m = fmaxf(m, __shfl_xor(m, 8));
            float mn = fmaxf(m_r[rg], m);
            al[rg] = __expf(m_r[rg] - mn);   // NEG-NEG -> 1; NEG-fin -> 0 (flushes garbage)
            m_r[rg] = mn;
            rs[rg] = 0.f;
        }
#pragma unroll
        for (int kt = 0; kt < 4; ++kt) {
#pragma unroll
            for (int rg = 0; rg < 4; ++rg) {
                float p = __expf(sv[kt][rg] - m_r[rg]);
                rs[rg] += p;
                int prow = 4 * lg + rg;
                *(f16*)(Ps_base + swz(prow, prow * 128 + (kt * 16 + lr) * 2)) = (_Float16)p;
            }
        }
#pragma unroll
        for (int rg = 0; rg < 4; ++rg) {
            float s = rs[rg];
            s += __shfl_xor(s, 1);
            s += __shfl_xor(s, 2);
            s += __shfl_xor(s, 4);
            s += __shfl_xor(s, 8);
            l_r[rg] = l_r[rg] * al[rg] + s;
#pragma unroll
            for (int dt = 0; dt < 4; ++dt) oacc[dt][rg] *= al[rg];
        }

        // ---- PV: A = P (per-wave LDS), B = V^T -----------------------------
        f16x8 pa0 = *(const f16x8*)(Ps_base + swz(lr, lr * 128 + lg * 16));
        f16x8 pa1 = *(const f16x8*)(Ps_base + swz(lr, lr * 128 + lg * 16 + 64));
#pragma unroll
        for (int dt = 0; dt < 4; ++dt) {
            int vrow = dt * 16 + lr;
            f16x8 vb0 = *(const f16x8*)(Vs_base + swz(vrow, vrow * 128 + lg * 16));
            f16x8 vb1 = *(const f16x8*)(Vs_base + swz(vrow, vrow * 128 + lg * 16 + 64));
            oacc[dt] = __builtin_amdgcn_mfma_f32_16x16x32_f16(pa0, vb0, oacc[dt], 0, 0, 0);
            oacc[dt] = __builtin_amdgcn_mfma_f32_16x16x32_f16(pa1, vb1, oacc[dt], 0, 0, 0);
        }
        __syncthreads();   // protect K/V/P before next tile restage
    }

    // ---- epilogue: normalize, stage O in LDS (stride 68), coalesced RMW -----
    float* Os = (float*)smem;
    float inv[4];
#pragma unroll
    for (int rg = 0; rg < 4; ++rg) inv[rg] = 1.f / l_r[rg];
#pragma unroll
    for (int dt = 0; dt < 4; ++dt) {
#pragma unroll
        for (int rg = 0; rg < 4; ++rg) {
            int row = w * 16 + 4 * lg + rg;
            Os[row * 68 + dt * 16 + lr] = oacc[dt][rg] * inv[rg];
        }
    }
    __syncthreads();
    {
        int row = tid >> 2;
        int c0 = (tid & 3) * 16;
        int s = q0 + row;
        float gv = g[((size_t)(b * Ss + s)) * 3 + ((MODE == 0) ? 1 : 2)];
        float* op = o + ((size_t)(b * Ss + s)) * DMm + h * HDd + c0;
#pragma unroll
        for (int j = 0; j < 4; ++j) {
            float4 val = *(const float4*)&Os[row * 68 + c0 + j * 4];
            float4 cur = *(const float4*)&op[j * 4];
            cur.x += val.x * gv; cur.y += val.y * gv;
            cur.z += val.z * gv; cur.w += val.w * gv;
            *(float4*)&op[j * 4] = cur;
        }
    }
}

// -------------------- K7: y = o @ Wo (tiled 64x64 fp32 GEMM) ------------------
__global__ __launch_bounds__(256) void k_outproj(const float* __restrict__ o,
        const float* __restrict__ Wo, float* __restrict__ y)
{
    const int m0 = blockIdx.x * 64;
    const int n0 = blockIdx.y * 64;
    __shared__ float As[16][68];
    __shared__ float Bs[16][68];
    const int tid = threadIdx.x;
    const int tx = tid & 15, ty = tid >> 4;
    float acc[4][4] = {};
    for (int k0 = 0; k0 < DMm; k0 += 16) {
        {
            int r = tid >> 2;
            int kq = (tid & 3) * 4;
            float4 t4 = *(const float4*)(o + (size_t)(m0 + r) * DMm + k0 + kq);
            As[kq + 0][r] = t4.x;
            As[kq + 1][r] = t4.y;
            As[kq + 2][r] = t4.z;
            As[kq + 3][r] = t4.w;
        }
        {
            int kk = tid >> 4;
            int nq = (tid & 15) * 4;
            float4 t4 = *(const float4*)(Wo + (size_t)(k0 + kk) * DMm + n0 + nq);
            Bs[kk][nq + 0] = t4.x;
            Bs[kk][nq + 1] = t4.y;
            Bs[kk][nq + 2] = t4.z;
            Bs[kk][nq + 3] = t4.w;
        }
        __syncthreads();
#pragma unroll
        for (int kk = 0; kk < 16; ++kk) {
            float4 av = *(const float4*)&As[kk][ty * 4];
            float4 bv = *(const float4*)&Bs[kk][tx * 4];
            acc[0][0] += av.x * bv.x; acc[0][1] += av.x * bv.y; acc[0][2] += av.x * bv.z; acc[0][3] += av.x * bv.w;
            acc[1][0] += av.y * bv.x; acc[1][1] += av.y * bv.y; acc[1][2] += av.y * bv.z; acc[1][3] += av.y * bv.w;
            acc[2][0] += av.z * bv.x; acc[2][1] += av.z * bv.y; acc[2][2] += av.z * bv.z; acc[2][3] += av.z * bv.w;
            acc[3][0] += av.w * bv.x; acc[3][1] += av.w * bv.y; acc[3][2] += av.w * bv.z; acc[3][3] += av.w * bv.w;
        }
        __syncthreads();
    }
#pragma unroll
    for (int i = 0; i < 4; ++i) {
        int m = m0 + ty * 4 + i;
#pragma unroll
        for (int j = 0; j < 4; ++j) {
            int n = n0 + tx * 4 + j;
            y[(size_t)m * DMm + n] = acc[i][j];
        }
    }
}

// -------------------- constant emitter (host-side contract checks) ------------
__global__ __launch_bounds__(256) void k_const(float* __restrict__ y, float val)
{
    int i = blockIdx.x * 256 + threadIdx.x;
    y[i] = val;
}

// -------------------- launch --------------------------------------------------
extern "C" void kernel_launch(void* const* d_in, const int* in_sizes, int n_in,
                              void* d_out, int out_size, void* d_ws, size_t ws_size,
                              hipStream_t stream) {
    float* y = (float*)d_out;
    if (n_in != 6) {
        k_const<<<dim3(16384), 256, 0, stream>>>(y, 88888.f);
        return;
    }
    if (in_sizes[0] != 4194304 || in_sizes[1] != 262144 || in_sizes[2] != 262144 ||
        in_sizes[3] != 262144 || in_sizes[4] != 262144 || in_sizes[5] != 1536) {
        k_const<<<dim3(16384), 256, 0, stream>>>(y, 77777.f);
        return;
    }
    if (ws_size < WS_FLOATS * sizeof(float)) {
        k_const<<<dim3(16384), 256, 0, stream>>>(y, 66666.f);
        return;
    }

    const float* x  = (const float*)d_in[0];
    const float* Wq = (const float*)d_in[1];
    const float* Wk = (const float*)d_in[2];
    const float* Wv = (const float*)d_in[3];
    const float* Wo = (const float*)d_in[4];
    const float* Wg = (const float*)d_in[5];
    float* ws = (float*)d_ws;

    float* qw   = ws + OFF_Q;
    float* kw   = ws + OFF_K;
    float* vw   = ws + OFF_V;
    float* ow   = ws + OFF_O;
    float* gw   = ws + OFF_G;
    float* kcw  = ws + OFF_KC;
    float* vcw  = ws + OFF_VC;
    float* impw = ws + OFF_IMPB;
    int*   selw = (int*)(ws + OFF_SEL);
    f16*   qhw  = (f16*)(ws + OFF_QH);
    f16*   khw  = (f16*)(ws + OFF_KH);
    f16*   vtw  = (f16*)(ws + OFF_VT);

    k_proj<<<dim3(128, 8, 3), 256, 0, stream>>>(x, Wq, Wk, Wv, ws);
    k_gate<<<dim3(32), 256, 0, stream>>>(x, Wg, gw);
    k_cvt_qk<<<dim3(4096), 256, 0, stream>>>(qw, kw, qhw, khw);
    k_cvt_vt<<<dim3(64, 16), 256, 0, stream>>>(vw, vtw);
    k_pool<<<dim3(512), 256, 0, stream>>>(kw, vw, kcw, vcw);
    k_zero<<<dim3(256), 256, 0, stream>>>(impw, Bb * Hh * NSs * NSs);
    k_cmp<<<dim3(4096, 16), 64, 0, stream>>>(qw, kcw, vcw, gw, impw, ow);
    k_topk<<<dim3(4), 256, 0, stream>>>(impw, selw);
    k_attn<0><<<dim3(64, 16), 256, 0, stream>>>(qhw, khw, vtw, selw, gw, ow);
    k_attn<1><<<dim3(64, 16), 256, 0, stream>>>(qhw, khw, vtw, selw, gw, ow);
    k_outproj<<<dim3(128, 8), 256, 0, stream>>>(ow, Wo, y);
}

// Round 2
// 572.190 us; speedup vs baseline: 2.5189x; 1.4042x over previous
//
#include <hip/hip_runtime.h>

// Problem constants
#define Hh    8
#define DMm   512
#define HDd   64
#define CBc   32
#define SBs   64
#define WINSZ 512
#define TOPKk 16
#define NEGF  (-1e30f)
#define Bb    2
#define Ss    4096
#define NCc   128   // S/CB
#define NSs   64    // S/SB
#define SCALE 0.125f

// Workspace layout (float offsets) — fp32 intermediates + f16 attention operands
#define OFF_Q    ((size_t)0)
#define OFF_K    ((size_t)4194304)
#define OFF_V    ((size_t)8388608)
#define OFF_O    ((size_t)12582912)
#define OFF_G    ((size_t)16777216)   // B*S*3 = 24576
#define OFF_KC   ((size_t)16801792)   // 131072
#define OFF_VC   ((size_t)16932864)   // 131072
#define OFF_IMPB ((size_t)17063936)   // B*H*NS*NS = 65536
#define OFF_SEL  ((size_t)17129472)   // B*H*NS*TOPK ints = 16384
#define OFF_QH   ((size_t)17145856)   // f16 q  [bh][s][d]  : 4194304 halves = 2097152 floats
#define OFF_KH   ((size_t)19243008)   // f16 k  [bh][s][d]
#define OFF_VT   ((size_t)21340160)   // f16 v^T [bh][d][s]
#define WS_FLOATS ((size_t)23437312)

typedef _Float16 f16;
typedef _Float16 f16x4 __attribute__((ext_vector_type(4)));
typedef _Float16 f16x8 __attribute__((ext_vector_type(8)));
typedef float    f32x4 __attribute__((ext_vector_type(4)));

__device__ __forceinline__ int swz(int row, int byteoff) {
    return byteoff ^ ((row & 7) << 4);   // spreads stride-128B rows across banks
}

// -------------------- K1: q/k/v projections (tiled 64x64 fp32 GEMM) -----------
__global__ __launch_bounds__(256) void k_proj(const float* __restrict__ x,
        const float* __restrict__ Wq, const float* __restrict__ Wk,
        const float* __restrict__ Wv, float* __restrict__ ws)
{
    const int zone = blockIdx.z;  // 0=q 1=k 2=v
    const float* W = (zone == 0) ? Wq : ((zone == 1) ? Wk : Wv);
    float* dst = ws + (size_t)zone * 4194304;
    const int m0 = blockIdx.x * 64;
    const int n0 = blockIdx.y * 64;
    __shared__ float As[16][68];  // [k][m]
    __shared__ float Bs[16][68];  // [k][n]
    const int tid = threadIdx.x;
    const int tx = tid & 15, ty = tid >> 4;
    float acc[4][4] = {};
    for (int k0 = 0; k0 < DMm; k0 += 16) {
        {
            int r = tid >> 2;
            int kq = (tid & 3) * 4;
            float4 t4 = *(const float4*)(x + (size_t)(m0 + r) * DMm + k0 + kq);
            As[kq + 0][r] = t4.x;
            As[kq + 1][r] = t4.y;
            As[kq + 2][r] = t4.z;
            As[kq + 3][r] = t4.w;
        }
        {
            int kk = tid >> 4;
            int nq = (tid & 15) * 4;
            float4 t4 = *(const float4*)(W + (size_t)(k0 + kk) * DMm + n0 + nq);
            Bs[kk][nq + 0] = t4.x;
            Bs[kk][nq + 1] = t4.y;
            Bs[kk][nq + 2] = t4.z;
            Bs[kk][nq + 3] = t4.w;
        }
        __syncthreads();
#pragma unroll
        for (int kk = 0; kk < 16; ++kk) {
            float4 av = *(const float4*)&As[kk][ty * 4];
            float4 bv = *(const float4*)&Bs[kk][tx * 4];
            acc[0][0] += av.x * bv.x; acc[0][1] += av.x * bv.y; acc[0][2] += av.x * bv.z; acc[0][3] += av.x * bv.w;
            acc[1][0] += av.y * bv.x; acc[1][1] += av.y * bv.y; acc[1][2] += av.y * bv.z; acc[1][3] += av.y * bv.w;
            acc[2][0] += av.z * bv.x; acc[2][1] += av.z * bv.y; acc[2][2] += av.z * bv.z; acc[2][3] += av.z * bv.w;
            acc[3][0] += av.w * bv.x; acc[3][1] += av.w * bv.y; acc[3][2] += av.w * bv.z; acc[3][3] += av.w * bv.w;
        }
        __syncthreads();
    }
    const int h = n0 >> 6;
#pragma unroll
    for (int i = 0; i < 4; ++i) {
        int m = m0 + ty * 4 + i;
        int b = m >> 12;
        int s = m & 4095;
#pragma unroll
        for (int j = 0; j < 4; ++j) {
            int d = tx * 4 + j;
            dst[(((size_t)(b * Hh + h)) * Ss + s) * HDd + d] = acc[i][j];
        }
    }
}

// -------------------- K2: gate = sigmoid(x @ Wg) ------------------------------
__global__ __launch_bounds__(256) void k_gate(const float* __restrict__ x,
        const float* __restrict__ Wg, float* __restrict__ g)
{
    int row = blockIdx.x * 256 + threadIdx.x;   // 0 .. 8191
    if (row >= Bb * Ss) return;
    const float* xr = x + (size_t)row * DMm;
    float a0 = 0.f, a1 = 0.f, a2 = 0.f;
    for (int d = 0; d < DMm; ++d) {
        float xv = xr[d];
        a0 += xv * Wg[d * 3 + 0];
        a1 += xv * Wg[d * 3 + 1];
        a2 += xv * Wg[d * 3 + 2];
    }
    g[(size_t)row * 3 + 0] = 1.f / (1.f + expf(-a0));
    g[(size_t)row * 3 + 1] = 1.f / (1.f + expf(-a1));
    g[(size_t)row * 3 + 2] = 1.f / (1.f + expf(-a2));
}

// -------------------- K2b: fp32 q,k -> f16 qh,kh (elementwise) ----------------
__global__ __launch_bounds__(256) void k_cvt_qk(const float* __restrict__ q,
        const float* __restrict__ k, f16* __restrict__ qh, f16* __restrict__ kh)
{
    size_t i = ((size_t)blockIdx.x * 256 + threadIdx.x) * 4;   // grid covers 4194304 exactly
    float4 a = *(const float4*)(q + i);
    float4 b = *(const float4*)(k + i);
    f16x4 ah = { (_Float16)a.x, (_Float16)a.y, (_Float16)a.z, (_Float16)a.w };
    f16x4 bh = { (_Float16)b.x, (_Float16)b.y, (_Float16)b.z, (_Float16)b.w };
    *(f16x4*)(qh + i) = ah;
    *(f16x4*)(kh + i) = bh;
}

// -------------------- K2c: fp32 v [bh][s][d] -> f16 vt [bh][d][s] -------------
__global__ __launch_bounds__(256) void k_cvt_vt(const float* __restrict__ v,
        f16* __restrict__ vt)
{
    const int s0 = blockIdx.x * 64;
    const int bh = blockIdx.y;
    __shared__ _Float16 tile[64][72];
    const int tid = threadIdx.x;
    const int r = tid >> 4;            // 0..15
    const int d0 = (tid & 15) * 4;
#pragma unroll
    for (int p = 0; p < 4; ++p) {
        int rr = r + p * 16;
        float4 t4 = *(const float4*)(v + ((size_t)bh * Ss + s0 + rr) * HDd + d0);
        tile[d0 + 0][rr] = (_Float16)t4.x;
        tile[d0 + 1][rr] = (_Float16)t4.y;
        tile[d0 + 2][rr] = (_Float16)t4.z;
        tile[d0 + 3][rr] = (_Float16)t4.w;
    }
    __syncthreads();
    const int d = tid >> 2;
    const int c0 = (tid & 3) * 16;
    f16* dst = vt + ((size_t)bh * HDd + d) * Ss + s0 + c0;
    *(f16x8*)(dst)     = *(const f16x8*)&tile[d][c0];
    *(f16x8*)(dst + 8) = *(const f16x8*)&tile[d][c0 + 8];
}

// -------------------- K3: mean-pool k,v into chunks (fp32 path, unchanged) ----
__global__ __launch_bounds__(256) void k_pool(const float* __restrict__ kk,
        const float* __restrict__ vv, float* __restrict__ kc, float* __restrict__ vc)
{
    int idx = blockIdx.x * 256 + threadIdx.x;  // B*H*NC*HD = 131072
    int d = idx & 63;
    int n = (idx >> 6) & 127;
    int bh = idx >> 13;
    const float* kp = kk + ((size_t)bh * Ss + n * CBc) * HDd + d;
    const float* vp = vv + ((size_t)bh * Ss + n * CBc) * HDd + d;
    float sk = 0.f, sv = 0.f;
    for (int t = 0; t < CBc; ++t) { sk += kp[(size_t)t * HDd]; sv += vp[(size_t)t * HDd]; }
    kc[idx] = sk * (1.f / CBc);
    vc[idx] = sv * (1.f / CBc);
}

// -------------------- K4: compressed attention + importance (tiled rewrite) ---
// One block per (qb, bh): 64 q-rows vs up to 128 visible chunks, fp32 all the
// way (selection numerics preserved). Scores into LDS P[64][132], wave-parallel
// softmax (4 lanes/row), register-blocked PV, block-local importance reduction
// written directly to impb (no atomics, no pre-zero).
__global__ __launch_bounds__(256) void k_cmp(const float* __restrict__ q,
        const float* __restrict__ kc, const float* __restrict__ vc,
        const float* __restrict__ g, float* __restrict__ impb, float* __restrict__ o)
{
    const int qb = blockIdx.x;   // 0..63
    const int bh = blockIdx.y;   // 0..15
    const int b = bh >> 3, h = bh & 7;
    const int q0 = qb * 64;
    const int tid = threadIdx.x;
    const int w = tid >> 6;      // wave 0..3
    const int l = tid & 63;      // lane

    __shared__ float qs[64 * 68];    // q tile [row][d]
    __shared__ float Pm[64 * 132];   // scores/probs [row][chunk]
    __shared__ float kv[64 * 65];    // kc^T [d][n] then vc [n][d]
    __shared__ float red2[256];

    const int nvis = 2 * qb + 2;          // chunks possibly visible for the block
    const int NCT = (nvis + 63) >> 6;     // 1 (qb<=30) or 2
    const int ncols = NCT * 64;

    // ---- stage q tile (float4, coalesced) -----------------------------------
#pragma unroll
    for (int p = 0; p < 4; ++p) {
        int idx = tid + p * 256;          // 0..1023
        int r = idx >> 4;
        int c4 = (idx & 15) * 4;
        float4 t4 = *(const float4*)(q + ((size_t)bh * Ss + q0 + r) * HDd + c4);
        qs[r * 68 + c4 + 0] = t4.x;
        qs[r * 68 + c4 + 1] = t4.y;
        qs[r * 68 + c4 + 2] = t4.z;
        qs[r * 68 + c4 + 3] = t4.w;
    }

    const float* kcb = kc + (size_t)bh * NCc * HDd;
    const float* vcb = vc + (size_t)bh * NCc * HDd;

    // ---- scores per chunk-tile ----------------------------------------------
    for (int ct = 0; ct < NCT; ++ct) {
        const int c0 = ct * 64;
        __syncthreads();   // q stage done (ct=0) / kv readers done (ct=1)
        for (int i = tid; i < 64 * 64; i += 256) {
            int n = i >> 6, d = i & 63;
            kv[d * 65 + n] = kcb[(size_t)(c0 + n) * HDd + d];
        }
        __syncthreads();
        float acc[16];
#pragma unroll
        for (int i = 0; i < 16; ++i) acc[i] = 0.f;
        for (int d0 = 0; d0 < 64; d0 += 8) {
            float kreg[8];
#pragma unroll
            for (int j = 0; j < 8; ++j) kreg[j] = kv[(d0 + j) * 65 + l];
#pragma unroll
            for (int qi = 0; qi < 16; ++qi) {
                int qq = w + 4 * qi;
                float4 a = *(const float4*)&qs[qq * 68 + d0];
                float4 bq = *(const float4*)&qs[qq * 68 + d0 + 4];
                acc[qi] += a.x * kreg[0] + a.y * kreg[1] + a.z * kreg[2] + a.w * kreg[3]
                         + bq.x * kreg[4] + bq.y * kreg[5] + bq.z * kreg[6] + bq.w * kreg[7];
            }
        }
        int n = c0 + l;
#pragma unroll
        for (int qi = 0; qi < 16; ++qi) {
            int qq = w + 4 * qi;
            int s = q0 + qq;
            bool valid = (32 * n + 31 <= s);
            Pm[qq * 132 + n] = valid ? acc[qi] * SCALE : NEGF;
        }
    }
    __syncthreads();

    // ---- softmax: 4 lanes per row, normalized probs written back ------------
    {
        int r = tid >> 2;
        int l4 = tid & 3;
        float m = NEGF;
        for (int c = l4; c < ncols; c += 4) m = fmaxf(m, Pm[r * 132 + c]);
        m = fmaxf(m, __shfl_xor(m, 1));
        m = fmaxf(m, __shfl_xor(m, 2));
        float sum = 0.f;
        if (m > NEGF * 0.5f) {
            for (int c = l4; c < ncols; c += 4) {
                float sv = Pm[r * 132 + c];
                float p = (sv <= NEGF * 0.5f) ? 0.f : __expf(sv - m);
                Pm[r * 132 + c] = p;
                sum += p;
            }
        } else {
            for (int c = l4; c < ncols; c += 4) Pm[r * 132 + c] = 0.f;
        }
        sum += __shfl_xor(sum, 1);
        sum += __shfl_xor(sum, 2);
        float inv = (sum > 0.f) ? 1.f / sum : 0.f;
        for (int c = l4; c < ncols; c += 4) Pm[r * 132 + c] *= inv;
    }
    __syncthreads();

    // ---- PV per chunk-tile (kv reused for vc) -------------------------------
    float outr[16];
#pragma unroll
    for (int i = 0; i < 16; ++i) outr[i] = 0.f;
    for (int ct = 0; ct < NCT; ++ct) {
        const int c0 = ct * 64;
        __syncthreads();   // kv readers (scores / prev PV tile) done
        for (int i = tid; i < 64 * 64; i += 256) {
            int n = i >> 6, d = i & 63;
            kv[n * 65 + d] = vcb[(size_t)(c0 + n) * HDd + d];
        }
        __syncthreads();
        for (int n0 = 0; n0 < 64; n0 += 8) {
            float vreg[8];
#pragma unroll
            for (int j = 0; j < 8; ++j) vreg[j] = kv[(n0 + j) * 65 + l];
#pragma unroll
            for (int qi = 0; qi < 16; ++qi) {
                int qq = w + 4 * qi;
                float4 p1 = *(const float4*)&Pm[qq * 132 + c0 + n0];
                float4 p2 = *(const float4*)&Pm[qq * 132 + c0 + n0 + 4];
                outr[qi] += p1.x * vreg[0] + p1.y * vreg[1] + p1.z * vreg[2] + p1.w * vreg[3]
                          + p2.x * vreg[4] + p2.y * vreg[5] + p2.z * vreg[6] + p2.w * vreg[7];
            }
        }
    }

    // ---- importance: block-local reduction, direct store --------------------
    {
        float part = 0.f;
#pragma unroll
        for (int rr = 0; rr < 16; ++rr) {
            int qq = w * 16 + rr;
            int c = 2 * l;
            if (c < ncols) {
                float2 pv2 = *(const float2*)&Pm[qq * 132 + c];
                part += pv2.x + pv2.y;
            }
        }
        red2[w * 64 + l] = part;
    }
    __syncthreads();
    if (tid < 64) {
        float tot = red2[tid] + red2[64 + tid] + red2[128 + tid] + red2[192 + tid];
        impb[((size_t)bh * NSs + qb) * NSs + tid] = tot;
    }

    // ---- output: o = g0 * out_c (first writer of o) -------------------------
#pragma unroll
    for (int qi = 0; qi < 16; ++qi) {
        int qq = w + 4 * qi;
        int s = q0 + qq;
        float g0 = g[((size_t)(b * Ss + s)) * 3 + 0];
        o[((size_t)(b * Ss + s)) * DMm + h * HDd + l] = g0 * outr[qi];
    }
}

// -------------------- K5: top-k selection -------------------------------------
__global__ __launch_bounds__(256) void k_topk(const float* __restrict__ impb,
        int* __restrict__ sel)
{
    int row = blockIdx.x * 256 + threadIdx.x;  // B*H*NS = 1024 rows
    if (row >= Bb * Hh * NSs) return;
    int qb = row & 63;
    float v[64];
    for (int j = 0; j < 64; ++j) {
        float t = impb[(size_t)row * 64 + j];
        if (j > qb) t = NEGF;
        if (j == qb) t += 1e9f;
        v[j] = t;
    }
    for (int t = 0; t < TOPKk; ++t) {
        int bi = 0; float bv = v[0];
        for (int j = 1; j < 64; ++j) {
            if (v[j] > bv) { bv = v[j]; bi = j; }
        }
        sel[(size_t)row * TOPKk + t] = bi;
        v[bi] = -3e38f;
    }
}

// -------------------- K6: MFMA attention, 64-query tiles ----------------------
// MODE 0 = selected (16 tiles from sel), MODE 1 = window (9 tiles qb-8..qb).
// 4 waves: wave w owns q rows [w*16, w*16+16). QK^T and PV on
// v_mfma_f32_16x16x32_f16; fp32 online softmax fully in registers.
template <int MODE>
__global__ __launch_bounds__(256) void k_attn(const f16* __restrict__ qh,
        const f16* __restrict__ kh, const f16* __restrict__ vt,
        const int* __restrict__ sel, const float* __restrict__ g,
        float* __restrict__ o)
{
    const int qb = blockIdx.x;    // 0..63
    const int bh = blockIdx.y;
    const int b = bh >> 3, h = bh & 7;
    const int q0 = qb * 64;
    const int tid = threadIdx.x;
    const int w  = tid >> 6;      // wave 0..3
    const int l  = tid & 63;
    const int lr = l & 15;
    const int lg = l >> 4;

    __shared__ __align__(16) char smem[24576];
    char* Ks_base = smem;                         // K tile, swizzled
    char* Vs_base = smem + 8192;                  // V^T tile, swizzled
    char* Ps_base = smem + 16384 + w * 2048;      // per-wave P tile

    // Q fragments (registers, once per block): rows q0 + w*16 + lr
    f16x8 qf0, qf1;
    {
        const f16* qptr = qh + ((size_t)bh * Ss + q0 + w * 16 + lr) * HDd + lg * 8;
        qf0 = *(const f16x8*)(qptr);
        qf1 = *(const f16x8*)(qptr + 32);
    }

    float m_r[4], l_r[4];
    f32x4 oacc[4];
#pragma unroll
    for (int rg = 0; rg < 4; ++rg) { m_r[rg] = NEGF; l_r[rg] = 0.f; }
#pragma unroll
    for (int dt = 0; dt < 4; ++dt) oacc[dt] = (f32x4){0.f, 0.f, 0.f, 0.f};

    const int NT = (MODE == 0) ? TOPKk : 9;
    for (int t = 0; t < NT; ++t) {
        int kb;
        if (MODE == 0) kb = sel[((size_t)bh * NSs + qb) * TOPKk + t];
        else { kb = qb - 8 + t; if (kb < 0) continue; }   // block-uniform
        const int kbase = kb * 64;

        // ---- stage K [key][d] and V^T [d][key] as f16, swizzled -------------
#pragma unroll
        for (int p = 0; p < 2; ++p) {
            int idx = tid + p * 256;      // 0..511
            int row = idx >> 3;           // 0..63
            int c8  = idx & 7;            // 8-half column block
            f16x8 kd = *(const f16x8*)(kh + ((size_t)bh * Ss + kbase + row) * HDd + c8 * 8);
            *(f16x8*)(Ks_base + swz(row, row * 128 + c8 * 16)) = kd;
            f16x8 vd = *(const f16x8*)(vt + ((size_t)bh * HDd + row) * Ss + kbase + c8 * 8);
            *(f16x8*)(Vs_base + swz(row, row * 128 + c8 * 16)) = vd;
        }
        __syncthreads();

        // ---- QK^T: 4 key-subtiles x (2 MFMAs over d) ------------------------
        float sv[4][4];   // [kt][reg]
#pragma unroll
        for (int kt = 0; kt < 4; ++kt) {
            int krow = kt * 16 + lr;
            f16x8 kb0 = *(const f16x8*)(Ks_base + swz(krow, krow * 128 + lg * 16));
            f16x8 kb1 = *(const f16x8*)(Ks_base + swz(krow, krow * 128 + lg * 16 + 64));
            f32x4 c = (f32x4){0.f, 0.f, 0.f, 0.f};
            c = __builtin_amdgcn_mfma_f32_16x16x32_f16(qf0, kb0, c, 0, 0, 0);
            c = __builtin_amdgcn_mfma_f32_16x16x32_f16(qf1, kb1, c, 0, 0, 0);
            int kpos = kbase + kt * 16 + lr;
#pragma unroll
            for (int rg = 0; rg < 4; ++rg) {
                int qpos = q0 + w * 16 + 4 * lg + rg;
                bool valid = (kpos <= qpos);
                if (MODE == 1) valid = valid && (kpos > qpos - WINSZ);
                sv[kt][rg] = valid ? c[rg] * SCALE : NEGF;
            }
        }

        // ---- online softmax (in-register; rows 4*lg+rg, 16 lanes/row) -------
        float al[4], rs[4];
#pragma unroll
        for (int rg = 0; rg < 4; ++rg) {
            float m = fmaxf(fmaxf(sv[0][rg], sv[1][rg]), fmaxf(sv[2][rg], sv[3][rg]));
            m = fmaxf(m, __shfl_xor(m, 1));
            m = fmaxf(m, __shfl_xor(m, 2));
            m = fmaxf(m, __shfl_xor(m, 4));
            m = fmaxf(m, __shfl_xor(m, 8));
            float mn = fmaxf(m_r[rg], m);
            al[rg] = __expf(m_r[rg] - mn);   // NEG-NEG -> 1; NEG-fin -> 0 (flushes garbage)
            m_r[rg] = mn;
            rs[rg] = 0.f;
        }
#pragma unroll
        for (int kt = 0; kt < 4; ++kt) {
#pragma unroll
            for (int rg = 0; rg < 4; ++rg) {
                float p = __expf(sv[kt][rg] - m_r[rg]);
                rs[rg] += p;
                int prow = 4 * lg + rg;
                *(f16*)(Ps_base + swz(prow, prow * 128 + (kt * 16 + lr) * 2)) = (_Float16)p;
            }
        }
#pragma unroll
        for (int rg = 0; rg < 4; ++rg) {
            float s = rs[rg];
            s += __shfl_xor(s, 1);
            s += __shfl_xor(s, 2);
            s += __shfl_xor(s, 4);
            s += __shfl_xor(s, 8);
            l_r[rg] = l_r[rg] * al[rg] + s;
#pragma unroll
            for (int dt = 0; dt < 4; ++dt) oacc[dt][rg] *= al[rg];
        }

        // ---- PV: A = P (per-wave LDS), B = V^T -----------------------------
        f16x8 pa0 = *(const f16x8*)(Ps_base + swz(lr, lr * 128 + lg * 16));
        f16x8 pa1 = *(const f16x8*)(Ps_base + swz(lr, lr * 128 + lg * 16 + 64));
#pragma unroll
        for (int dt = 0; dt < 4; ++dt) {
            int vrow = dt * 16 + lr;
            f16x8 vb0 = *(const f16x8*)(Vs_base + swz(vrow, vrow * 128 + lg * 16));
            f16x8 vb1 = *(const f16x8*)(Vs_base + swz(vrow, vrow * 128 + lg * 16 + 64));
            oacc[dt] = __builtin_amdgcn_mfma_f32_16x16x32_f16(pa0, vb0, oacc[dt], 0, 0, 0);
            oacc[dt] = __builtin_amdgcn_mfma_f32_16x16x32_f16(pa1, vb1, oacc[dt], 0, 0, 0);
        }
        __syncthreads();   // protect K/V/P before next tile restage
    }

    // ---- epilogue: normalize, stage O in LDS (stride 68), coalesced RMW -----
    float* Os = (float*)smem;
    float inv[4];
#pragma unroll
    for (int rg = 0; rg < 4; ++rg) inv[rg] = 1.f / l_r[rg];
#pragma unroll
    for (int dt = 0; dt < 4; ++dt) {
#pragma unroll
        for (int rg = 0; rg < 4; ++rg) {
            int row = w * 16 + 4 * lg + rg;
            Os[row * 68 + dt * 16 + lr] = oacc[dt][rg] * inv[rg];
        }
    }
    __syncthreads();
    {
        int row = tid >> 2;
        int c0 = (tid & 3) * 16;
        int s = q0 + row;
        float gv = g[((size_t)(b * Ss + s)) * 3 + ((MODE == 0) ? 1 : 2)];
        float* op = o + ((size_t)(b * Ss + s)) * DMm + h * HDd + c0;
#pragma unroll
        for (int j = 0; j < 4; ++j) {
            float4 val = *(const float4*)&Os[row * 68 + c0 + j * 4];
            float4 cur = *(const float4*)&op[j * 4];
            cur.x += val.x * gv; cur.y += val.y * gv;
            cur.z += val.z * gv; cur.w += val.w * gv;
            *(float4*)&op[j * 4] = cur;
        }
    }
}

// -------------------- K7: y = o @ Wo (tiled 64x64 fp32 GEMM) ------------------
__global__ __launch_bounds__(256) void k_outproj(const float* __restrict__ o,
        const float* __restrict__ Wo, float* __restrict__ y)
{
    const int m0 = blockIdx.x * 64;
    const int n0 = blockIdx.y * 64;
    __shared__ float As[16][68];
    __shared__ float Bs[16][68];
    const int tid = threadIdx.x;
    const int tx = tid & 15, ty = tid >> 4;
    float acc[4][4] = {};
    for (int k0 = 0; k0 < DMm; k0 += 16) {
        {
            int r = tid >> 2;
            int kq = (tid & 3) * 4;
            float4 t4 = *(const float4*)(o + (size_t)(m0 + r) * DMm + k0 + kq);
            As[kq + 0][r] = t4.x;
            As[kq + 1][r] = t4.y;
            As[kq + 2][r] = t4.z;
            As[kq + 3][r] = t4.w;
        }
        {
            int kk = tid >> 4;
            int nq = (tid & 15) * 4;
            float4 t4 = *(const float4*)(Wo + (size_t)(k0 + kk) * DMm + n0 + nq);
            Bs[kk][nq + 0] = t4.x;
            Bs[kk][nq + 1] = t4.y;
            Bs[kk][nq + 2] = t4.z;
            Bs[kk][nq + 3] = t4.w;
        }
        __syncthreads();
#pragma unroll
        for (int kk = 0; kk < 16; ++kk) {
            float4 av = *(const float4*)&As[kk][ty * 4];
            float4 bv = *(const float4*)&Bs[kk][tx * 4];
            acc[0][0] += av.x * bv.x; acc[0][1] += av.x * bv.y; acc[0][2] += av.x * bv.z; acc[0][3] += av.x * bv.w;
            acc[1][0] += av.y * bv.x; acc[1][1] += av.y * bv.y; acc[1][2] += av.y * bv.z; acc[1][3] += av.y * bv.w;
            acc[2][0] += av.z * bv.x; acc[2][1] += av.z * bv.y; acc[2][2] += av.z * bv.z; acc[2][3] += av.z * bv.w;
            acc[3][0] += av.w * bv.x; acc[3][1] += av.w * bv.y; acc[3][2] += av.w * bv.z; acc[3][3] += av.w * bv.w;
        }
        __syncthreads();
    }
#pragma unroll
    for (int i = 0; i < 4; ++i) {
        int m = m0 + ty * 4 + i;
#pragma unroll
        for (int j = 0; j < 4; ++j) {
            int n = n0 + tx * 4 + j;
            y[(size_t)m * DMm + n] = acc[i][j];
        }
    }
}

// -------------------- constant emitter (host-side contract checks) ------------
__global__ __launch_bounds__(256) void k_const(float* __restrict__ y, float val)
{
    int i = blockIdx.x * 256 + threadIdx.x;
    y[i] = val;
}

// -------------------- launch --------------------------------------------------
extern "C" void kernel_launch(void* const* d_in, const int* in_sizes, int n_in,
                              void* d_out, int out_size, void* d_ws, size_t ws_size,
                              hipStream_t stream) {
    float* y = (float*)d_out;
    if (n_in != 6) {
        k_const<<<dim3(16384), 256, 0, stream>>>(y, 88888.f);
        return;
    }
    if (in_sizes[0] != 4194304 || in_sizes[1] != 262144 || in_sizes[2] != 262144 ||
        in_sizes[3] != 262144 || in_sizes[4] != 262144 || in_sizes[5] != 1536) {
        k_const<<<dim3(16384), 256, 0, stream>>>(y, 77777.f);
        return;
    }
    if (ws_size < WS_FLOATS * sizeof(float)) {
        k_const<<<dim3(16384), 256, 0, stream>>>(y, 66666.f);
        return;
    }

    const float* x  = (const float*)d_in[0];
    const float* Wq = (const float*)d_in[1];
    const float* Wk = (const float*)d_in[2];
    const float* Wv = (const float*)d_in[3];
    const float* Wo = (const float*)d_in[4];
    const float* Wg = (const float*)d_in[5];
    float* ws = (float*)d_ws;

    float* qw   = ws + OFF_Q;
    float* kw   = ws + OFF_K;
    float* vw   = ws + OFF_V;
    float* ow   = ws + OFF_O;
    float* gw   = ws + OFF_G;
    float* kcw  = ws + OFF_KC;
    float* vcw  = ws + OFF_VC;
    float* impw = ws + OFF_IMPB;
    int*   selw = (int*)(ws + OFF_SEL);
    f16*   qhw  = (f16*)(ws + OFF_QH);
    f16*   khw  = (f16*)(ws + OFF_KH);
    f16*   vtw  = (f16*)(ws + OFF_VT);

    k_proj<<<dim3(128, 8, 3), 256, 0, stream>>>(x, Wq, Wk, Wv, ws);
    k_gate<<<dim3(32), 256, 0, stream>>>(x, Wg, gw);
    k_cvt_qk<<<dim3(4096), 256, 0, stream>>>(qw, kw, qhw, khw);
    k_cvt_vt<<<dim3(64, 16), 256, 0, stream>>>(vw, vtw);
    k_pool<<<dim3(512), 256, 0, stream>>>(kw, vw, kcw, vcw);
    k_cmp<<<dim3(64, 16), 256, 0, stream>>>(qw, kcw, vcw, gw, impw, ow);
    k_topk<<<dim3(4), 256, 0, stream>>>(impw, selw);
    k_attn<0><<<dim3(64, 16), 256, 0, stream>>>(qhw, khw, vtw, selw, gw, ow);
    k_attn<1><<<dim3(64, 16), 256, 0, stream>>>(qhw, khw, vtw, selw, gw, ow);
    k_outproj<<<dim3(128, 8), 256, 0, stream>>>(ow, Wo, y);
}

// Round 3
// 439.663 us; speedup vs baseline: 3.2782x; 1.3014x over previous
//
#include <hip/hip_runtime.h>

// Problem constants
#define Hh    8
#define DMm   512
#define HDd   64
#define CBc   32
#define SBs   64
#define WINSZ 512
#define TOPKk 16
#define NEGF  (-1e30f)
#define Bb    2
#define Ss    4096
#define NCc   128   // S/CB
#define NSs   64    // S/SB
#define SCALE 0.125f

// Workspace layout (float offsets)
#define OFF_Q    ((size_t)0)
#define OFF_K    ((size_t)4194304)
#define OFF_V    ((size_t)8388608)
#define OFF_O    ((size_t)12582912)   // ALIASED: x_hi/x_lo live here until k_cmp writes o
#define OFF_G    ((size_t)16777216)   // B*S*3 = 24576
#define OFF_KC   ((size_t)16801792)   // 131072
#define OFF_VC   ((size_t)16932864)   // 131072
#define OFF_IMPB ((size_t)17063936)   // B*H*NS*NS = 65536
#define OFF_SEL  ((size_t)17129472)   // B*H*NS*TOPK ints = 16384
#define OFF_QH   ((size_t)17145856)   // f16 q  [bh][s][d]
#define OFF_KH   ((size_t)19243008)   // f16 k  [bh][s][d]
#define OFF_VT   ((size_t)21340160)   // f16 v^T [bh][d][s]
#define OFF_WT   ((size_t)23437312)   // 7 x 131072 floats of f16 W^T (hi/lo)
#define WS_FLOATS ((size_t)24354816)

// x_hi/x_lo alias the o region (o first written by k_cmp, after GEMMs)
#define OFF_XH   (OFF_O)
#define OFF_XL   (OFF_O + 2097152)

typedef _Float16 f16;
typedef _Float16 f16x4 __attribute__((ext_vector_type(4)));
typedef _Float16 f16x8 __attribute__((ext_vector_type(8)));
typedef float    f32x4 __attribute__((ext_vector_type(4)));

__device__ __forceinline__ int swz(int row, int byteoff) {
    return byteoff ^ ((row & 7) << 4);   // spreads stride-128B rows across banks
}

// -------------------- K0a: x -> x_hi, x_lo (f16 split) ------------------------
__global__ __launch_bounds__(256) void k_prep_x(const float* __restrict__ x,
        f16* __restrict__ xh, f16* __restrict__ xl)
{
    size_t base = ((size_t)blockIdx.x * 256 + threadIdx.x) * 8;   // covers 4194304
    float4 a = *(const float4*)(x + base);
    float4 b = *(const float4*)(x + base + 4);
    f16x8 h, l;
    h[0] = (_Float16)a.x; l[0] = (_Float16)(a.x - (float)h[0]);
    h[1] = (_Float16)a.y; l[1] = (_Float16)(a.y - (float)h[1]);
    h[2] = (_Float16)a.z; l[2] = (_Float16)(a.z - (float)h[2]);
    h[3] = (_Float16)a.w; l[3] = (_Float16)(a.w - (float)h[3]);
    h[4] = (_Float16)b.x; l[4] = (_Float16)(b.x - (float)h[4]);
    h[5] = (_Float16)b.y; l[5] = (_Float16)(b.y - (float)h[5]);
    h[6] = (_Float16)b.z; l[6] = (_Float16)(b.z - (float)h[6]);
    h[7] = (_Float16)b.w; l[7] = (_Float16)(b.w - (float)h[7]);
    *(f16x8*)(xh + base) = h;
    *(f16x8*)(xl + base) = l;
}

// -------------------- K0b: W -> W^T hi/lo (f16) -------------------------------
// z=0: Wq (hi+lo), z=1: Wk (hi+lo), z=2: Wv (hi+lo), z=3: Wo (hi only)
__global__ __launch_bounds__(256) void k_prep_w(
        const float* __restrict__ Wq, const float* __restrict__ Wk,
        const float* __restrict__ Wv, const float* __restrict__ Wo,
        f16* __restrict__ wqh, f16* __restrict__ wql,
        f16* __restrict__ wkh, f16* __restrict__ wkl,
        f16* __restrict__ wvh, f16* __restrict__ wvl,
        f16* __restrict__ woh)
{
    const int k0 = blockIdx.x * 64;
    const int n0 = blockIdx.y * 64;
    const int z = blockIdx.z;
    const float* W = (z == 0) ? Wq : ((z == 1) ? Wk : ((z == 2) ? Wv : Wo));
    f16* dh = (z == 0) ? wqh : ((z == 1) ? wkh : ((z == 2) ? wvh : woh));
    f16* dl = (z == 0) ? wql : ((z == 1) ? wkl : ((z == 2) ? wvl : (f16*)0));
    __shared__ float T[64][68];
    const int tid = threadIdx.x;
    {
        int r = tid >> 2;
        int c16 = (tid & 3) * 16;
#pragma unroll
        for (int j = 0; j < 4; ++j) {
            float4 w4 = *(const float4*)(W + (size_t)(k0 + r) * DMm + n0 + c16 + j * 4);
            *(float4*)&T[r][c16 + j * 4] = w4;
        }
    }
    __syncthreads();
    {
        int n = tid >> 2;
        int k16 = (tid & 3) * 16;
        f16x8 h0, h1, l0, l1;
#pragma unroll
        for (int j = 0; j < 8; ++j) {
            float wv = T[k16 + j][n];
            h0[j] = (_Float16)wv; l0[j] = (_Float16)(wv - (float)h0[j]);
        }
#pragma unroll
        for (int j = 0; j < 8; ++j) {
            float wv = T[k16 + 8 + j][n];
            h1[j] = (_Float16)wv; l1[j] = (_Float16)(wv - (float)h1[j]);
        }
        size_t o = (size_t)(n0 + n) * DMm + k0 + k16;
        *(f16x8*)(dh + o) = h0;
        *(f16x8*)(dh + o + 8) = h1;
        if (dl) { *(f16x8*)(dl + o) = l0; *(f16x8*)(dl + o + 8) = l1; }
    }
}

// -------------------- K1: MFMA GEMM (128x64 tile, BK=32) ----------------------
// SPLIT: 3-product split-f16 (fp32-grade accuracy). AF32: A staged from fp32.
// OUTM 0: write fp32 [bh][s][d] (+ optional f16 copy). OUTM 1: flat y[m][n].
// Fragment convention identical to k_attn (verified): A/B rows by lr, k=lg*8;
// C: row = 4*lg+rg, col = lr.
template <int SPLIT, int AF32, int OUTM>
__global__ __launch_bounds__(256) void k_gemm(
        const f16* __restrict__ Ah, const f16* __restrict__ Al,
        const float* __restrict__ Af,
        const f16* __restrict__ Bh, const f16* __restrict__ Bl,
        float* __restrict__ Cf, f16* __restrict__ Ch)
{
    const int m0 = blockIdx.x * 128;
    const int n0 = blockIdx.y * 64;
    const int tid = threadIdx.x;
    const int w = tid >> 6, l = tid & 63;
    const int lr = l & 15, lg = l >> 4;
    const int wm = w >> 1, wn = w & 1;

    __shared__ f16 As[SPLIT ? 2 : 1][128 * 40];
    __shared__ f16 Bs[SPLIT ? 2 : 1][64 * 40];

    f32x4 acc[4][2];
#pragma unroll
    for (int mf = 0; mf < 4; ++mf)
#pragma unroll
        for (int nf = 0; nf < 2; ++nf) acc[mf][nf] = (f32x4){0.f, 0.f, 0.f, 0.f};

    const int ar = tid >> 1, ac = (tid & 1) * 16;
    const int bn = tid >> 2, bc = (tid & 3) * 8;

    for (int k0 = 0; k0 < DMm; k0 += 32) {
        // ---- stage A tile [128][32] ----------------------------------------
        if (AF32) {
            const float* src = Af + (size_t)(m0 + ar) * DMm + k0 + ac;
            float4 a0 = *(const float4*)(src);
            float4 a1 = *(const float4*)(src + 4);
            float4 a2 = *(const float4*)(src + 8);
            float4 a3 = *(const float4*)(src + 12);
            f16x8 h0, h1;
            h0[0] = (_Float16)a0.x; h0[1] = (_Float16)a0.y; h0[2] = (_Float16)a0.z; h0[3] = (_Float16)a0.w;
            h0[4] = (_Float16)a1.x; h0[5] = (_Float16)a1.y; h0[6] = (_Float16)a1.z; h0[7] = (_Float16)a1.w;
            h1[0] = (_Float16)a2.x; h1[1] = (_Float16)a2.y; h1[2] = (_Float16)a2.z; h1[3] = (_Float16)a2.w;
            h1[4] = (_Float16)a3.x; h1[5] = (_Float16)a3.y; h1[6] = (_Float16)a3.z; h1[7] = (_Float16)a3.w;
            *(f16x8*)&As[0][ar * 40 + ac] = h0;
            *(f16x8*)&As[0][ar * 40 + ac + 8] = h1;
        } else {
            const f16* src = Ah + (size_t)(m0 + ar) * DMm + k0 + ac;
            *(f16x8*)&As[0][ar * 40 + ac] = *(const f16x8*)src;
            *(f16x8*)&As[0][ar * 40 + ac + 8] = *(const f16x8*)(src + 8);
            if (SPLIT) {
                const f16* src2 = Al + (size_t)(m0 + ar) * DMm + k0 + ac;
                *(f16x8*)&As[SPLIT ? 1 : 0][ar * 40 + ac] = *(const f16x8*)src2;
                *(f16x8*)&As[SPLIT ? 1 : 0][ar * 40 + ac + 8] = *(const f16x8*)(src2 + 8);
            }
        }
        // ---- stage B tile [64][32] (B is W^T: [n][k]) ----------------------
        {
            const f16* src = Bh + (size_t)(n0 + bn) * DMm + k0 + bc;
            *(f16x8*)&Bs[0][bn * 40 + bc] = *(const f16x8*)src;
            if (SPLIT) {
                const f16* src2 = Bl + (size_t)(n0 + bn) * DMm + k0 + bc;
                *(f16x8*)&Bs[SPLIT ? 1 : 0][bn * 40 + bc] = *(const f16x8*)src2;
            }
        }
        __syncthreads();

        f16x8 ahf[4], alf[4], bhf[2], blf[2];
#pragma unroll
        for (int mf = 0; mf < 4; ++mf) {
            int row = wm * 64 + mf * 16 + lr;
            ahf[mf] = *(const f16x8*)&As[0][row * 40 + lg * 8];
            if (SPLIT) alf[mf] = *(const f16x8*)&As[SPLIT ? 1 : 0][row * 40 + lg * 8];
        }
#pragma unroll
        for (int nf = 0; nf < 2; ++nf) {
            int row = wn * 32 + nf * 16 + lr;
            bhf[nf] = *(const f16x8*)&Bs[0][row * 40 + lg * 8];
            if (SPLIT) blf[nf] = *(const f16x8*)&Bs[SPLIT ? 1 : 0][row * 40 + lg * 8];
        }
#pragma unroll
        for (int mf = 0; mf < 4; ++mf)
#pragma unroll
            for (int nf = 0; nf < 2; ++nf) {
                acc[mf][nf] = __builtin_amdgcn_mfma_f32_16x16x32_f16(ahf[mf], bhf[nf], acc[mf][nf], 0, 0, 0);
                if (SPLIT) {
                    acc[mf][nf] = __builtin_amdgcn_mfma_f32_16x16x32_f16(ahf[mf], blf[nf], acc[mf][nf], 0, 0, 0);
                    acc[mf][nf] = __builtin_amdgcn_mfma_f32_16x16x32_f16(alf[mf], bhf[nf], acc[mf][nf], 0, 0, 0);
                }
            }
        __syncthreads();
    }

    // ---- epilogue -----------------------------------------------------------
#pragma unroll
    for (int mf = 0; mf < 4; ++mf)
#pragma unroll
        for (int nf = 0; nf < 2; ++nf)
#pragma unroll
            for (int rg = 0; rg < 4; ++rg) {
                int m = m0 + wm * 64 + mf * 16 + 4 * lg + rg;
                int n = n0 + wn * 32 + nf * 16 + lr;
                float val = acc[mf][nf][rg];
                if (OUTM == 0) {
                    int b = m >> 12, s = m & 4095;
                    int h = n >> 6, d = n & 63;
                    size_t o = (((size_t)(b * Hh + h)) * Ss + s) * HDd + d;
                    Cf[o] = val;
                    if (Ch) Ch[o] = (f16)val;
                } else {
                    Cf[(size_t)m * DMm + n] = val;
                }
            }
}

// -------------------- K2: gate = sigmoid(x @ Wg) ------------------------------
__global__ __launch_bounds__(256) void k_gate(const float* __restrict__ x,
        const float* __restrict__ Wg, float* __restrict__ g)
{
    int row = blockIdx.x * 256 + threadIdx.x;   // 0 .. 8191
    if (row >= Bb * Ss) return;
    const float* xr = x + (size_t)row * DMm;
    float a0 = 0.f, a1 = 0.f, a2 = 0.f;
    for (int d = 0; d < DMm; ++d) {
        float xv = xr[d];
        a0 += xv * Wg[d * 3 + 0];
        a1 += xv * Wg[d * 3 + 1];
        a2 += xv * Wg[d * 3 + 2];
    }
    g[(size_t)row * 3 + 0] = 1.f / (1.f + expf(-a0));
    g[(size_t)row * 3 + 1] = 1.f / (1.f + expf(-a1));
    g[(size_t)row * 3 + 2] = 1.f / (1.f + expf(-a2));
}

// -------------------- K2c: fp32 v [bh][s][d] -> f16 vt [bh][d][s] -------------
__global__ __launch_bounds__(256) void k_cvt_vt(const float* __restrict__ v,
        f16* __restrict__ vt)
{
    const int s0 = blockIdx.x * 64;
    const int bh = blockIdx.y;
    __shared__ _Float16 tile[64][72];
    const int tid = threadIdx.x;
    const int r = tid >> 4;            // 0..15
    const int d0 = (tid & 15) * 4;
#pragma unroll
    for (int p = 0; p < 4; ++p) {
        int rr = r + p * 16;
        float4 t4 = *(const float4*)(v + ((size_t)bh * Ss + s0 + rr) * HDd + d0);
        tile[d0 + 0][rr] = (_Float16)t4.x;
        tile[d0 + 1][rr] = (_Float16)t4.y;
        tile[d0 + 2][rr] = (_Float16)t4.z;
        tile[d0 + 3][rr] = (_Float16)t4.w;
    }
    __syncthreads();
    const int d = tid >> 2;
    const int c0 = (tid & 3) * 16;
    f16* dst = vt + ((size_t)bh * HDd + d) * Ss + s0 + c0;
    *(f16x8*)(dst)     = *(const f16x8*)&tile[d][c0];
    *(f16x8*)(dst + 8) = *(const f16x8*)&tile[d][c0 + 8];
}

// -------------------- K3: mean-pool k,v into chunks ---------------------------
__global__ __launch_bounds__(256) void k_pool(const float* __restrict__ kk,
        const float* __restrict__ vv, float* __restrict__ kc, float* __restrict__ vc)
{
    int idx = blockIdx.x * 256 + threadIdx.x;  // B*H*NC*HD = 131072
    int d = idx & 63;
    int n = (idx >> 6) & 127;
    int bh = idx >> 13;
    const float* kp = kk + ((size_t)bh * Ss + n * CBc) * HDd + d;
    const float* vp = vv + ((size_t)bh * Ss + n * CBc) * HDd + d;
    float sk = 0.f, sv = 0.f;
    for (int t = 0; t < CBc; ++t) { sk += kp[(size_t)t * HDd]; sv += vp[(size_t)t * HDd]; }
    kc[idx] = sk * (1.f / CBc);
    vc[idx] = sv * (1.f / CBc);
}

// -------------------- K4: compressed attention + importance -------------------
__global__ __launch_bounds__(256) void k_cmp(const float* __restrict__ q,
        const float* __restrict__ kc, const float* __restrict__ vc,
        const float* __restrict__ g, float* __restrict__ impb, float* __restrict__ o)
{
    const int qb = blockIdx.x;   // 0..63
    const int bh = blockIdx.y;   // 0..15
    const int b = bh >> 3, h = bh & 7;
    const int q0 = qb * 64;
    const int tid = threadIdx.x;
    const int w = tid >> 6;      // wave 0..3
    const int l = tid & 63;      // lane

    __shared__ float qs[64 * 68];    // q tile [row][d]
    __shared__ float Pm[64 * 132];   // scores/probs [row][chunk]
    __shared__ float kv[64 * 65];    // kc^T [d][n] then vc [n][d]
    __shared__ float red2[256];

    const int nvis = 2 * qb + 2;          // chunks possibly visible for the block
    const int NCT = (nvis + 63) >> 6;     // 1 (qb<=30) or 2
    const int ncols = NCT * 64;

#pragma unroll
    for (int p = 0; p < 4; ++p) {
        int idx = tid + p * 256;          // 0..1023
        int r = idx >> 4;
        int c4 = (idx & 15) * 4;
        float4 t4 = *(const float4*)(q + ((size_t)bh * Ss + q0 + r) * HDd + c4);
        qs[r * 68 + c4 + 0] = t4.x;
        qs[r * 68 + c4 + 1] = t4.y;
        qs[r * 68 + c4 + 2] = t4.z;
        qs[r * 68 + c4 + 3] = t4.w;
    }

    const float* kcb = kc + (size_t)bh * NCc * HDd;
    const float* vcb = vc + (size_t)bh * NCc * HDd;

    for (int ct = 0; ct < NCT; ++ct) {
        const int c0 = ct * 64;
        __syncthreads();
        for (int i = tid; i < 64 * 64; i += 256) {
            int n = i >> 6, d = i & 63;
            kv[d * 65 + n] = kcb[(size_t)(c0 + n) * HDd + d];
        }
        __syncthreads();
        float acc[16];
#pragma unroll
        for (int i = 0; i < 16; ++i) acc[i] = 0.f;
        for (int d0 = 0; d0 < 64; d0 += 8) {
            float kreg[8];
#pragma unroll
            for (int j = 0; j < 8; ++j) kreg[j] = kv[(d0 + j) * 65 + l];
#pragma unroll
            for (int qi = 0; qi < 16; ++qi) {
                int qq = w + 4 * qi;
                float4 a = *(const float4*)&qs[qq * 68 + d0];
                float4 bq = *(const float4*)&qs[qq * 68 + d0 + 4];
                acc[qi] += a.x * kreg[0] + a.y * kreg[1] + a.z * kreg[2] + a.w * kreg[3]
                         + bq.x * kreg[4] + bq.y * kreg[5] + bq.z * kreg[6] + bq.w * kreg[7];
            }
        }
        int n = c0 + l;
#pragma unroll
        for (int qi = 0; qi < 16; ++qi) {
            int qq = w + 4 * qi;
            int s = q0 + qq;
            bool valid = (32 * n + 31 <= s);
            Pm[qq * 132 + n] = valid ? acc[qi] * SCALE : NEGF;
        }
    }
    __syncthreads();

    {
        int r = tid >> 2;
        int l4 = tid & 3;
        float m = NEGF;
        for (int c = l4; c < ncols; c += 4) m = fmaxf(m, Pm[r * 132 + c]);
        m = fmaxf(m, __shfl_xor(m, 1));
        m = fmaxf(m, __shfl_xor(m, 2));
        float sum = 0.f;
        if (m > NEGF * 0.5f) {
            for (int c = l4; c < ncols; c += 4) {
                float sv = Pm[r * 132 + c];
                float p = (sv <= NEGF * 0.5f) ? 0.f : __expf(sv - m);
                Pm[r * 132 + c] = p;
                sum += p;
            }
        } else {
            for (int c = l4; c < ncols; c += 4) Pm[r * 132 + c] = 0.f;
        }
        sum += __shfl_xor(sum, 1);
        sum += __shfl_xor(sum, 2);
        float inv = (sum > 0.f) ? 1.f / sum : 0.f;
        for (int c = l4; c < ncols; c += 4) Pm[r * 132 + c] *= inv;
    }
    __syncthreads();

    float outr[16];
#pragma unroll
    for (int i = 0; i < 16; ++i) outr[i] = 0.f;
    for (int ct = 0; ct < NCT; ++ct) {
        const int c0 = ct * 64;
        __syncthreads();
        for (int i = tid; i < 64 * 64; i += 256) {
            int n = i >> 6, d = i & 63;
            kv[n * 65 + d] = vcb[(size_t)(c0 + n) * HDd + d];
        }
        __syncthreads();
        for (int n0 = 0; n0 < 64; n0 += 8) {
            float vreg[8];
#pragma unroll
            for (int j = 0; j < 8; ++j) vreg[j] = kv[(n0 + j) * 65 + l];
#pragma unroll
            for (int qi = 0; qi < 16; ++qi) {
                int qq = w + 4 * qi;
                float4 p1 = *(const float4*)&Pm[qq * 132 + c0 + n0];
                float4 p2 = *(const float4*)&Pm[qq * 132 + c0 + n0 + 4];
                outr[qi] += p1.x * vreg[0] + p1.y * vreg[1] + p1.z * vreg[2] + p1.w * vreg[3]
                          + p2.x * vreg[4] + p2.y * vreg[5] + p2.z * vreg[6] + p2.w * vreg[7];
            }
        }
    }

    {
        float part = 0.f;
#pragma unroll
        for (int rr = 0; rr < 16; ++rr) {
            int qq = w * 16 + rr;
            int c = 2 * l;
            if (c < ncols) {
                float2 pv2 = *(const float2*)&Pm[qq * 132 + c];
                part += pv2.x + pv2.y;
            }
        }
        red2[w * 64 + l] = part;
    }
    __syncthreads();
    if (tid < 64) {
        float tot = red2[tid] + red2[64 + tid] + red2[128 + tid] + red2[192 + tid];
        impb[((size_t)bh * NSs + qb) * NSs + tid] = tot;
    }

#pragma unroll
    for (int qi = 0; qi < 16; ++qi) {
        int qq = w + 4 * qi;
        int s = q0 + qq;
        float g0 = g[((size_t)(b * Ss + s)) * 3 + 0];
        o[((size_t)(b * Ss + s)) * DMm + h * HDd + l] = g0 * outr[qi];
    }
}

// -------------------- K5: top-k selection -------------------------------------
__global__ __launch_bounds__(256) void k_topk(const float* __restrict__ impb,
        int* __restrict__ sel)
{
    int row = blockIdx.x * 256 + threadIdx.x;  // B*H*NS = 1024 rows
    if (row >= Bb * Hh * NSs) return;
    int qb = row & 63;
    float v[64];
    for (int j = 0; j < 64; ++j) {
        float t = impb[(size_t)row * 64 + j];
        if (j > qb) t = NEGF;
        if (j == qb) t += 1e9f;
        v[j] = t;
    }
    for (int t = 0; t < TOPKk; ++t) {
        int bi = 0; float bv = v[0];
        for (int j = 1; j < 64; ++j) {
            if (v[j] > bv) { bv = v[j]; bi = j; }
        }
        sel[(size_t)row * TOPKk + t] = bi;
        v[bi] = -3e38f;
    }
}

// -------------------- K6: MFMA attention, 64-query tiles ----------------------
template <int MODE>
__global__ __launch_bounds__(256) void k_attn(const f16* __restrict__ qh,
        const f16* __restrict__ kh, const f16* __restrict__ vt,
        const int* __restrict__ sel, const float* __restrict__ g,
        float* __restrict__ o)
{
    const int qb = blockIdx.x;    // 0..63
    const int bh = blockIdx.y;
    const int b = bh >> 3, h = bh & 7;
    const int q0 = qb * 64;
    const int tid = threadIdx.x;
    const int w  = tid >> 6;      // wave 0..3
    const int l  = tid & 63;
    const int lr = l & 15;
    const int lg = l >> 4;

    __shared__ __align__(16) char smem[24576];
    char* Ks_base = smem;                         // K tile, swizzled
    char* Vs_base = smem + 8192;                  // V^T tile, swizzled
    char* Ps_base = smem + 16384 + w * 2048;      // per-wave P tile

    f16x8 qf0, qf1;
    {
        const f16* qptr = qh + ((size_t)bh * Ss + q0 + w * 16 + lr) * HDd + lg * 8;
        qf0 = *(const f16x8*)(qptr);
        qf1 = *(const f16x8*)(qptr + 32);
    }

    float m_r[4], l_r[4];
    f32x4 oacc[4];
#pragma unroll
    for (int rg = 0; rg < 4; ++rg) { m_r[rg] = NEGF; l_r[rg] = 0.f; }
#pragma unroll
    for (int dt = 0; dt < 4; ++dt) oacc[dt] = (f32x4){0.f, 0.f, 0.f, 0.f};

    const int NT = (MODE == 0) ? TOPKk : 9;
    for (int t = 0; t < NT; ++t) {
        int kb;
        if (MODE == 0) kb = sel[((size_t)bh * NSs + qb) * TOPKk + t];
        else { kb = qb - 8 + t; if (kb < 0) continue; }   // block-uniform
        const int kbase = kb * 64;

#pragma unroll
        for (int p = 0; p < 2; ++p) {
            int idx = tid + p * 256;      // 0..511
            int row = idx >> 3;           // 0..63
            int c8  = idx & 7;            // 8-half column block
            f16x8 kd = *(const f16x8*)(kh + ((size_t)bh * Ss + kbase + row) * HDd + c8 * 8);
            *(f16x8*)(Ks_base + swz(row, row * 128 + c8 * 16)) = kd;
            f16x8 vd = *(const f16x8*)(vt + ((size_t)bh * HDd + row) * Ss + kbase + c8 * 8);
            *(f16x8*)(Vs_base + swz(row, row * 128 + c8 * 16)) = vd;
        }
        __syncthreads();

        float sv[4][4];   // [kt][reg]
#pragma unroll
        for (int kt = 0; kt < 4; ++kt) {
            int krow = kt * 16 + lr;
            f16x8 kb0 = *(const f16x8*)(Ks_base + swz(krow, krow * 128 + lg * 16));
            f16x8 kb1 = *(const f16x8*)(Ks_base + swz(krow, krow * 128 + lg * 16 + 64));
            f32x4 c = (f32x4){0.f, 0.f, 0.f, 0.f};
            c = __builtin_amdgcn_mfma_f32_16x16x32_f16(qf0, kb0, c, 0, 0, 0);
            c = __builtin_amdgcn_mfma_f32_16x16x32_f16(qf1, kb1, c, 0, 0, 0);
            int kpos = kbase + kt * 16 + lr;
#pragma unroll
            for (int rg = 0; rg < 4; ++rg) {
                int qpos = q0 + w * 16 + 4 * lg + rg;
                bool valid = (kpos <= qpos);
                if (MODE == 1) valid = valid && (kpos > qpos - WINSZ);
                sv[kt][rg] = valid ? c[rg] * SCALE : NEGF;
            }
        }

        float al[4], rs[4];
#pragma unroll
        for (int rg = 0; rg < 4; ++rg) {
            float m = fmaxf(fmaxf(sv[0][rg], sv[1][rg]), fmaxf(sv[2][rg], sv[3][rg]));
            m = fmaxf(m, __shfl_xor(m, 1));
            m = fmaxf(m, __shfl_xor(m, 2));
            m = fmaxf(m, __shfl_xor(m, 4));
            m = fmaxf(m, __shfl_xor(m, 8));
            float mn = fmaxf(m_r[rg], m);
            al[rg] = __expf(m_r[rg] - mn);
            m_r[rg] = mn;
            rs[rg] = 0.f;
        }
#pragma unroll
        for (int kt = 0; kt < 4; ++kt) {
#pragma unroll
            for (int rg = 0; rg < 4; ++rg) {
                float p = __expf(sv[kt][rg] - m_r[rg]);
                rs[rg] += p;
                int prow = 4 * lg + rg;
                *(f16*)(Ps_base + swz(prow, prow * 128 + (kt * 16 + lr) * 2)) = (_Float16)p;
            }
        }
#pragma unroll
        for (int rg = 0; rg < 4; ++rg) {
            float s = rs[rg];
            s += __shfl_xor(s, 1);
            s += __shfl_xor(s, 2);
            s += __shfl_xor(s, 4);
            s += __shfl_xor(s, 8);
            l_r[rg] = l_r[rg] * al[rg] + s;
#pragma unroll
            for (int dt = 0; dt < 4; ++dt) oacc[dt][rg] *= al[rg];
        }

        f16x8 pa0 = *(const f16x8*)(Ps_base + swz(lr, lr * 128 + lg * 16));
        f16x8 pa1 = *(const f16x8*)(Ps_base + swz(lr, lr * 128 + lg * 16 + 64));
#pragma unroll
        for (int dt = 0; dt < 4; ++dt) {
            int vrow = dt * 16 + lr;
            f16x8 vb0 = *(const f16x8*)(Vs_base + swz(vrow, vrow * 128 + lg * 16));
            f16x8 vb1 = *(const f16x8*)(Vs_base + swz(vrow, vrow * 128 + lg * 16 + 64));
            oacc[dt] = __builtin_amdgcn_mfma_f32_16x16x32_f16(pa0, vb0, oacc[dt], 0, 0, 0);
            oacc[dt] = __builtin_amdgcn_mfma_f32_16x16x32_f16(pa1, vb1, oacc[dt], 0, 0, 0);
        }
        __syncthreads();
    }

    float* Os = (float*)smem;
    float inv[4];
#pragma unroll
    for (int rg = 0; rg < 4; ++rg) inv[rg] = 1.f / l_r[rg];
#pragma unroll
    for (int dt = 0; dt < 4; ++dt) {
#pragma unroll
        for (int rg = 0; rg < 4; ++rg) {
            int row = w * 16 + 4 * lg + rg;
            Os[row * 68 + dt * 16 + lr] = oacc[dt][rg] * inv[rg];
        }
    }
    __syncthreads();
    {
        int row = tid >> 2;
        int c0 = (tid & 3) * 16;
        int s = q0 + row;
        float gv = g[((size_t)(b * Ss + s)) * 3 + ((MODE == 0) ? 1 : 2)];
        float* op = o + ((size_t)(b * Ss + s)) * DMm + h * HDd + c0;
#pragma unroll
        for (int j = 0; j < 4; ++j) {
            float4 val = *(const float4*)&Os[row * 68 + c0 + j * 4];
            float4 cur = *(const float4*)&op[j * 4];
            cur.x += val.x * gv; cur.y += val.y * gv;
            cur.z += val.z * gv; cur.w += val.w * gv;
            *(float4*)&op[j * 4] = cur;
        }
    }
}

// -------------------- constant emitter (host-side contract checks) ------------
__global__ __launch_bounds__(256) void k_const(float* __restrict__ y, float val)
{
    int i = blockIdx.x * 256 + threadIdx.x;
    y[i] = val;
}

// -------------------- launch --------------------------------------------------
extern "C" void kernel_launch(void* const* d_in, const int* in_sizes, int n_in,
                              void* d_out, int out_size, void* d_ws, size_t ws_size,
                              hipStream_t stream) {
    float* y = (float*)d_out;
    if (n_in != 6) {
        k_const<<<dim3(16384), 256, 0, stream>>>(y, 88888.f);
        return;
    }
    if (in_sizes[0] != 4194304 || in_sizes[1] != 262144 || in_sizes[2] != 262144 ||
        in_sizes[3] != 262144 || in_sizes[4] != 262144 || in_sizes[5] != 1536) {
        k_const<<<dim3(16384), 256, 0, stream>>>(y, 77777.f);
        return;
    }
    if (ws_size < WS_FLOATS * sizeof(float)) {
        k_const<<<dim3(16384), 256, 0, stream>>>(y, 66666.f);
        return;
    }

    const float* x  = (const float*)d_in[0];
    const float* Wq = (const float*)d_in[1];
    const float* Wk = (const float*)d_in[2];
    const float* Wv = (const float*)d_in[3];
    const float* Wo = (const float*)d_in[4];
    const float* Wg = (const float*)d_in[5];
    float* ws = (float*)d_ws;

    float* qw   = ws + OFF_Q;
    float* kw   = ws + OFF_K;
    float* vw   = ws + OFF_V;
    float* ow   = ws + OFF_O;
    float* gw   = ws + OFF_G;
    float* kcw  = ws + OFF_KC;
    float* vcw  = ws + OFF_VC;
    float* impw = ws + OFF_IMPB;
    int*   selw = (int*)(ws + OFF_SEL);
    f16*   qhw  = (f16*)(ws + OFF_QH);
    f16*   khw  = (f16*)(ws + OFF_KH);
    f16*   vtw  = (f16*)(ws + OFF_VT);
    f16*   xhw  = (f16*)(ws + OFF_XH);   // aliases o region (freed before k_cmp)
    f16*   xlw  = (f16*)(ws + OFF_XL);
    f16*   wqh  = (f16*)(ws + OFF_WT);
    f16*   wql  = (f16*)(ws + OFF_WT + 131072);
    f16*   wkh  = (f16*)(ws + OFF_WT + 262144);
    f16*   wkl  = (f16*)(ws + OFF_WT + 393216);
    f16*   wvh  = (f16*)(ws + OFF_WT + 524288);
    f16*   wvl  = (f16*)(ws + OFF_WT + 655360);
    f16*   woh  = (f16*)(ws + OFF_WT + 786432);

    k_prep_x<<<dim3(2048), 256, 0, stream>>>(x, xhw, xlw);
    k_prep_w<<<dim3(8, 8, 4), 256, 0, stream>>>(Wq, Wk, Wv, Wo,
            wqh, wql, wkh, wkl, wvh, wvl, woh);
    // q, k, v projections: split-f16 MFMA (fp32-grade, selection-safe)
    k_gemm<1, 0, 0><<<dim3(64, 8), 256, 0, stream>>>(xhw, xlw, (const float*)0,
            wqh, wql, qw, qhw);
    k_gemm<1, 0, 0><<<dim3(64, 8), 256, 0, stream>>>(xhw, xlw, (const float*)0,
            wkh, wkl, kw, khw);
    k_gemm<1, 0, 0><<<dim3(64, 8), 256, 0, stream>>>(xhw, xlw, (const float*)0,
            wvh, wvl, vw, (f16*)0);
    k_gate<<<dim3(32), 256, 0, stream>>>(x, Wg, gw);
    k_cvt_vt<<<dim3(64, 16), 256, 0, stream>>>(vw, vtw);
    k_pool<<<dim3(512), 256, 0, stream>>>(kw, vw, kcw, vcw);
    k_cmp<<<dim3(64, 16), 256, 0, stream>>>(qw, kcw, vcw, gw, impw, ow);
    k_topk<<<dim3(4), 256, 0, stream>>>(impw, selw);
    k_attn<0><<<dim3(64, 16), 256, 0, stream>>>(qhw, khw, vtw, selw, gw, ow);
    k_attn<1><<<dim3(64, 16), 256, 0, stream>>>(qhw, khw, vtw, selw, gw, ow);
    // out projection: plain f16 MFMA, A staged from fp32 o
    k_gemm<0, 1, 1><<<dim3(64, 8), 256, 0, stream>>>((const f16*)0, (const f16*)0,
            ow, woh, (const f16*)0, y, (f16*)0);
}

// Round 4
// 378.763 us; speedup vs baseline: 3.8053x; 1.1608x over previous
//
#include <hip/hip_runtime.h>

// Problem constants
#define Hh    8
#define DMm   512
#define HDd   64
#define CBc   32
#define SBs   64
#define WINSZ 512
#define TOPKk 16
#define NEGF  (-1e30f)
#define Bb    2
#define Ss    4096
#define NCc   128   // S/CB
#define NSs   64    // S/SB
#define SCALE 0.125f

// Workspace layout (float offsets)
#define OFF_Q    ((size_t)0)          // (unused fp32 q region, kept for layout stability)
#define OFF_K    ((size_t)4194304)
#define OFF_V    ((size_t)8388608)
#define OFF_O    ((size_t)12582912)   // ALIASED: x_hi/x_lo live here until k_cmp writes o
#define OFF_G    ((size_t)16777216)   // B*S*3 = 24576
#define OFF_KC   ((size_t)16801792)   // now: kc_hi/kc_lo f16 (2 x 131072 halves)
#define OFF_VC   ((size_t)16932864)   // now: vc^T f16 (131072 halves)
#define OFF_IMPB ((size_t)17063936)   // B*H*NS*NS = 65536
#define OFF_SEL  ((size_t)17129472)   // B*H*NS*TOPK ints = 16384
#define OFF_QH   ((size_t)17145856)   // f16 q  [bh][s][d]
#define OFF_KH   ((size_t)19243008)   // f16 k  [bh][s][d]
#define OFF_VT   ((size_t)21340160)   // f16 v^T [bh][d][s]
#define OFF_WT   ((size_t)23437312)   // 7 x 131072 floats of f16 W^T (hi/lo)
#define OFF_QL   ((size_t)24354816)   // f16 q_lo [bh][s][d] : 2097152 halves
#define WS_FLOATS ((size_t)25403392)

// x_hi/x_lo alias the o region (o first written by k_cmp, after GEMMs)
#define OFF_XH   (OFF_O)
#define OFF_XL   (OFF_O + 2097152)

#define OFF_KCH  (OFF_KC)
#define OFF_KCL  (OFF_KC + 65536)
#define OFF_VCT  (OFF_VC)

typedef _Float16 f16;
typedef _Float16 f16x4 __attribute__((ext_vector_type(4)));
typedef _Float16 f16x8 __attribute__((ext_vector_type(8)));
typedef float    f32x4 __attribute__((ext_vector_type(4)));

__device__ __forceinline__ int swz(int row, int byteoff) {
    return byteoff ^ ((row & 7) << 4);   // spreads stride-128B rows across banks
}

// -------------------- K0a: x -> x_hi, x_lo (f16 split) ------------------------
__global__ __launch_bounds__(256) void k_prep_x(const float* __restrict__ x,
        f16* __restrict__ xh, f16* __restrict__ xl)
{
    size_t base = ((size_t)blockIdx.x * 256 + threadIdx.x) * 8;   // covers 4194304
    float4 a = *(const float4*)(x + base);
    float4 b = *(const float4*)(x + base + 4);
    f16x8 h, l;
    h[0] = (_Float16)a.x; l[0] = (_Float16)(a.x - (float)h[0]);
    h[1] = (_Float16)a.y; l[1] = (_Float16)(a.y - (float)h[1]);
    h[2] = (_Float16)a.z; l[2] = (_Float16)(a.z - (float)h[2]);
    h[3] = (_Float16)a.w; l[3] = (_Float16)(a.w - (float)h[3]);
    h[4] = (_Float16)b.x; l[4] = (_Float16)(b.x - (float)h[4]);
    h[5] = (_Float16)b.y; l[5] = (_Float16)(b.y - (float)h[5]);
    h[6] = (_Float16)b.z; l[6] = (_Float16)(b.z - (float)h[6]);
    h[7] = (_Float16)b.w; l[7] = (_Float16)(b.w - (float)h[7]);
    *(f16x8*)(xh + base) = h;
    *(f16x8*)(xl + base) = l;
}

// -------------------- K0b: W -> W^T hi/lo (f16) -------------------------------
__global__ __launch_bounds__(256) void k_prep_w(
        const float* __restrict__ Wq, const float* __restrict__ Wk,
        const float* __restrict__ Wv, const float* __restrict__ Wo,
        f16* __restrict__ wqh, f16* __restrict__ wql,
        f16* __restrict__ wkh, f16* __restrict__ wkl,
        f16* __restrict__ wvh, f16* __restrict__ wvl,
        f16* __restrict__ woh)
{
    const int k0 = blockIdx.x * 64;
    const int n0 = blockIdx.y * 64;
    const int z = blockIdx.z;
    const float* W = (z == 0) ? Wq : ((z == 1) ? Wk : ((z == 2) ? Wv : Wo));
    f16* dh = (z == 0) ? wqh : ((z == 1) ? wkh : ((z == 2) ? wvh : woh));
    f16* dl = (z == 0) ? wql : ((z == 1) ? wkl : ((z == 2) ? wvl : (f16*)0));
    __shared__ float T[64][68];
    const int tid = threadIdx.x;
    {
        int r = tid >> 2;
        int c16 = (tid & 3) * 16;
#pragma unroll
        for (int j = 0; j < 4; ++j) {
            float4 w4 = *(const float4*)(W + (size_t)(k0 + r) * DMm + n0 + c16 + j * 4);
            *(float4*)&T[r][c16 + j * 4] = w4;
        }
    }
    __syncthreads();
    {
        int n = tid >> 2;
        int k16 = (tid & 3) * 16;
        f16x8 h0, h1, l0, l1;
#pragma unroll
        for (int j = 0; j < 8; ++j) {
            float wv = T[k16 + j][n];
            h0[j] = (_Float16)wv; l0[j] = (_Float16)(wv - (float)h0[j]);
        }
#pragma unroll
        for (int j = 0; j < 8; ++j) {
            float wv = T[k16 + 8 + j][n];
            h1[j] = (_Float16)wv; l1[j] = (_Float16)(wv - (float)h1[j]);
        }
        size_t o = (size_t)(n0 + n) * DMm + k0 + k16;
        *(f16x8*)(dh + o) = h0;
        *(f16x8*)(dh + o + 8) = h1;
        if (dl) { *(f16x8*)(dl + o) = l0; *(f16x8*)(dl + o + 8) = l1; }
    }
}

// -------------------- K1: MFMA GEMM (128x64 tile, BK=32) ----------------------
// SPLIT: 3-product split-f16 (fp32-grade). AF32: A staged from fp32.
// OUTM 0: write [bh][s][d]: fp32 (if Cf), f16 hi (if Ch), f16 lo (if Cl).
// OUTM 1: flat y[m][n].
template <int SPLIT, int AF32, int OUTM>
__global__ __launch_bounds__(256) void k_gemm(
        const f16* __restrict__ Ah, const f16* __restrict__ Al,
        const float* __restrict__ Af,
        const f16* __restrict__ Bh, const f16* __restrict__ Bl,
        float* __restrict__ Cf, f16* __restrict__ Ch, f16* __restrict__ Cl)
{
    const int m0 = blockIdx.x * 128;
    const int n0 = blockIdx.y * 64;
    const int tid = threadIdx.x;
    const int w = tid >> 6, l = tid & 63;
    const int lr = l & 15, lg = l >> 4;
    const int wm = w >> 1, wn = w & 1;

    __shared__ f16 As[SPLIT ? 2 : 1][128 * 40];
    __shared__ f16 Bs[SPLIT ? 2 : 1][64 * 40];

    f32x4 acc[4][2];
#pragma unroll
    for (int mf = 0; mf < 4; ++mf)
#pragma unroll
        for (int nf = 0; nf < 2; ++nf) acc[mf][nf] = (f32x4){0.f, 0.f, 0.f, 0.f};

    const int ar = tid >> 1, ac = (tid & 1) * 16;
    const int bn = tid >> 2, bc = (tid & 3) * 8;

    for (int k0 = 0; k0 < DMm; k0 += 32) {
        if (AF32) {
            const float* src = Af + (size_t)(m0 + ar) * DMm + k0 + ac;
            float4 a0 = *(const float4*)(src);
            float4 a1 = *(const float4*)(src + 4);
            float4 a2 = *(const float4*)(src + 8);
            float4 a3 = *(const float4*)(src + 12);
            f16x8 h0, h1;
            h0[0] = (_Float16)a0.x; h0[1] = (_Float16)a0.y; h0[2] = (_Float16)a0.z; h0[3] = (_Float16)a0.w;
            h0[4] = (_Float16)a1.x; h0[5] = (_Float16)a1.y; h0[6] = (_Float16)a1.z; h0[7] = (_Float16)a1.w;
            h1[0] = (_Float16)a2.x; h1[1] = (_Float16)a2.y; h1[2] = (_Float16)a2.z; h1[3] = (_Float16)a2.w;
            h1[4] = (_Float16)a3.x; h1[5] = (_Float16)a3.y; h1[6] = (_Float16)a3.z; h1[7] = (_Float16)a3.w;
            *(f16x8*)&As[0][ar * 40 + ac] = h0;
            *(f16x8*)&As[0][ar * 40 + ac + 8] = h1;
        } else {
            const f16* src = Ah + (size_t)(m0 + ar) * DMm + k0 + ac;
            *(f16x8*)&As[0][ar * 40 + ac] = *(const f16x8*)src;
            *(f16x8*)&As[0][ar * 40 + ac + 8] = *(const f16x8*)(src + 8);
            if (SPLIT) {
                const f16* src2 = Al + (size_t)(m0 + ar) * DMm + k0 + ac;
                *(f16x8*)&As[SPLIT ? 1 : 0][ar * 40 + ac] = *(const f16x8*)src2;
                *(f16x8*)&As[SPLIT ? 1 : 0][ar * 40 + ac + 8] = *(const f16x8*)(src2 + 8);
            }
        }
        {
            const f16* src = Bh + (size_t)(n0 + bn) * DMm + k0 + bc;
            *(f16x8*)&Bs[0][bn * 40 + bc] = *(const f16x8*)src;
            if (SPLIT) {
                const f16* src2 = Bl + (size_t)(n0 + bn) * DMm + k0 + bc;
                *(f16x8*)&Bs[SPLIT ? 1 : 0][bn * 40 + bc] = *(const f16x8*)src2;
            }
        }
        __syncthreads();

        f16x8 ahf[4], alf[4], bhf[2], blf[2];
#pragma unroll
        for (int mf = 0; mf < 4; ++mf) {
            int row = wm * 64 + mf * 16 + lr;
            ahf[mf] = *(const f16x8*)&As[0][row * 40 + lg * 8];
            if (SPLIT) alf[mf] = *(const f16x8*)&As[SPLIT ? 1 : 0][row * 40 + lg * 8];
        }
#pragma unroll
        for (int nf = 0; nf < 2; ++nf) {
            int row = wn * 32 + nf * 16 + lr;
            bhf[nf] = *(const f16x8*)&Bs[0][row * 40 + lg * 8];
            if (SPLIT) blf[nf] = *(const f16x8*)&Bs[SPLIT ? 1 : 0][row * 40 + lg * 8];
        }
#pragma unroll
        for (int mf = 0; mf < 4; ++mf)
#pragma unroll
            for (int nf = 0; nf < 2; ++nf) {
                acc[mf][nf] = __builtin_amdgcn_mfma_f32_16x16x32_f16(ahf[mf], bhf[nf], acc[mf][nf], 0, 0, 0);
                if (SPLIT) {
                    acc[mf][nf] = __builtin_amdgcn_mfma_f32_16x16x32_f16(ahf[mf], blf[nf], acc[mf][nf], 0, 0, 0);
                    acc[mf][nf] = __builtin_amdgcn_mfma_f32_16x16x32_f16(alf[mf], bhf[nf], acc[mf][nf], 0, 0, 0);
                }
            }
        __syncthreads();
    }

#pragma unroll
    for (int mf = 0; mf < 4; ++mf)
#pragma unroll
        for (int nf = 0; nf < 2; ++nf)
#pragma unroll
            for (int rg = 0; rg < 4; ++rg) {
                int m = m0 + wm * 64 + mf * 16 + 4 * lg + rg;
                int n = n0 + wn * 32 + nf * 16 + lr;
                float val = acc[mf][nf][rg];
                if (OUTM == 0) {
                    int b = m >> 12, s = m & 4095;
                    int h = n >> 6, d = n & 63;
                    size_t o = (((size_t)(b * Hh + h)) * Ss + s) * HDd + d;
                    if (Cf) Cf[o] = val;
                    if (Ch) {
                        f16 hv = (f16)val;
                        Ch[o] = hv;
                        if (Cl) Cl[o] = (f16)(val - (float)hv);
                    }
                } else {
                    Cf[(size_t)m * DMm + n] = val;
                }
            }
}

// -------------------- K2: gate = sigmoid(x @ Wg) ------------------------------
__global__ __launch_bounds__(256) void k_gate(const float* __restrict__ x,
        const float* __restrict__ Wg, float* __restrict__ g)
{
    int row = blockIdx.x * 256 + threadIdx.x;   // 0 .. 8191
    if (row >= Bb * Ss) return;
    const float* xr = x + (size_t)row * DMm;
    float a0 = 0.f, a1 = 0.f, a2 = 0.f;
    for (int d = 0; d < DMm; ++d) {
        float xv = xr[d];
        a0 += xv * Wg[d * 3 + 0];
        a1 += xv * Wg[d * 3 + 1];
        a2 += xv * Wg[d * 3 + 2];
    }
    g[(size_t)row * 3 + 0] = 1.f / (1.f + expf(-a0));
    g[(size_t)row * 3 + 1] = 1.f / (1.f + expf(-a1));
    g[(size_t)row * 3 + 2] = 1.f / (1.f + expf(-a2));
}

// -------------------- K2c: fp32 v [bh][s][d] -> f16 vt [bh][d][s] -------------
__global__ __launch_bounds__(256) void k_cvt_vt(const float* __restrict__ v,
        f16* __restrict__ vt)
{
    const int s0 = blockIdx.x * 64;
    const int bh = blockIdx.y;
    __shared__ _Float16 tile[64][72];
    const int tid = threadIdx.x;
    const int r = tid >> 4;            // 0..15
    const int d0 = (tid & 15) * 4;
#pragma unroll
    for (int p = 0; p < 4; ++p) {
        int rr = r + p * 16;
        float4 t4 = *(const float4*)(v + ((size_t)bh * Ss + s0 + rr) * HDd + d0);
        tile[d0 + 0][rr] = (_Float16)t4.x;
        tile[d0 + 1][rr] = (_Float16)t4.y;
        tile[d0 + 2][rr] = (_Float16)t4.z;
        tile[d0 + 3][rr] = (_Float16)t4.w;
    }
    __syncthreads();
    const int d = tid >> 2;
    const int c0 = (tid & 3) * 16;
    f16* dst = vt + ((size_t)bh * HDd + d) * Ss + s0 + c0;
    *(f16x8*)(dst)     = *(const f16x8*)&tile[d][c0];
    *(f16x8*)(dst + 8) = *(const f16x8*)&tile[d][c0 + 8];
}

// -------------------- K3: mean-pool k,v -> f16 kc_hi/kc_lo [n][d], vc^T [d][n] -
__global__ __launch_bounds__(256) void k_pool(const float* __restrict__ kk,
        const float* __restrict__ vv, f16* __restrict__ kch,
        f16* __restrict__ kcl, f16* __restrict__ vct)
{
    int idx = blockIdx.x * 256 + threadIdx.x;  // B*H*NC*HD = 131072
    int d = idx & 63;
    int n = (idx >> 6) & 127;
    int bh = idx >> 13;
    const float* kp = kk + ((size_t)bh * Ss + n * CBc) * HDd + d;
    const float* vp = vv + ((size_t)bh * Ss + n * CBc) * HDd + d;
    float sk = 0.f, sv = 0.f;
    for (int t = 0; t < CBc; ++t) { sk += kp[(size_t)t * HDd]; sv += vp[(size_t)t * HDd]; }
    float mk = sk * (1.f / CBc);
    float mv = sv * (1.f / CBc);
    f16 h = (f16)mk;
    kch[idx] = h;
    kcl[idx] = (f16)(mk - (float)h);
    vct[((size_t)bh * HDd + d) * NCc + n] = (f16)mv;
}

// -------------------- K4: compressed attention + importance (split-f16 MFMA) --
// Scores: split-f16 MFMA (fp32-grade -> selection-safe). Softmax + importance:
// exact fp32 from LDS Pm. PV: plain f16 MFMA on normalized probs.
__global__ __launch_bounds__(256) void k_cmp(const f16* __restrict__ qh,
        const f16* __restrict__ ql, const f16* __restrict__ kch,
        const f16* __restrict__ kcl, const f16* __restrict__ vct,
        const float* __restrict__ g, float* __restrict__ impb, float* __restrict__ o)
{
    const int qb = blockIdx.x;   // 0..63
    const int bh = blockIdx.y;   // 0..15
    const int b = bh >> 3, h = bh & 7;
    const int q0 = qb * 64;
    const int tid = threadIdx.x;
    const int w = tid >> 6, l = tid & 63;
    const int lr = l & 15, lg = l >> 4;

    __shared__ __align__(16) char smem[51200];
    float* Pm = (float*)smem;                       // [64][132] fp32 scores/probs
    char* U = smem + 33792;                         // 16KB union: {KCh,KCl} / {VCt,Ps}
    float* red2 = (float*)(smem + 33792 + 16384);   // 256 floats

    const int NCT = (qb <= 30) ? 1 : 2;
    const int ncols = NCT * 64;

    // q fragments hi/lo (registers)
    f16x8 qfh0, qfh1, qfl0, qfl1;
    {
        size_t qoff = ((size_t)bh * Ss + q0 + w * 16 + lr) * HDd + lg * 8;
        qfh0 = *(const f16x8*)(qh + qoff);
        qfh1 = *(const f16x8*)(qh + qoff + 32);
        qfl0 = *(const f16x8*)(ql + qoff);
        qfl1 = *(const f16x8*)(ql + qoff + 32);
    }

    // ---- scores: split-f16 MFMA per chunk-tile ------------------------------
    for (int ct = 0; ct < NCT; ++ct) {
        __syncthreads();
#pragma unroll
        for (int p = 0; p < 2; ++p) {
            int idx = tid + p * 256;
            int row = idx >> 3;           // chunk 0..63
            int c8 = idx & 7;
            size_t src = ((size_t)bh * NCc + ct * 64 + row) * HDd + c8 * 8;
            *(f16x8*)(U + swz(row, row * 128 + c8 * 16)) = *(const f16x8*)(kch + src);
            *(f16x8*)(U + 8192 + swz(row, row * 128 + c8 * 16)) = *(const f16x8*)(kcl + src);
        }
        __syncthreads();
#pragma unroll
        for (int kt = 0; kt < 4; ++kt) {
            int krow = kt * 16 + lr;
            f16x8 bh0 = *(const f16x8*)(U + swz(krow, krow * 128 + lg * 16));
            f16x8 bh1 = *(const f16x8*)(U + swz(krow, krow * 128 + lg * 16 + 64));
            f16x8 bl0 = *(const f16x8*)(U + 8192 + swz(krow, krow * 128 + lg * 16));
            f16x8 bl1 = *(const f16x8*)(U + 8192 + swz(krow, krow * 128 + lg * 16 + 64));
            f32x4 c = (f32x4){0.f, 0.f, 0.f, 0.f};
            c = __builtin_amdgcn_mfma_f32_16x16x32_f16(qfh0, bh0, c, 0, 0, 0);
            c = __builtin_amdgcn_mfma_f32_16x16x32_f16(qfh1, bh1, c, 0, 0, 0);
            c = __builtin_amdgcn_mfma_f32_16x16x32_f16(qfh0, bl0, c, 0, 0, 0);
            c = __builtin_amdgcn_mfma_f32_16x16x32_f16(qfh1, bl1, c, 0, 0, 0);
            c = __builtin_amdgcn_mfma_f32_16x16x32_f16(qfl0, bh0, c, 0, 0, 0);
            c = __builtin_amdgcn_mfma_f32_16x16x32_f16(qfl1, bh1, c, 0, 0, 0);
            int n = ct * 64 + kt * 16 + lr;
#pragma unroll
            for (int rg = 0; rg < 4; ++rg) {
                int row = w * 16 + 4 * lg + rg;
                int s = q0 + row;
                bool valid = (32 * n + 31 <= s);
                Pm[row * 132 + n] = valid ? c[rg] * SCALE : NEGF;
            }
        }
    }
    __syncthreads();

    // ---- softmax: 4 lanes per row, exact fp32, normalized in place ----------
    {
        int r = tid >> 2;
        int l4 = tid & 3;
        float m = NEGF;
        for (int c = l4; c < ncols; c += 4) m = fmaxf(m, Pm[r * 132 + c]);
        m = fmaxf(m, __shfl_xor(m, 1));
        m = fmaxf(m, __shfl_xor(m, 2));
        float sum = 0.f;
        if (m > NEGF * 0.5f) {
            for (int c = l4; c < ncols; c += 4) {
                float sv = Pm[r * 132 + c];
                float p = (sv <= NEGF * 0.5f) ? 0.f : __expf(sv - m);
                Pm[r * 132 + c] = p;
                sum += p;
            }
        } else {
            for (int c = l4; c < ncols; c += 4) Pm[r * 132 + c] = 0.f;
        }
        sum += __shfl_xor(sum, 1);
        sum += __shfl_xor(sum, 2);
        float inv = (sum > 0.f) ? 1.f / sum : 0.f;
        for (int c = l4; c < ncols; c += 4) Pm[r * 132 + c] *= inv;
    }
    __syncthreads();

    // ---- importance: block-local reduction, direct store --------------------
    {
        float part = 0.f;
#pragma unroll
        for (int rr = 0; rr < 16; ++rr) {
            int qq = w * 16 + rr;
            int c = 2 * l;
            if (c < ncols) {
                float2 pv2 = *(const float2*)&Pm[qq * 132 + c];
                part += pv2.x + pv2.y;
            }
        }
        red2[w * 64 + l] = part;
    }
    __syncthreads();
    if (tid < 64) {
        float tot = red2[tid] + red2[64 + tid] + red2[128 + tid] + red2[192 + tid];
        impb[((size_t)bh * NSs + qb) * NSs + tid] = tot;
    }

    // ---- PV: plain f16 MFMA on normalized probs -----------------------------
    f32x4 oacc[4];
#pragma unroll
    for (int dt = 0; dt < 4; ++dt) oacc[dt] = (f32x4){0.f, 0.f, 0.f, 0.f};
    char* Ps = U + 8192 + w * 2048;   // per-wave P tile [16][64] f16 swizzled
    for (int ct = 0; ct < NCT; ++ct) {
        __syncthreads();   // prior U/Ps readers done
#pragma unroll
        for (int p = 0; p < 2; ++p) {
            int idx = tid + p * 256;
            int row = idx >> 3;           // d 0..63
            int c8 = idx & 7;
            size_t src = ((size_t)bh * HDd + row) * NCc + ct * 64 + c8 * 8;
            *(f16x8*)(U + swz(row, row * 128 + c8 * 16)) = *(const f16x8*)(vct + src);
        }
        {
            int r = l >> 2;
            int c0 = (l & 3) * 16;
            const float* pr = &Pm[(w * 16 + r) * 132 + ct * 64 + c0];
            float4 p0 = *(const float4*)(pr);
            float4 p1 = *(const float4*)(pr + 4);
            float4 p2 = *(const float4*)(pr + 8);
            float4 p3 = *(const float4*)(pr + 12);
            f16x8 h0, h1;
            h0[0] = (_Float16)p0.x; h0[1] = (_Float16)p0.y; h0[2] = (_Float16)p0.z; h0[3] = (_Float16)p0.w;
            h0[4] = (_Float16)p1.x; h0[5] = (_Float16)p1.y; h0[6] = (_Float16)p1.z; h0[7] = (_Float16)p1.w;
            h1[0] = (_Float16)p2.x; h1[1] = (_Float16)p2.y; h1[2] = (_Float16)p2.z; h1[3] = (_Float16)p2.w;
            h1[4] = (_Float16)p3.x; h1[5] = (_Float16)p3.y; h1[6] = (_Float16)p3.z; h1[7] = (_Float16)p3.w;
            *(f16x8*)(Ps + swz(r, r * 128 + c0 * 2)) = h0;
            *(f16x8*)(Ps + swz(r, r * 128 + c0 * 2 + 16)) = h1;
        }
        __syncthreads();
        f16x8 pa0 = *(const f16x8*)(Ps + swz(lr, lr * 128 + lg * 16));
        f16x8 pa1 = *(const f16x8*)(Ps + swz(lr, lr * 128 + lg * 16 + 64));
#pragma unroll
        for (int dt = 0; dt < 4; ++dt) {
            int vrow = dt * 16 + lr;
            f16x8 vb0 = *(const f16x8*)(U + swz(vrow, vrow * 128 + lg * 16));
            f16x8 vb1 = *(const f16x8*)(U + swz(vrow, vrow * 128 + lg * 16 + 64));
            oacc[dt] = __builtin_amdgcn_mfma_f32_16x16x32_f16(pa0, vb0, oacc[dt], 0, 0, 0);
            oacc[dt] = __builtin_amdgcn_mfma_f32_16x16x32_f16(pa1, vb1, oacc[dt], 0, 0, 0);
        }
    }

    // ---- output: o = g0 * out_c (probs pre-normalized; first writer of o) ---
#pragma unroll
    for (int rg = 0; rg < 4; ++rg) {
        int row = w * 16 + 4 * lg + rg;
        int s = q0 + row;
        float g0 = g[((size_t)(b * Ss + s)) * 3 + 0];
#pragma unroll
        for (int dt = 0; dt < 4; ++dt)
            o[((size_t)(b * Ss + s)) * DMm + h * HDd + dt * 16 + lr] = g0 * oacc[dt][rg];
    }
}

// -------------------- K5: top-k selection -------------------------------------
__global__ __launch_bounds__(256) void k_topk(const float* __restrict__ impb,
        int* __restrict__ sel)
{
    int row = blockIdx.x * 256 + threadIdx.x;  // B*H*NS = 1024 rows
    if (row >= Bb * Hh * NSs) return;
    int qb = row & 63;
    float v[64];
    for (int j = 0; j < 64; ++j) {
        float t = impb[(size_t)row * 64 + j];
        if (j > qb) t = NEGF;
        if (j == qb) t += 1e9f;
        v[j] = t;
    }
    for (int t = 0; t < TOPKk; ++t) {
        int bi = 0; float bv = v[0];
        for (int j = 1; j < 64; ++j) {
            if (v[j] > bv) { bv = v[j]; bi = j; }
        }
        sel[(size_t)row * TOPKk + t] = bi;
        v[bi] = -3e38f;
    }
}

// -------------------- K6: MFMA attention, 64-query tiles ----------------------
template <int MODE>
__global__ __launch_bounds__(256) void k_attn(const f16* __restrict__ qh,
        const f16* __restrict__ kh, const f16* __restrict__ vt,
        const int* __restrict__ sel, const float* __restrict__ g,
        float* __restrict__ o)
{
    const int qb = blockIdx.x;    // 0..63
    const int bh = blockIdx.y;
    const int b = bh >> 3, h = bh & 7;
    const int q0 = qb * 64;
    const int tid = threadIdx.x;
    const int w  = tid >> 6;      // wave 0..3
    const int l  = tid & 63;
    const int lr = l & 15;
    const int lg = l >> 4;

    __shared__ __align__(16) char smem[24576];
    char* Ks_base = smem;                         // K tile, swizzled
    char* Vs_base = smem + 8192;                  // V^T tile, swizzled
    char* Ps_base = smem + 16384 + w * 2048;      // per-wave P tile

    f16x8 qf0, qf1;
    {
        const f16* qptr = qh + ((size_t)bh * Ss + q0 + w * 16 + lr) * HDd + lg * 8;
        qf0 = *(const f16x8*)(qptr);
        qf1 = *(const f16x8*)(qptr + 32);
    }

    float m_r[4], l_r[4];
    f32x4 oacc[4];
#pragma unroll
    for (int rg = 0; rg < 4; ++rg) { m_r[rg] = NEGF; l_r[rg] = 0.f; }
#pragma unroll
    for (int dt = 0; dt < 4; ++dt) oacc[dt] = (f32x4){0.f, 0.f, 0.f, 0.f};

    const int NT = (MODE == 0) ? TOPKk : 9;
    for (int t = 0; t < NT; ++t) {
        int kb;
        if (MODE == 0) kb = sel[((size_t)bh * NSs + qb) * TOPKk + t];
        else { kb = qb - 8 + t; if (kb < 0) continue; }   // block-uniform
        const int kbase = kb * 64;

#pragma unroll
        for (int p = 0; p < 2; ++p) {
            int idx = tid + p * 256;      // 0..511
            int row = idx >> 3;           // 0..63
            int c8  = idx & 7;            // 8-half column block
            f16x8 kd = *(const f16x8*)(kh + ((size_t)bh * Ss + kbase + row) * HDd + c8 * 8);
            *(f16x8*)(Ks_base + swz(row, row * 128 + c8 * 16)) = kd;
            f16x8 vd = *(const f16x8*)(vt + ((size_t)bh * HDd + row) * Ss + kbase + c8 * 8);
            *(f16x8*)(Vs_base + swz(row, row * 128 + c8 * 16)) = vd;
        }
        __syncthreads();

        float sv[4][4];   // [kt][reg]
#pragma unroll
        for (int kt = 0; kt < 4; ++kt) {
            int krow = kt * 16 + lr;
            f16x8 kb0 = *(const f16x8*)(Ks_base + swz(krow, krow * 128 + lg * 16));
            f16x8 kb1 = *(const f16x8*)(Ks_base + swz(krow, krow * 128 + lg * 16 + 64));
            f32x4 c = (f32x4){0.f, 0.f, 0.f, 0.f};
            c = __builtin_amdgcn_mfma_f32_16x16x32_f16(qf0, kb0, c, 0, 0, 0);
            c = __builtin_amdgcn_mfma_f32_16x16x32_f16(qf1, kb1, c, 0, 0, 0);
            int kpos = kbase + kt * 16 + lr;
#pragma unroll
            for (int rg = 0; rg < 4; ++rg) {
                int qpos = q0 + w * 16 + 4 * lg + rg;
                bool valid = (kpos <= qpos);
                if (MODE == 1) valid = valid && (kpos > qpos - WINSZ);
                sv[kt][rg] = valid ? c[rg] * SCALE : NEGF;
            }
        }

        float al[4], rs[4];
#pragma unroll
        for (int rg = 0; rg < 4; ++rg) {
            float m = fmaxf(fmaxf(sv[0][rg], sv[1][rg]), fmaxf(sv[2][rg], sv[3][rg]));
            m = fmaxf(m, __shfl_xor(m, 1));
            m = fmaxf(m, __shfl_xor(m, 2));
            m = fmaxf(m, __shfl_xor(m, 4));
            m = fmaxf(m, __shfl_xor(m, 8));
            float mn = fmaxf(m_r[rg], m);
            al[rg] = __expf(m_r[rg] - mn);
            m_r[rg] = mn;
            rs[rg] = 0.f;
        }
#pragma unroll
        for (int kt = 0; kt < 4; ++kt) {
#pragma unroll
            for (int rg = 0; rg < 4; ++rg) {
                float p = __expf(sv[kt][rg] - m_r[rg]);
                rs[rg] += p;
                int prow = 4 * lg + rg;
                *(f16*)(Ps_base + swz(prow, prow * 128 + (kt * 16 + lr) * 2)) = (_Float16)p;
            }
        }
#pragma unroll
        for (int rg = 0; rg < 4; ++rg) {
            float s = rs[rg];
            s += __shfl_xor(s, 1);
            s += __shfl_xor(s, 2);
            s += __shfl_xor(s, 4);
            s += __shfl_xor(s, 8);
            l_r[rg] = l_r[rg] * al[rg] + s;
#pragma unroll
            for (int dt = 0; dt < 4; ++dt) oacc[dt][rg] *= al[rg];
        }

        f16x8 pa0 = *(const f16x8*)(Ps_base + swz(lr, lr * 128 + lg * 16));
        f16x8 pa1 = *(const f16x8*)(Ps_base + swz(lr, lr * 128 + lg * 16 + 64));
#pragma unroll
        for (int dt = 0; dt < 4; ++dt) {
            int vrow = dt * 16 + lr;
            f16x8 vb0 = *(const f16x8*)(Vs_base + swz(vrow, vrow * 128 + lg * 16));
            f16x8 vb1 = *(const f16x8*)(Vs_base + swz(vrow, vrow * 128 + lg * 16 + 64));
            oacc[dt] = __builtin_amdgcn_mfma_f32_16x16x32_f16(pa0, vb0, oacc[dt], 0, 0, 0);
            oacc[dt] = __builtin_amdgcn_mfma_f32_16x16x32_f16(pa1, vb1, oacc[dt], 0, 0, 0);
        }
        __syncthreads();
    }

    float* Os = (float*)smem;
    float inv[4];
#pragma unroll
    for (int rg = 0; rg < 4; ++rg) inv[rg] = 1.f / l_r[rg];
#pragma unroll
    for (int dt = 0; dt < 4; ++dt) {
#pragma unroll
        for (int rg = 0; rg < 4; ++rg) {
            int row = w * 16 + 4 * lg + rg;
            Os[row * 68 + dt * 16 + lr] = oacc[dt][rg] * inv[rg];
        }
    }
    __syncthreads();
    {
        int row = tid >> 2;
        int c0 = (tid & 3) * 16;
        int s = q0 + row;
        float gv = g[((size_t)(b * Ss + s)) * 3 + ((MODE == 0) ? 1 : 2)];
        float* op = o + ((size_t)(b * Ss + s)) * DMm + h * HDd + c0;
#pragma unroll
        for (int j = 0; j < 4; ++j) {
            float4 val = *(const float4*)&Os[row * 68 + c0 + j * 4];
            float4 cur = *(const float4*)&op[j * 4];
            cur.x += val.x * gv; cur.y += val.y * gv;
            cur.z += val.z * gv; cur.w += val.w * gv;
            *(float4*)&op[j * 4] = cur;
        }
    }
}

// -------------------- constant emitter (host-side contract checks) ------------
__global__ __launch_bounds__(256) void k_const(float* __restrict__ y, float val)
{
    int i = blockIdx.x * 256 + threadIdx.x;
    y[i] = val;
}

// -------------------- launch --------------------------------------------------
extern "C" void kernel_launch(void* const* d_in, const int* in_sizes, int n_in,
                              void* d_out, int out_size, void* d_ws, size_t ws_size,
                              hipStream_t stream) {
    float* y = (float*)d_out;
    if (n_in != 6) {
        k_const<<<dim3(16384), 256, 0, stream>>>(y, 88888.f);
        return;
    }
    if (in_sizes[0] != 4194304 || in_sizes[1] != 262144 || in_sizes[2] != 262144 ||
        in_sizes[3] != 262144 || in_sizes[4] != 262144 || in_sizes[5] != 1536) {
        k_const<<<dim3(16384), 256, 0, stream>>>(y, 77777.f);
        return;
    }
    if (ws_size < WS_FLOATS * sizeof(float)) {
        k_const<<<dim3(16384), 256, 0, stream>>>(y, 66666.f);
        return;
    }

    const float* x  = (const float*)d_in[0];
    const float* Wq = (const float*)d_in[1];
    const float* Wk = (const float*)d_in[2];
    const float* Wv = (const float*)d_in[3];
    const float* Wo = (const float*)d_in[4];
    const float* Wg = (const float*)d_in[5];
    float* ws = (float*)d_ws;

    float* kw   = ws + OFF_K;
    float* vw   = ws + OFF_V;
    float* ow   = ws + OFF_O;
    float* gw   = ws + OFF_G;
    float* impw = ws + OFF_IMPB;
    int*   selw = (int*)(ws + OFF_SEL);
    f16*   qhw  = (f16*)(ws + OFF_QH);
    f16*   qlw  = (f16*)(ws + OFF_QL);
    f16*   khw  = (f16*)(ws + OFF_KH);
    f16*   vtw  = (f16*)(ws + OFF_VT);
    f16*   kchw = (f16*)(ws + OFF_KCH);
    f16*   kclw = (f16*)(ws + OFF_KCL);
    f16*   vctw = (f16*)(ws + OFF_VCT);
    f16*   xhw  = (f16*)(ws + OFF_XH);   // aliases o region (freed before k_cmp)
    f16*   xlw  = (f16*)(ws + OFF_XL);
    f16*   wqh  = (f16*)(ws + OFF_WT);
    f16*   wql  = (f16*)(ws + OFF_WT + 131072);
    f16*   wkh  = (f16*)(ws + OFF_WT + 262144);
    f16*   wkl  = (f16*)(ws + OFF_WT + 393216);
    f16*   wvh  = (f16*)(ws + OFF_WT + 524288);
    f16*   wvl  = (f16*)(ws + OFF_WT + 655360);
    f16*   woh  = (f16*)(ws + OFF_WT + 786432);

    k_prep_x<<<dim3(2048), 256, 0, stream>>>(x, xhw, xlw);
    k_prep_w<<<dim3(8, 8, 4), 256, 0, stream>>>(Wq, Wk, Wv, Wo,
            wqh, wql, wkh, wkl, wvh, wvl, woh);
    // q: split GEMM -> f16 hi/lo only (fp32 q no longer needed anywhere)
    k_gemm<1, 0, 0><<<dim3(64, 8), 256, 0, stream>>>(xhw, xlw, (const float*)0,
            wqh, wql, (float*)0, qhw, qlw);
    // k: split GEMM -> fp32 (for pooling) + f16 hi
    k_gemm<1, 0, 0><<<dim3(64, 8), 256, 0, stream>>>(xhw, xlw, (const float*)0,
            wkh, wkl, kw, khw, (f16*)0);
    // v: split GEMM -> fp32 (for pooling / vt)
    k_gemm<1, 0, 0><<<dim3(64, 8), 256, 0, stream>>>(xhw, xlw, (const float*)0,
            wvh, wvl, vw, (f16*)0, (f16*)0);
    k_gate<<<dim3(32), 256, 0, stream>>>(x, Wg, gw);
    k_cvt_vt<<<dim3(64, 16), 256, 0, stream>>>(vw, vtw);
    k_pool<<<dim3(512), 256, 0, stream>>>(kw, vw, kchw, kclw, vctw);
    k_cmp<<<dim3(64, 16), 256, 0, stream>>>(qhw, qlw, kchw, kclw, vctw, gw, impw, ow);
    k_topk<<<dim3(4), 256, 0, stream>>>(impw, selw);
    k_attn<0><<<dim3(64, 16), 256, 0, stream>>>(qhw, khw, vtw, selw, gw, ow);
    k_attn<1><<<dim3(64, 16), 256, 0, stream>>>(qhw, khw, vtw, selw, gw, ow);
    // out projection: plain f16 MFMA, A staged from fp32 o
    k_gemm<0, 1, 1><<<dim3(64, 8), 256, 0, stream>>>((const f16*)0, (const f16*)0,
            ow, woh, (const f16*)0, y, (f16*)0, (f16*)0);
}

// Round 5
// 364.572 us; speedup vs baseline: 3.9534x; 1.0389x over previous
//
#include <hip/hip_runtime.h>

// Problem constants
#define Hh    8
#define DMm   512
#define HDd   64
#define CBc   32
#define SBs   64
#define WINSZ 512
#define TOPKk 16
#define NEGF  (-1e30f)
#define Bb    2
#define Ss    4096
#define NCc   128   // S/CB
#define NSs   64    // S/SB
#define SCALE 0.125f

// Workspace layout (float offsets)
#define OFF_Q    ((size_t)0)          // (unused fp32 q region, kept for layout stability)
#define OFF_K    ((size_t)4194304)
#define OFF_V    ((size_t)8388608)
#define OFF_O    ((size_t)12582912)   // ALIASED: x_hi/x_lo live here until k_cmp writes o
#define OFF_G    ((size_t)16777216)   // B*S*3 = 24576
#define OFF_KC   ((size_t)16801792)   // kc_hi/kc_lo f16 (2 x 131072 halves)
#define OFF_VC   ((size_t)16932864)   // vc^T f16 (131072 halves)
#define OFF_IMPB ((size_t)17063936)   // B*H*NS*NS = 65536
#define OFF_SEL  ((size_t)17129472)   // B*H*NS*TOPK ints = 16384
#define OFF_QH   ((size_t)17145856)   // f16 q  [bh][s][d]
#define OFF_KH   ((size_t)19243008)   // f16 k  [bh][s][d]
#define OFF_VT   ((size_t)21340160)   // f16 v^T [bh][d][s]
#define OFF_WT   ((size_t)23437312)   // 7 x 131072 floats of f16 W^T (hi/lo)
#define OFF_QL   ((size_t)24354816)   // f16 q_lo [bh][s][d] : 2097152 halves
#define WS_FLOATS ((size_t)25403392)

// x_hi/x_lo alias the o region (o first written by k_cmp, after GEMMs)
#define OFF_XH   (OFF_O)
#define OFF_XL   (OFF_O + 2097152)

#define OFF_KCH  (OFF_KC)
#define OFF_KCL  (OFF_KC + 65536)
#define OFF_VCT  (OFF_VC)

typedef _Float16 f16;
typedef _Float16 f16x4 __attribute__((ext_vector_type(4)));
typedef _Float16 f16x8 __attribute__((ext_vector_type(8)));
typedef float    f32x4 __attribute__((ext_vector_type(4)));

__device__ __forceinline__ int swz(int row, int byteoff) {
    return byteoff ^ ((row & 7) << 4);   // spreads stride-128B rows across banks
}

// -------------------- K0a: x -> x_hi, x_lo (f16 split) ------------------------
__global__ __launch_bounds__(256) void k_prep_x(const float* __restrict__ x,
        f16* __restrict__ xh, f16* __restrict__ xl)
{
    size_t base = ((size_t)blockIdx.x * 256 + threadIdx.x) * 8;   // covers 4194304
    float4 a = *(const float4*)(x + base);
    float4 b = *(const float4*)(x + base + 4);
    f16x8 h, l;
    h[0] = (_Float16)a.x; l[0] = (_Float16)(a.x - (float)h[0]);
    h[1] = (_Float16)a.y; l[1] = (_Float16)(a.y - (float)h[1]);
    h[2] = (_Float16)a.z; l[2] = (_Float16)(a.z - (float)h[2]);
    h[3] = (_Float16)a.w; l[3] = (_Float16)(a.w - (float)h[3]);
    h[4] = (_Float16)b.x; l[4] = (_Float16)(b.x - (float)h[4]);
    h[5] = (_Float16)b.y; l[5] = (_Float16)(b.y - (float)h[5]);
    h[6] = (_Float16)b.z; l[6] = (_Float16)(b.z - (float)h[6]);
    h[7] = (_Float16)b.w; l[7] = (_Float16)(b.w - (float)h[7]);
    *(f16x8*)(xh + base) = h;
    *(f16x8*)(xl + base) = l;
}

// -------------------- K0b: W -> W^T hi/lo (f16) -------------------------------
__global__ __launch_bounds__(256) void k_prep_w(
        const float* __restrict__ Wq, const float* __restrict__ Wk,
        const float* __restrict__ Wv, const float* __restrict__ Wo,
        f16* __restrict__ wqh, f16* __restrict__ wql,
        f16* __restrict__ wkh, f16* __restrict__ wkl,
        f16* __restrict__ wvh, f16* __restrict__ wvl,
        f16* __restrict__ woh)
{
    const int k0 = blockIdx.x * 64;
    const int n0 = blockIdx.y * 64;
    const int z = blockIdx.z;
    const float* W = (z == 0) ? Wq : ((z == 1) ? Wk : ((z == 2) ? Wv : Wo));
    f16* dh = (z == 0) ? wqh : ((z == 1) ? wkh : ((z == 2) ? wvh : woh));
    f16* dl = (z == 0) ? wql : ((z == 1) ? wkl : ((z == 2) ? wvl : (f16*)0));
    __shared__ float T[64][68];
    const int tid = threadIdx.x;
    {
        int r = tid >> 2;
        int c16 = (tid & 3) * 16;
#pragma unroll
        for (int j = 0; j < 4; ++j) {
            float4 w4 = *(const float4*)(W + (size_t)(k0 + r) * DMm + n0 + c16 + j * 4);
            *(float4*)&T[r][c16 + j * 4] = w4;
        }
    }
    __syncthreads();
    {
        int n = tid >> 2;
        int k16 = (tid & 3) * 16;
        f16x8 h0, h1, l0, l1;
#pragma unroll
        for (int j = 0; j < 8; ++j) {
            float wv = T[k16 + j][n];
            h0[j] = (_Float16)wv; l0[j] = (_Float16)(wv - (float)h0[j]);
        }
#pragma unroll
        for (int j = 0; j < 8; ++j) {
            float wv = T[k16 + 8 + j][n];
            h1[j] = (_Float16)wv; l1[j] = (_Float16)(wv - (float)h1[j]);
        }
        size_t o = (size_t)(n0 + n) * DMm + k0 + k16;
        *(f16x8*)(dh + o) = h0;
        *(f16x8*)(dh + o + 8) = h1;
        if (dl) { *(f16x8*)(dl + o) = l0; *(f16x8*)(dl + o + 8) = l1; }
    }
}

// -------------------- K1: MFMA GEMM (128x64 tile, BK=32) ----------------------
template <int SPLIT, int AF32, int OUTM>
__global__ __launch_bounds__(256) void k_gemm(
        const f16* __restrict__ Ah, const f16* __restrict__ Al,
        const float* __restrict__ Af,
        const f16* __restrict__ Bh, const f16* __restrict__ Bl,
        float* __restrict__ Cf, f16* __restrict__ Ch, f16* __restrict__ Cl)
{
    const int m0 = blockIdx.x * 128;
    const int n0 = blockIdx.y * 64;
    const int tid = threadIdx.x;
    const int w = tid >> 6, l = tid & 63;
    const int lr = l & 15, lg = l >> 4;
    const int wm = w >> 1, wn = w & 1;

    __shared__ f16 As[SPLIT ? 2 : 1][128 * 40];
    __shared__ f16 Bs[SPLIT ? 2 : 1][64 * 40];

    f32x4 acc[4][2];
#pragma unroll
    for (int mf = 0; mf < 4; ++mf)
#pragma unroll
        for (int nf = 0; nf < 2; ++nf) acc[mf][nf] = (f32x4){0.f, 0.f, 0.f, 0.f};

    const int ar = tid >> 1, ac = (tid & 1) * 16;
    const int bn = tid >> 2, bc = (tid & 3) * 8;

    for (int k0 = 0; k0 < DMm; k0 += 32) {
        if (AF32) {
            const float* src = Af + (size_t)(m0 + ar) * DMm + k0 + ac;
            float4 a0 = *(const float4*)(src);
            float4 a1 = *(const float4*)(src + 4);
            float4 a2 = *(const float4*)(src + 8);
            float4 a3 = *(const float4*)(src + 12);
            f16x8 h0, h1;
            h0[0] = (_Float16)a0.x; h0[1] = (_Float16)a0.y; h0[2] = (_Float16)a0.z; h0[3] = (_Float16)a0.w;
            h0[4] = (_Float16)a1.x; h0[5] = (_Float16)a1.y; h0[6] = (_Float16)a1.z; h0[7] = (_Float16)a1.w;
            h1[0] = (_Float16)a2.x; h1[1] = (_Float16)a2.y; h1[2] = (_Float16)a2.z; h1[3] = (_Float16)a2.w;
            h1[4] = (_Float16)a3.x; h1[5] = (_Float16)a3.y; h1[6] = (_Float16)a3.z; h1[7] = (_Float16)a3.w;
            *(f16x8*)&As[0][ar * 40 + ac] = h0;
            *(f16x8*)&As[0][ar * 40 + ac + 8] = h1;
        } else {
            const f16* src = Ah + (size_t)(m0 + ar) * DMm + k0 + ac;
            *(f16x8*)&As[0][ar * 40 + ac] = *(const f16x8*)src;
            *(f16x8*)&As[0][ar * 40 + ac + 8] = *(const f16x8*)(src + 8);
            if (SPLIT) {
                const f16* src2 = Al + (size_t)(m0 + ar) * DMm + k0 + ac;
                *(f16x8*)&As[SPLIT ? 1 : 0][ar * 40 + ac] = *(const f16x8*)src2;
                *(f16x8*)&As[SPLIT ? 1 : 0][ar * 40 + ac + 8] = *(const f16x8*)(src2 + 8);
            }
        }
        {
            const f16* src = Bh + (size_t)(n0 + bn) * DMm + k0 + bc;
            *(f16x8*)&Bs[0][bn * 40 + bc] = *(const f16x8*)src;
            if (SPLIT) {
                const f16* src2 = Bl + (size_t)(n0 + bn) * DMm + k0 + bc;
                *(f16x8*)&Bs[SPLIT ? 1 : 0][bn * 40 + bc] = *(const f16x8*)src2;
            }
        }
        __syncthreads();

        f16x8 ahf[4], alf[4], bhf[2], blf[2];
#pragma unroll
        for (int mf = 0; mf < 4; ++mf) {
            int row = wm * 64 + mf * 16 + lr;
            ahf[mf] = *(const f16x8*)&As[0][row * 40 + lg * 8];
            if (SPLIT) alf[mf] = *(const f16x8*)&As[SPLIT ? 1 : 0][row * 40 + lg * 8];
        }
#pragma unroll
        for (int nf = 0; nf < 2; ++nf) {
            int row = wn * 32 + nf * 16 + lr;
            bhf[nf] = *(const f16x8*)&Bs[0][row * 40 + lg * 8];
            if (SPLIT) blf[nf] = *(const f16x8*)&Bs[SPLIT ? 1 : 0][row * 40 + lg * 8];
        }
#pragma unroll
        for (int mf = 0; mf < 4; ++mf)
#pragma unroll
            for (int nf = 0; nf < 2; ++nf) {
                acc[mf][nf] = __builtin_amdgcn_mfma_f32_16x16x32_f16(ahf[mf], bhf[nf], acc[mf][nf], 0, 0, 0);
                if (SPLIT) {
                    acc[mf][nf] = __builtin_amdgcn_mfma_f32_16x16x32_f16(ahf[mf], blf[nf], acc[mf][nf], 0, 0, 0);
                    acc[mf][nf] = __builtin_amdgcn_mfma_f32_16x16x32_f16(alf[mf], bhf[nf], acc[mf][nf], 0, 0, 0);
                }
            }
        __syncthreads();
    }

#pragma unroll
    for (int mf = 0; mf < 4; ++mf)
#pragma unroll
        for (int nf = 0; nf < 2; ++nf)
#pragma unroll
            for (int rg = 0; rg < 4; ++rg) {
                int m = m0 + wm * 64 + mf * 16 + 4 * lg + rg;
                int n = n0 + wn * 32 + nf * 16 + lr;
                float val = acc[mf][nf][rg];
                if (OUTM == 0) {
                    int b = m >> 12, s = m & 4095;
                    int h = n >> 6, d = n & 63;
                    size_t o = (((size_t)(b * Hh + h)) * Ss + s) * HDd + d;
                    if (Cf) Cf[o] = val;
                    if (Ch) {
                        f16 hv = (f16)val;
                        Ch[o] = hv;
                        if (Cl) Cl[o] = (f16)(val - (float)hv);
                    }
                } else {
                    Cf[(size_t)m * DMm + n] = val;
                }
            }
}

// -------------------- K2: gate = sigmoid(x @ Wg) ------------------------------
__global__ __launch_bounds__(256) void k_gate(const float* __restrict__ x,
        const float* __restrict__ Wg, float* __restrict__ g)
{
    int row = blockIdx.x * 256 + threadIdx.x;   // 0 .. 8191
    if (row >= Bb * Ss) return;
    const float* xr = x + (size_t)row * DMm;
    float a0 = 0.f, a1 = 0.f, a2 = 0.f;
    for (int d = 0; d < DMm; ++d) {
        float xv = xr[d];
        a0 += xv * Wg[d * 3 + 0];
        a1 += xv * Wg[d * 3 + 1];
        a2 += xv * Wg[d * 3 + 2];
    }
    g[(size_t)row * 3 + 0] = 1.f / (1.f + expf(-a0));
    g[(size_t)row * 3 + 1] = 1.f / (1.f + expf(-a1));
    g[(size_t)row * 3 + 2] = 1.f / (1.f + expf(-a2));
}

// -------------------- K2c: fp32 v [bh][s][d] -> f16 vt [bh][d][s] -------------
__global__ __launch_bounds__(256) void k_cvt_vt(const float* __restrict__ v,
        f16* __restrict__ vt)
{
    const int s0 = blockIdx.x * 64;
    const int bh = blockIdx.y;
    __shared__ _Float16 tile[64][72];
    const int tid = threadIdx.x;
    const int r = tid >> 4;            // 0..15
    const int d0 = (tid & 15) * 4;
#pragma unroll
    for (int p = 0; p < 4; ++p) {
        int rr = r + p * 16;
        float4 t4 = *(const float4*)(v + ((size_t)bh * Ss + s0 + rr) * HDd + d0);
        tile[d0 + 0][rr] = (_Float16)t4.x;
        tile[d0 + 1][rr] = (_Float16)t4.y;
        tile[d0 + 2][rr] = (_Float16)t4.z;
        tile[d0 + 3][rr] = (_Float16)t4.w;
    }
    __syncthreads();
    const int d = tid >> 2;
    const int c0 = (tid & 3) * 16;
    f16* dst = vt + ((size_t)bh * HDd + d) * Ss + s0 + c0;
    *(f16x8*)(dst)     = *(const f16x8*)&tile[d][c0];
    *(f16x8*)(dst + 8) = *(const f16x8*)&tile[d][c0 + 8];
}

// -------------------- K3: mean-pool k,v -> f16 kc_hi/kc_lo [n][d], vc^T [d][n] -
__global__ __launch_bounds__(256) void k_pool(const float* __restrict__ kk,
        const float* __restrict__ vv, f16* __restrict__ kch,
        f16* __restrict__ kcl, f16* __restrict__ vct)
{
    int idx = blockIdx.x * 256 + threadIdx.x;  // B*H*NC*HD = 131072
    int d = idx & 63;
    int n = (idx >> 6) & 127;
    int bh = idx >> 13;
    const float* kp = kk + ((size_t)bh * Ss + n * CBc) * HDd + d;
    const float* vp = vv + ((size_t)bh * Ss + n * CBc) * HDd + d;
    float sk = 0.f, sv = 0.f;
    for (int t = 0; t < CBc; ++t) { sk += kp[(size_t)t * HDd]; sv += vp[(size_t)t * HDd]; }
    float mk = sk * (1.f / CBc);
    float mv = sv * (1.f / CBc);
    f16 h = (f16)mk;
    kch[idx] = h;
    kcl[idx] = (f16)(mk - (float)h);
    vct[((size_t)bh * HDd + d) * NCc + n] = (f16)mv;
}

// -------------------- K4: compressed attention + importance (split-f16 MFMA) --
__global__ __launch_bounds__(256) void k_cmp(const f16* __restrict__ qh,
        const f16* __restrict__ ql, const f16* __restrict__ kch,
        const f16* __restrict__ kcl, const f16* __restrict__ vct,
        const float* __restrict__ g, float* __restrict__ impb, float* __restrict__ o)
{
    const int qb = blockIdx.x;   // 0..63
    const int bh = blockIdx.y;   // 0..15
    const int b = bh >> 3, h = bh & 7;
    const int q0 = qb * 64;
    const int tid = threadIdx.x;
    const int w = tid >> 6, l = tid & 63;
    const int lr = l & 15, lg = l >> 4;

    __shared__ __align__(16) char smem[51200];
    float* Pm = (float*)smem;                       // [64][132] fp32 scores/probs
    char* U = smem + 33792;                         // 16KB union: {KCh,KCl} / {VCt,Ps}
    float* red2 = (float*)(smem + 33792 + 16384);   // 256 floats

    const int NCT = (qb <= 30) ? 1 : 2;
    const int ncols = NCT * 64;

    f16x8 qfh0, qfh1, qfl0, qfl1;
    {
        size_t qoff = ((size_t)bh * Ss + q0 + w * 16 + lr) * HDd + lg * 8;
        qfh0 = *(const f16x8*)(qh + qoff);
        qfh1 = *(const f16x8*)(qh + qoff + 32);
        qfl0 = *(const f16x8*)(ql + qoff);
        qfl1 = *(const f16x8*)(ql + qoff + 32);
    }

    for (int ct = 0; ct < NCT; ++ct) {
        __syncthreads();
#pragma unroll
        for (int p = 0; p < 2; ++p) {
            int idx = tid + p * 256;
            int row = idx >> 3;           // chunk 0..63
            int c8 = idx & 7;
            size_t src = ((size_t)bh * NCc + ct * 64 + row) * HDd + c8 * 8;
            *(f16x8*)(U + swz(row, row * 128 + c8 * 16)) = *(const f16x8*)(kch + src);
            *(f16x8*)(U + 8192 + swz(row, row * 128 + c8 * 16)) = *(const f16x8*)(kcl + src);
        }
        __syncthreads();
#pragma unroll
        for (int kt = 0; kt < 4; ++kt) {
            int krow = kt * 16 + lr;
            f16x8 bh0 = *(const f16x8*)(U + swz(krow, krow * 128 + lg * 16));
            f16x8 bh1 = *(const f16x8*)(U + swz(krow, krow * 128 + lg * 16 + 64));
            f16x8 bl0 = *(const f16x8*)(U + 8192 + swz(krow, krow * 128 + lg * 16));
            f16x8 bl1 = *(const f16x8*)(U + 8192 + swz(krow, krow * 128 + lg * 16 + 64));
            f32x4 c = (f32x4){0.f, 0.f, 0.f, 0.f};
            c = __builtin_amdgcn_mfma_f32_16x16x32_f16(qfh0, bh0, c, 0, 0, 0);
            c = __builtin_amdgcn_mfma_f32_16x16x32_f16(qfh1, bh1, c, 0, 0, 0);
            c = __builtin_amdgcn_mfma_f32_16x16x32_f16(qfh0, bl0, c, 0, 0, 0);
            c = __builtin_amdgcn_mfma_f32_16x16x32_f16(qfh1, bl1, c, 0, 0, 0);
            c = __builtin_amdgcn_mfma_f32_16x16x32_f16(qfl0, bh0, c, 0, 0, 0);
            c = __builtin_amdgcn_mfma_f32_16x16x32_f16(qfl1, bh1, c, 0, 0, 0);
            int n = ct * 64 + kt * 16 + lr;
#pragma unroll
            for (int rg = 0; rg < 4; ++rg) {
                int row = w * 16 + 4 * lg + rg;
                int s = q0 + row;
                bool valid = (32 * n + 31 <= s);
                Pm[row * 132 + n] = valid ? c[rg] * SCALE : NEGF;
            }
        }
    }
    __syncthreads();

    {
        int r = tid >> 2;
        int l4 = tid & 3;
        float m = NEGF;
        for (int c = l4; c < ncols; c += 4) m = fmaxf(m, Pm[r * 132 + c]);
        m = fmaxf(m, __shfl_xor(m, 1));
        m = fmaxf(m, __shfl_xor(m, 2));
        float sum = 0.f;
        if (m > NEGF * 0.5f) {
            for (int c = l4; c < ncols; c += 4) {
                float sv = Pm[r * 132 + c];
                float p = (sv <= NEGF * 0.5f) ? 0.f : __expf(sv - m);
                Pm[r * 132 + c] = p;
                sum += p;
            }
        } else {
            for (int c = l4; c < ncols; c += 4) Pm[r * 132 + c] = 0.f;
        }
        sum += __shfl_xor(sum, 1);
        sum += __shfl_xor(sum, 2);
        float inv = (sum > 0.f) ? 1.f / sum : 0.f;
        for (int c = l4; c < ncols; c += 4) Pm[r * 132 + c] *= inv;
    }
    __syncthreads();

    {
        float part = 0.f;
#pragma unroll
        for (int rr = 0; rr < 16; ++rr) {
            int qq = w * 16 + rr;
            int c = 2 * l;
            if (c < ncols) {
                float2 pv2 = *(const float2*)&Pm[qq * 132 + c];
                part += pv2.x + pv2.y;
            }
        }
        red2[w * 64 + l] = part;
    }
    __syncthreads();
    if (tid < 64) {
        float tot = red2[tid] + red2[64 + tid] + red2[128 + tid] + red2[192 + tid];
        impb[((size_t)bh * NSs + qb) * NSs + tid] = tot;
    }

    f32x4 oacc[4];
#pragma unroll
    for (int dt = 0; dt < 4; ++dt) oacc[dt] = (f32x4){0.f, 0.f, 0.f, 0.f};
    char* Ps = U + 8192 + w * 2048;
    for (int ct = 0; ct < NCT; ++ct) {
        __syncthreads();
#pragma unroll
        for (int p = 0; p < 2; ++p) {
            int idx = tid + p * 256;
            int row = idx >> 3;           // d 0..63
            int c8 = idx & 7;
            size_t src = ((size_t)bh * HDd + row) * NCc + ct * 64 + c8 * 8;
            *(f16x8*)(U + swz(row, row * 128 + c8 * 16)) = *(const f16x8*)(vct + src);
        }
        {
            int r = l >> 2;
            int c0 = (l & 3) * 16;
            const float* pr = &Pm[(w * 16 + r) * 132 + ct * 64 + c0];
            float4 p0 = *(const float4*)(pr);
            float4 p1 = *(const float4*)(pr + 4);
            float4 p2 = *(const float4*)(pr + 8);
            float4 p3 = *(const float4*)(pr + 12);
            f16x8 h0, h1;
            h0[0] = (_Float16)p0.x; h0[1] = (_Float16)p0.y; h0[2] = (_Float16)p0.z; h0[3] = (_Float16)p0.w;
            h0[4] = (_Float16)p1.x; h0[5] = (_Float16)p1.y; h0[6] = (_Float16)p1.z; h0[7] = (_Float16)p1.w;
            h1[0] = (_Float16)p2.x; h1[1] = (_Float16)p2.y; h1[2] = (_Float16)p2.z; h1[3] = (_Float16)p2.w;
            h1[4] = (_Float16)p3.x; h1[5] = (_Float16)p3.y; h1[6] = (_Float16)p3.z; h1[7] = (_Float16)p3.w;
            *(f16x8*)(Ps + swz(r, r * 128 + c0 * 2)) = h0;
            *(f16x8*)(Ps + swz(r, r * 128 + c0 * 2 + 16)) = h1;
        }
        __syncthreads();
        f16x8 pa0 = *(const f16x8*)(Ps + swz(lr, lr * 128 + lg * 16));
        f16x8 pa1 = *(const f16x8*)(Ps + swz(lr, lr * 128 + lg * 16 + 64));
#pragma unroll
        for (int dt = 0; dt < 4; ++dt) {
            int vrow = dt * 16 + lr;
            f16x8 vb0 = *(const f16x8*)(U + swz(vrow, vrow * 128 + lg * 16));
            f16x8 vb1 = *(const f16x8*)(U + swz(vrow, vrow * 128 + lg * 16 + 64));
            oacc[dt] = __builtin_amdgcn_mfma_f32_16x16x32_f16(pa0, vb0, oacc[dt], 0, 0, 0);
            oacc[dt] = __builtin_amdgcn_mfma_f32_16x16x32_f16(pa1, vb1, oacc[dt], 0, 0, 0);
        }
    }

#pragma unroll
    for (int rg = 0; rg < 4; ++rg) {
        int row = w * 16 + 4 * lg + rg;
        int s = q0 + row;
        float g0 = g[((size_t)(b * Ss + s)) * 3 + 0];
#pragma unroll
        for (int dt = 0; dt < 4; ++dt)
            o[((size_t)(b * Ss + s)) * DMm + h * HDd + dt * 16 + lr] = g0 * oacc[dt][rg];
    }
}

// -------------------- K5: top-k selection -------------------------------------
__global__ __launch_bounds__(256) void k_topk(const float* __restrict__ impb,
        int* __restrict__ sel)
{
    int row = blockIdx.x * 256 + threadIdx.x;  // B*H*NS = 1024 rows
    if (row >= Bb * Hh * NSs) return;
    int qb = row & 63;
    float v[64];
    for (int j = 0; j < 64; ++j) {
        float t = impb[(size_t)row * 64 + j];
        if (j > qb) t = NEGF;
        if (j == qb) t += 1e9f;
        v[j] = t;
    }
    for (int t = 0; t < TOPKk; ++t) {
        int bi = 0; float bv = v[0];
        for (int j = 1; j < 64; ++j) {
            if (v[j] > bv) { bv = v[j]; bi = j; }
        }
        sel[(size_t)row * TOPKk + t] = bi;
        v[bi] = -3e38f;
    }
}

// -------------------- K6: merged MFMA attention (selected + window) -----------
// One block per (qb,bh). Phase A: 16 selected tiles; phase B: window tiles.
// C=0 softmax (shift-invariant; scores << fp32 exp range): p = exp(s), masked
// s = NEGF -> exp -> 0 exactly. Per-lane row-sums in registers, ONE 16-lane
// reduce per phase. K/V double-buffered in LDS with async reg-staged prefetch:
// one barrier per tile. Epilogue: o += g1*osel + g2*owin in a single RMW pass.
__global__ __launch_bounds__(256) void k_attn2(const f16* __restrict__ qh,
        const f16* __restrict__ kh, const f16* __restrict__ vt,
        const int* __restrict__ sel, const float* __restrict__ g,
        float* __restrict__ o)
{
    const int qb = blockIdx.x;    // 0..63
    const int bh = blockIdx.y;
    const int b = bh >> 3, h = bh & 7;
    const int q0 = qb * 64;
    const int tid = threadIdx.x;
    const int w  = tid >> 6;      // wave 0..3
    const int l  = tid & 63;
    const int lr = l & 15;
    const int lg = l >> 4;

    __shared__ __align__(16) char smem[40960];
    // K dbuf: [0,8K) [8K,16K); V dbuf: [16K,24K) [24K,32K); P: [32K,40K)
    char* Ps = smem + 32768 + w * 2048;

    // Q fragments (registers)
    f16x8 qf0, qf1;
    {
        const f16* qptr = qh + ((size_t)bh * Ss + q0 + w * 16 + lr) * HDd + lg * 8;
        qf0 = *(const f16x8*)(qptr);
        qf1 = *(const f16x8*)(qptr + 32);
    }

    const int W0 = (qb < 8) ? (8 - qb) : 0;
    const int NT = 25 - W0;             // 16 selected + (9-W0) window
    const int* selrow = sel + ((size_t)bh * NSs + qb) * TOPKk;

    float lsum[4];
    f32x4 oacc[4], osel[4];
#pragma unroll
    for (int rg = 0; rg < 4; ++rg) lsum[rg] = 0.f;
#pragma unroll
    for (int dt = 0; dt < 4; ++dt) {
        oacc[dt] = (f32x4){0.f, 0.f, 0.f, 0.f};
        osel[dt] = (f32x4){0.f, 0.f, 0.f, 0.f};
    }

    const int srow0 = tid >> 3, sc8 = tid & 7;         // staging unit p=0
    const int srow1 = (tid + 256) >> 3;                // staging unit p=1 (same c8)
    f16x8 pk0, pk1, pv0, pv1;

    // prologue: stage tile 0 into buf 0
    int kb_cur = selrow[0];
    {
        size_t kbase = (size_t)bh * Ss + kb_cur * 64;
        pk0 = *(const f16x8*)(kh + (kbase + srow0) * HDd + sc8 * 8);
        pk1 = *(const f16x8*)(kh + (kbase + srow1) * HDd + sc8 * 8);
        pv0 = *(const f16x8*)(vt + ((size_t)bh * HDd + srow0) * Ss + kb_cur * 64 + sc8 * 8);
        pv1 = *(const f16x8*)(vt + ((size_t)bh * HDd + srow1) * Ss + kb_cur * 64 + sc8 * 8);
        *(f16x8*)(smem + swz(srow0, srow0 * 128 + sc8 * 16)) = pk0;
        *(f16x8*)(smem + swz(srow1, srow1 * 128 + sc8 * 16)) = pk1;
        *(f16x8*)(smem + 16384 + swz(srow0, srow0 * 128 + sc8 * 16)) = pv0;
        *(f16x8*)(smem + 16384 + swz(srow1, srow1 * 128 + sc8 * 16)) = pv1;
    }
    __syncthreads();

    int cur = 0;
    for (int t = 0; t < NT; ++t) {
        // ---- prefetch issue (next tile -> regs) -----------------------------
        int kb_nxt = 0;
        const bool hasNext = (t + 1 < NT);
        if (hasNext) {
            kb_nxt = (t + 1 < 16) ? selrow[t + 1] : (qb - 8 + W0 + (t + 1 - 16));
            size_t kbase = (size_t)bh * Ss + kb_nxt * 64;
            pk0 = *(const f16x8*)(kh + (kbase + srow0) * HDd + sc8 * 8);
            pk1 = *(const f16x8*)(kh + (kbase + srow1) * HDd + sc8 * 8);
            pv0 = *(const f16x8*)(vt + ((size_t)bh * HDd + srow0) * Ss + kb_nxt * 64 + sc8 * 8);
            pv1 = *(const f16x8*)(vt + ((size_t)bh * HDd + srow1) * Ss + kb_nxt * 64 + sc8 * 8);
        }
        const char* Kc = smem + (cur ? 8192 : 0);
        const char* Vc = smem + 16384 + (cur ? 8192 : 0);
        const bool isw = (t >= 16);
        const int kbase = kb_cur * 64;

        // ---- QK^T -----------------------------------------------------------
        float sv[4][4];
#pragma unroll
        for (int kt = 0; kt < 4; ++kt) {
            int krow = kt * 16 + lr;
            f16x8 kb0 = *(const f16x8*)(Kc + swz(krow, krow * 128 + lg * 16));
            f16x8 kb1 = *(const f16x8*)(Kc + swz(krow, krow * 128 + lg * 16 + 64));
            f32x4 c = (f32x4){0.f, 0.f, 0.f, 0.f};
            c = __builtin_amdgcn_mfma_f32_16x16x32_f16(qf0, kb0, c, 0, 0, 0);
            c = __builtin_amdgcn_mfma_f32_16x16x32_f16(qf1, kb1, c, 0, 0, 0);
            int kpos = kbase + kt * 16 + lr;
#pragma unroll
            for (int rg = 0; rg < 4; ++rg) {
                int qpos = q0 + w * 16 + 4 * lg + rg;
                bool valid = (kpos <= qpos);
                if (isw) valid = valid && (kpos > qpos - WINSZ);
                sv[kt][rg] = valid ? c[rg] * SCALE : NEGF;
            }
        }

        // ---- softmax-lite: p = exp(s) (masked -> 0), lane-local row sums ----
#pragma unroll
        for (int kt = 0; kt < 4; ++kt) {
#pragma unroll
            for (int rg = 0; rg < 4; ++rg) {
                float p = __expf(sv[kt][rg]);
                lsum[rg] += p;
                int prow = 4 * lg + rg;
                *(f16*)(Ps + swz(prow, prow * 128 + (kt * 16 + lr) * 2)) = (_Float16)p;
            }
        }

        // ---- PV -------------------------------------------------------------
        f16x8 pa0 = *(const f16x8*)(Ps + swz(lr, lr * 128 + lg * 16));
        f16x8 pa1 = *(const f16x8*)(Ps + swz(lr, lr * 128 + lg * 16 + 64));
#pragma unroll
        for (int dt = 0; dt < 4; ++dt) {
            int vrow = dt * 16 + lr;
            f16x8 vb0 = *(const f16x8*)(Vc + swz(vrow, vrow * 128 + lg * 16));
            f16x8 vb1 = *(const f16x8*)(Vc + swz(vrow, vrow * 128 + lg * 16 + 64));
            oacc[dt] = __builtin_amdgcn_mfma_f32_16x16x32_f16(pa0, vb0, oacc[dt], 0, 0, 0);
            oacc[dt] = __builtin_amdgcn_mfma_f32_16x16x32_f16(pa1, vb1, oacc[dt], 0, 0, 0);
        }

        // ---- phase boundary: snapshot selected result, reset ----------------
        if (t == 15) {
#pragma unroll
            for (int rg = 0; rg < 4; ++rg) {
                float s = lsum[rg];
                s += __shfl_xor(s, 1);
                s += __shfl_xor(s, 2);
                s += __shfl_xor(s, 4);
                s += __shfl_xor(s, 8);
                float inv = 1.f / s;
#pragma unroll
                for (int dt = 0; dt < 4; ++dt) osel[dt][rg] = oacc[dt][rg] * inv;
                lsum[rg] = 0.f;
            }
#pragma unroll
            for (int dt = 0; dt < 4; ++dt) oacc[dt] = (f32x4){0.f, 0.f, 0.f, 0.f};
        }

        // ---- write prefetched tile into the other buffer --------------------
        if (hasNext) {
            char* Kn = smem + (cur ? 0 : 8192);
            char* Vn = smem + 16384 + (cur ? 0 : 8192);
            *(f16x8*)(Kn + swz(srow0, srow0 * 128 + sc8 * 16)) = pk0;
            *(f16x8*)(Kn + swz(srow1, srow1 * 128 + sc8 * 16)) = pk1;
            *(f16x8*)(Vn + swz(srow0, srow0 * 128 + sc8 * 16)) = pv0;
            *(f16x8*)(Vn + swz(srow1, srow1 * 128 + sc8 * 16)) = pv1;
        }
        __syncthreads();
        cur ^= 1;
        kb_cur = kb_nxt;
    }

    // ---- epilogue: combine phases, gate, single coalesced RMW ---------------
    float* Os = (float*)smem;
#pragma unroll
    for (int rg = 0; rg < 4; ++rg) {
        float s = lsum[rg];
        s += __shfl_xor(s, 1);
        s += __shfl_xor(s, 2);
        s += __shfl_xor(s, 4);
        s += __shfl_xor(s, 8);
        float inv = 1.f / s;
        int row = w * 16 + 4 * lg + rg;
        int sq = q0 + row;
        float g1 = g[((size_t)(b * Ss + sq)) * 3 + 1];
        float g2 = g[((size_t)(b * Ss + sq)) * 3 + 2];
#pragma unroll
        for (int dt = 0; dt < 4; ++dt)
            Os[row * 68 + dt * 16 + lr] = g1 * osel[dt][rg] + g2 * oacc[dt][rg] * inv;
    }
    __syncthreads();
    {
        int row = tid >> 2;
        int c0 = (tid & 3) * 16;
        int s = q0 + row;
        float* op = o + ((size_t)(b * Ss + s)) * DMm + h * HDd + c0;
#pragma unroll
        for (int j = 0; j < 4; ++j) {
            float4 val = *(const float4*)&Os[row * 68 + c0 + j * 4];
            float4 cur4 = *(const float4*)&op[j * 4];
            cur4.x += val.x; cur4.y += val.y;
            cur4.z += val.z; cur4.w += val.w;
            *(float4*)&op[j * 4] = cur4;
        }
    }
}

// -------------------- constant emitter (host-side contract checks) ------------
__global__ __launch_bounds__(256) void k_const(float* __restrict__ y, float val)
{
    int i = blockIdx.x * 256 + threadIdx.x;
    y[i] = val;
}

// -------------------- launch --------------------------------------------------
extern "C" void kernel_launch(void* const* d_in, const int* in_sizes, int n_in,
                              void* d_out, int out_size, void* d_ws, size_t ws_size,
                              hipStream_t stream) {
    float* y = (float*)d_out;
    if (n_in != 6) {
        k_const<<<dim3(16384), 256, 0, stream>>>(y, 88888.f);
        return;
    }
    if (in_sizes[0] != 4194304 || in_sizes[1] != 262144 || in_sizes[2] != 262144 ||
        in_sizes[3] != 262144 || in_sizes[4] != 262144 || in_sizes[5] != 1536) {
        k_const<<<dim3(16384), 256, 0, stream>>>(y, 77777.f);
        return;
    }
    if (ws_size < WS_FLOATS * sizeof(float)) {
        k_const<<<dim3(16384), 256, 0, stream>>>(y, 66666.f);
        return;
    }

    const float* x  = (const float*)d_in[0];
    const float* Wq = (const float*)d_in[1];
    const float* Wk = (const float*)d_in[2];
    const float* Wv = (const float*)d_in[3];
    const float* Wo = (const float*)d_in[4];
    const float* Wg = (const float*)d_in[5];
    float* ws = (float*)d_ws;

    float* kw   = ws + OFF_K;
    float* vw   = ws + OFF_V;
    float* ow   = ws + OFF_O;
    float* gw   = ws + OFF_G;
    float* impw = ws + OFF_IMPB;
    int*   selw = (int*)(ws + OFF_SEL);
    f16*   qhw  = (f16*)(ws + OFF_QH);
    f16*   qlw  = (f16*)(ws + OFF_QL);
    f16*   khw  = (f16*)(ws + OFF_KH);
    f16*   vtw  = (f16*)(ws + OFF_VT);
    f16*   kchw = (f16*)(ws + OFF_KCH);
    f16*   kclw = (f16*)(ws + OFF_KCL);
    f16*   vctw = (f16*)(ws + OFF_VCT);
    f16*   xhw  = (f16*)(ws + OFF_XH);   // aliases o region (freed before k_cmp)
    f16*   xlw  = (f16*)(ws + OFF_XL);
    f16*   wqh  = (f16*)(ws + OFF_WT);
    f16*   wql  = (f16*)(ws + OFF_WT + 131072);
    f16*   wkh  = (f16*)(ws + OFF_WT + 262144);
    f16*   wkl  = (f16*)(ws + OFF_WT + 393216);
    f16*   wvh  = (f16*)(ws + OFF_WT + 524288);
    f16*   wvl  = (f16*)(ws + OFF_WT + 655360);
    f16*   woh  = (f16*)(ws + OFF_WT + 786432);

    k_prep_x<<<dim3(2048), 256, 0, stream>>>(x, xhw, xlw);
    k_prep_w<<<dim3(8, 8, 4), 256, 0, stream>>>(Wq, Wk, Wv, Wo,
            wqh, wql, wkh, wkl, wvh, wvl, woh);
    k_gemm<1, 0, 0><<<dim3(64, 8), 256, 0, stream>>>(xhw, xlw, (const float*)0,
            wqh, wql, (float*)0, qhw, qlw);
    k_gemm<1, 0, 0><<<dim3(64, 8), 256, 0, stream>>>(xhw, xlw, (const float*)0,
            wkh, wkl, kw, khw, (f16*)0);
    k_gemm<1, 0, 0><<<dim3(64, 8), 256, 0, stream>>>(xhw, xlw, (const float*)0,
            wvh, wvl, vw, (f16*)0, (f16*)0);
    k_gate<<<dim3(32), 256, 0, stream>>>(x, Wg, gw);
    k_cvt_vt<<<dim3(64, 16), 256, 0, stream>>>(vw, vtw);
    k_pool<<<dim3(512), 256, 0, stream>>>(kw, vw, kchw, kclw, vctw);
    k_cmp<<<dim3(64, 16), 256, 0, stream>>>(qhw, qlw, kchw, kclw, vctw, gw, impw, ow);
    k_topk<<<dim3(4), 256, 0, stream>>>(impw, selw);
    k_attn2<<<dim3(64, 16), 256, 0, stream>>>(qhw, khw, vtw, selw, gw, ow);
    k_gemm<0, 1, 1><<<dim3(64, 8), 256, 0, stream>>>((const f16*)0, (const f16*)0,
            ow, woh, (const f16*)0, y, (f16*)0, (f16*)0);
}

// Round 6
// 348.894 us; speedup vs baseline: 4.1310x; 1.0449x over previous
//
#include <hip/hip_runtime.h>

// Problem constants
#define Hh    8
#define DMm   512
#define HDd   64
#define CBc   32
#define SBs   64
#define WINSZ 512
#define TOPKk 16
#define NEGF  (-1e30f)
#define Bb    2
#define Ss    4096
#define NCc   128   // S/CB
#define NSs   64    // S/SB
#define SCALE 0.125f

// Workspace layout (float offsets)
#define OFF_Q    ((size_t)0)          // (unused fp32 q region, kept for layout stability)
#define OFF_K    ((size_t)4194304)
#define OFF_V    ((size_t)8388608)
#define OFF_O    ((size_t)12582912)   // ALIASED: x_hi/x_lo live here until k_cmp writes o
#define OFF_G    ((size_t)16777216)   // B*S*3 = 24576
#define OFF_KC   ((size_t)16801792)   // kc_hi/kc_lo f16 (2 x 131072 halves)
#define OFF_VC   ((size_t)16932864)   // vc^T f16 (131072 halves)
#define OFF_IMPB ((size_t)17063936)   // B*H*NS*NS = 65536
#define OFF_SEL  ((size_t)17129472)   // B*H*NS*TOPK ints = 16384
#define OFF_QH   ((size_t)17145856)   // f16 q  [bh][s][d]
#define OFF_KH   ((size_t)19243008)   // f16 k  [bh][s][d]
#define OFF_VT   ((size_t)21340160)   // f16 v^T [bh][d][s]
#define OFF_WT   ((size_t)23437312)   // 7 x 131072 floats of f16 W^T (hi/lo)
#define OFF_QL   ((size_t)24354816)   // f16 q_lo [bh][s][d] : 2097152 halves
#define WS_FLOATS ((size_t)25403392)

// x_hi/x_lo alias the o region (o first written by k_cmp, after GEMMs)
#define OFF_XH   (OFF_O)
#define OFF_XL   (OFF_O + 2097152)

#define OFF_KCH  (OFF_KC)
#define OFF_KCL  (OFF_KC + 65536)
#define OFF_VCT  (OFF_VC)

typedef _Float16 f16;
typedef _Float16 f16x4 __attribute__((ext_vector_type(4)));
typedef _Float16 f16x8 __attribute__((ext_vector_type(8)));
typedef float    f32x4 __attribute__((ext_vector_type(4)));

__device__ __forceinline__ int swz(int row, int byteoff) {
    return byteoff ^ ((row & 7) << 4);   // spreads stride-128B rows across banks
}

// -------------------- K0a: x -> x_hi, x_lo (f16 split) ------------------------
__global__ __launch_bounds__(256) void k_prep_x(const float* __restrict__ x,
        f16* __restrict__ xh, f16* __restrict__ xl)
{
    size_t base = ((size_t)blockIdx.x * 256 + threadIdx.x) * 8;   // covers 4194304
    float4 a = *(const float4*)(x + base);
    float4 b = *(const float4*)(x + base + 4);
    f16x8 h, l;
    h[0] = (_Float16)a.x; l[0] = (_Float16)(a.x - (float)h[0]);
    h[1] = (_Float16)a.y; l[1] = (_Float16)(a.y - (float)h[1]);
    h[2] = (_Float16)a.z; l[2] = (_Float16)(a.z - (float)h[2]);
    h[3] = (_Float16)a.w; l[3] = (_Float16)(a.w - (float)h[3]);
    h[4] = (_Float16)b.x; l[4] = (_Float16)(b.x - (float)h[4]);
    h[5] = (_Float16)b.y; l[5] = (_Float16)(b.y - (float)h[5]);
    h[6] = (_Float16)b.z; l[6] = (_Float16)(b.z - (float)h[6]);
    h[7] = (_Float16)b.w; l[7] = (_Float16)(b.w - (float)h[7]);
    *(f16x8*)(xh + base) = h;
    *(f16x8*)(xl + base) = l;
}

// -------------------- K0b: W -> W^T hi/lo (f16) -------------------------------
__global__ __launch_bounds__(256) void k_prep_w(
        const float* __restrict__ Wq, const float* __restrict__ Wk,
        const float* __restrict__ Wv, const float* __restrict__ Wo,
        f16* __restrict__ wqh, f16* __restrict__ wql,
        f16* __restrict__ wkh, f16* __restrict__ wkl,
        f16* __restrict__ wvh, f16* __restrict__ wvl,
        f16* __restrict__ woh)
{
    const int k0 = blockIdx.x * 64;
    const int n0 = blockIdx.y * 64;
    const int z = blockIdx.z;
    const float* W = (z == 0) ? Wq : ((z == 1) ? Wk : ((z == 2) ? Wv : Wo));
    f16* dh = (z == 0) ? wqh : ((z == 1) ? wkh : ((z == 2) ? wvh : woh));
    f16* dl = (z == 0) ? wql : ((z == 1) ? wkl : ((z == 2) ? wvl : (f16*)0));
    __shared__ float T[64][68];
    const int tid = threadIdx.x;
    {
        int r = tid >> 2;
        int c16 = (tid & 3) * 16;
#pragma unroll
        for (int j = 0; j < 4; ++j) {
            float4 w4 = *(const float4*)(W + (size_t)(k0 + r) * DMm + n0 + c16 + j * 4);
            *(float4*)&T[r][c16 + j * 4] = w4;
        }
    }
    __syncthreads();
    {
        int n = tid >> 2;
        int k16 = (tid & 3) * 16;
        f16x8 h0, h1, l0, l1;
#pragma unroll
        for (int j = 0; j < 8; ++j) {
            float wv = T[k16 + j][n];
            h0[j] = (_Float16)wv; l0[j] = (_Float16)(wv - (float)h0[j]);
        }
#pragma unroll
        for (int j = 0; j < 8; ++j) {
            float wv = T[k16 + 8 + j][n];
            h1[j] = (_Float16)wv; l1[j] = (_Float16)(wv - (float)h1[j]);
        }
        size_t o = (size_t)(n0 + n) * DMm + k0 + k16;
        *(f16x8*)(dh + o) = h0;
        *(f16x8*)(dh + o + 8) = h1;
        if (dl) { *(f16x8*)(dl + o) = l0; *(f16x8*)(dl + o + 8) = l1; }
    }
}

// -------------------- K1: MFMA GEMM (128x64 tile, BK=32) ----------------------
template <int SPLIT, int AF32, int OUTM>
__global__ __launch_bounds__(256) void k_gemm(
        const f16* __restrict__ Ah, const f16* __restrict__ Al,
        const float* __restrict__ Af,
        const f16* __restrict__ Bh, const f16* __restrict__ Bl,
        float* __restrict__ Cf, f16* __restrict__ Ch, f16* __restrict__ Cl)
{
    const int m0 = blockIdx.x * 128;
    const int n0 = blockIdx.y * 64;
    const int tid = threadIdx.x;
    const int w = tid >> 6, l = tid & 63;
    const int lr = l & 15, lg = l >> 4;
    const int wm = w >> 1, wn = w & 1;

    __shared__ f16 As[SPLIT ? 2 : 1][128 * 40];
    __shared__ f16 Bs[SPLIT ? 2 : 1][64 * 40];

    f32x4 acc[4][2];
#pragma unroll
    for (int mf = 0; mf < 4; ++mf)
#pragma unroll
        for (int nf = 0; nf < 2; ++nf) acc[mf][nf] = (f32x4){0.f, 0.f, 0.f, 0.f};

    const int ar = tid >> 1, ac = (tid & 1) * 16;
    const int bn = tid >> 2, bc = (tid & 3) * 8;

    for (int k0 = 0; k0 < DMm; k0 += 32) {
        if (AF32) {
            const float* src = Af + (size_t)(m0 + ar) * DMm + k0 + ac;
            float4 a0 = *(const float4*)(src);
            float4 a1 = *(const float4*)(src + 4);
            float4 a2 = *(const float4*)(src + 8);
            float4 a3 = *(const float4*)(src + 12);
            f16x8 h0, h1;
            h0[0] = (_Float16)a0.x; h0[1] = (_Float16)a0.y; h0[2] = (_Float16)a0.z; h0[3] = (_Float16)a0.w;
            h0[4] = (_Float16)a1.x; h0[5] = (_Float16)a1.y; h0[6] = (_Float16)a1.z; h0[7] = (_Float16)a1.w;
            h1[0] = (_Float16)a2.x; h1[1] = (_Float16)a2.y; h1[2] = (_Float16)a2.z; h1[3] = (_Float16)a2.w;
            h1[4] = (_Float16)a3.x; h1[5] = (_Float16)a3.y; h1[6] = (_Float16)a3.z; h1[7] = (_Float16)a3.w;
            *(f16x8*)&As[0][ar * 40 + ac] = h0;
            *(f16x8*)&As[0][ar * 40 + ac + 8] = h1;
        } else {
            const f16* src = Ah + (size_t)(m0 + ar) * DMm + k0 + ac;
            *(f16x8*)&As[0][ar * 40 + ac] = *(const f16x8*)src;
            *(f16x8*)&As[0][ar * 40 + ac + 8] = *(const f16x8*)(src + 8);
            if (SPLIT) {
                const f16* src2 = Al + (size_t)(m0 + ar) * DMm + k0 + ac;
                *(f16x8*)&As[SPLIT ? 1 : 0][ar * 40 + ac] = *(const f16x8*)src2;
                *(f16x8*)&As[SPLIT ? 1 : 0][ar * 40 + ac + 8] = *(const f16x8*)(src2 + 8);
            }
        }
        {
            const f16* src = Bh + (size_t)(n0 + bn) * DMm + k0 + bc;
            *(f16x8*)&Bs[0][bn * 40 + bc] = *(const f16x8*)src;
            if (SPLIT) {
                const f16* src2 = Bl + (size_t)(n0 + bn) * DMm + k0 + bc;
                *(f16x8*)&Bs[SPLIT ? 1 : 0][bn * 40 + bc] = *(const f16x8*)src2;
            }
        }
        __syncthreads();

        f16x8 ahf[4], alf[4], bhf[2], blf[2];
#pragma unroll
        for (int mf = 0; mf < 4; ++mf) {
            int row = wm * 64 + mf * 16 + lr;
            ahf[mf] = *(const f16x8*)&As[0][row * 40 + lg * 8];
            if (SPLIT) alf[mf] = *(const f16x8*)&As[SPLIT ? 1 : 0][row * 40 + lg * 8];
        }
#pragma unroll
        for (int nf = 0; nf < 2; ++nf) {
            int row = wn * 32 + nf * 16 + lr;
            bhf[nf] = *(const f16x8*)&Bs[0][row * 40 + lg * 8];
            if (SPLIT) blf[nf] = *(const f16x8*)&Bs[SPLIT ? 1 : 0][row * 40 + lg * 8];
        }
#pragma unroll
        for (int mf = 0; mf < 4; ++mf)
#pragma unroll
            for (int nf = 0; nf < 2; ++nf) {
                acc[mf][nf] = __builtin_amdgcn_mfma_f32_16x16x32_f16(ahf[mf], bhf[nf], acc[mf][nf], 0, 0, 0);
                if (SPLIT) {
                    acc[mf][nf] = __builtin_amdgcn_mfma_f32_16x16x32_f16(ahf[mf], blf[nf], acc[mf][nf], 0, 0, 0);
                    acc[mf][nf] = __builtin_amdgcn_mfma_f32_16x16x32_f16(alf[mf], bhf[nf], acc[mf][nf], 0, 0, 0);
                }
            }
        __syncthreads();
    }

#pragma unroll
    for (int mf = 0; mf < 4; ++mf)
#pragma unroll
        for (int nf = 0; nf < 2; ++nf)
#pragma unroll
            for (int rg = 0; rg < 4; ++rg) {
                int m = m0 + wm * 64 + mf * 16 + 4 * lg + rg;
                int n = n0 + wn * 32 + nf * 16 + lr;
                float val = acc[mf][nf][rg];
                if (OUTM == 0) {
                    int b = m >> 12, s = m & 4095;
                    int h = n >> 6, d = n & 63;
                    size_t o = (((size_t)(b * Hh + h)) * Ss + s) * HDd + d;
                    if (Cf) Cf[o] = val;
                    if (Ch) {
                        f16 hv = (f16)val;
                        Ch[o] = hv;
                        if (Cl) Cl[o] = (f16)(val - (float)hv);
                    }
                } else {
                    Cf[(size_t)m * DMm + n] = val;
                }
            }
}

// -------------------- K2: gate = sigmoid(x @ Wg) ------------------------------
__global__ __launch_bounds__(256) void k_gate(const float* __restrict__ x,
        const float* __restrict__ Wg, float* __restrict__ g)
{
    int row = blockIdx.x * 256 + threadIdx.x;   // 0 .. 8191
    if (row >= Bb * Ss) return;
    const float* xr = x + (size_t)row * DMm;
    float a0 = 0.f, a1 = 0.f, a2 = 0.f;
    for (int d = 0; d < DMm; ++d) {
        float xv = xr[d];
        a0 += xv * Wg[d * 3 + 0];
        a1 += xv * Wg[d * 3 + 1];
        a2 += xv * Wg[d * 3 + 2];
    }
    g[(size_t)row * 3 + 0] = 1.f / (1.f + expf(-a0));
    g[(size_t)row * 3 + 1] = 1.f / (1.f + expf(-a1));
    g[(size_t)row * 3 + 2] = 1.f / (1.f + expf(-a2));
}

// -------------------- K2c: fp32 v [bh][s][d] -> f16 vt [bh][d][s] -------------
__global__ __launch_bounds__(256) void k_cvt_vt(const float* __restrict__ v,
        f16* __restrict__ vt)
{
    const int s0 = blockIdx.x * 64;
    const int bh = blockIdx.y;
    __shared__ _Float16 tile[64][72];
    const int tid = threadIdx.x;
    const int r = tid >> 4;            // 0..15
    const int d0 = (tid & 15) * 4;
#pragma unroll
    for (int p = 0; p < 4; ++p) {
        int rr = r + p * 16;
        float4 t4 = *(const float4*)(v + ((size_t)bh * Ss + s0 + rr) * HDd + d0);
        tile[d0 + 0][rr] = (_Float16)t4.x;
        tile[d0 + 1][rr] = (_Float16)t4.y;
        tile[d0 + 2][rr] = (_Float16)t4.z;
        tile[d0 + 3][rr] = (_Float16)t4.w;
    }
    __syncthreads();
    const int d = tid >> 2;
    const int c0 = (tid & 3) * 16;
    f16* dst = vt + ((size_t)bh * HDd + d) * Ss + s0 + c0;
    *(f16x8*)(dst)     = *(const f16x8*)&tile[d][c0];
    *(f16x8*)(dst + 8) = *(const f16x8*)&tile[d][c0 + 8];
}

// -------------------- K3: mean-pool k,v -> f16 kc_hi/kc_lo [n][d], vc^T [d][n] -
__global__ __launch_bounds__(256) void k_pool(const float* __restrict__ kk,
        const float* __restrict__ vv, f16* __restrict__ kch,
        f16* __restrict__ kcl, f16* __restrict__ vct)
{
    int idx = blockIdx.x * 256 + threadIdx.x;  // B*H*NC*HD = 131072
    int d = idx & 63;
    int n = (idx >> 6) & 127;
    int bh = idx >> 13;
    const float* kp = kk + ((size_t)bh * Ss + n * CBc) * HDd + d;
    const float* vp = vv + ((size_t)bh * Ss + n * CBc) * HDd + d;
    float sk = 0.f, sv = 0.f;
    for (int t = 0; t < CBc; ++t) { sk += kp[(size_t)t * HDd]; sv += vp[(size_t)t * HDd]; }
    float mk = sk * (1.f / CBc);
    float mv = sv * (1.f / CBc);
    f16 h = (f16)mk;
    kch[idx] = h;
    kcl[idx] = (f16)(mk - (float)h);
    vct[((size_t)bh * HDd + d) * NCc + n] = (f16)mv;
}

// -------------------- K4: compressed attention + importance (split-f16 MFMA) --
__global__ __launch_bounds__(256) void k_cmp(const f16* __restrict__ qh,
        const f16* __restrict__ ql, const f16* __restrict__ kch,
        const f16* __restrict__ kcl, const f16* __restrict__ vct,
        const float* __restrict__ g, float* __restrict__ impb, float* __restrict__ o)
{
    const int qb = blockIdx.x;   // 0..63
    const int bh = blockIdx.y;   // 0..15
    const int b = bh >> 3, h = bh & 7;
    const int q0 = qb * 64;
    const int tid = threadIdx.x;
    const int w = tid >> 6, l = tid & 63;
    const int lr = l & 15, lg = l >> 4;

    __shared__ __align__(16) char smem[51200];
    float* Pm = (float*)smem;                       // [64][132] fp32 scores/probs
    char* U = smem + 33792;                         // 16KB union: {KCh,KCl} / {VCt,Ps}
    float* red2 = (float*)(smem + 33792 + 16384);   // 256 floats

    const int NCT = (qb <= 30) ? 1 : 2;
    const int ncols = NCT * 64;

    f16x8 qfh0, qfh1, qfl0, qfl1;
    {
        size_t qoff = ((size_t)bh * Ss + q0 + w * 16 + lr) * HDd + lg * 8;
        qfh0 = *(const f16x8*)(qh + qoff);
        qfh1 = *(const f16x8*)(qh + qoff + 32);
        qfl0 = *(const f16x8*)(ql + qoff);
        qfl1 = *(const f16x8*)(ql + qoff + 32);
    }

    for (int ct = 0; ct < NCT; ++ct) {
        __syncthreads();
#pragma unroll
        for (int p = 0; p < 2; ++p) {
            int idx = tid + p * 256;
            int row = idx >> 3;           // chunk 0..63
            int c8 = idx & 7;
            size_t src = ((size_t)bh * NCc + ct * 64 + row) * HDd + c8 * 8;
            *(f16x8*)(U + swz(row, row * 128 + c8 * 16)) = *(const f16x8*)(kch + src);
            *(f16x8*)(U + 8192 + swz(row, row * 128 + c8 * 16)) = *(const f16x8*)(kcl + src);
        }
        __syncthreads();
#pragma unroll
        for (int kt = 0; kt < 4; ++kt) {
            int krow = kt * 16 + lr;
            f16x8 bh0 = *(const f16x8*)(U + swz(krow, krow * 128 + lg * 16));
            f16x8 bh1 = *(const f16x8*)(U + swz(krow, krow * 128 + lg * 16 + 64));
            f16x8 bl0 = *(const f16x8*)(U + 8192 + swz(krow, krow * 128 + lg * 16));
            f16x8 bl1 = *(const f16x8*)(U + 8192 + swz(krow, krow * 128 + lg * 16 + 64));
            f32x4 c = (f32x4){0.f, 0.f, 0.f, 0.f};
            c = __builtin_amdgcn_mfma_f32_16x16x32_f16(qfh0, bh0, c, 0, 0, 0);
            c = __builtin_amdgcn_mfma_f32_16x16x32_f16(qfh1, bh1, c, 0, 0, 0);
            c = __builtin_amdgcn_mfma_f32_16x16x32_f16(qfh0, bl0, c, 0, 0, 0);
            c = __builtin_amdgcn_mfma_f32_16x16x32_f16(qfh1, bl1, c, 0, 0, 0);
            c = __builtin_amdgcn_mfma_f32_16x16x32_f16(qfl0, bh0, c, 0, 0, 0);
            c = __builtin_amdgcn_mfma_f32_16x16x32_f16(qfl1, bh1, c, 0, 0, 0);
            int n = ct * 64 + kt * 16 + lr;
#pragma unroll
            for (int rg = 0; rg < 4; ++rg) {
                int row = w * 16 + 4 * lg + rg;
                int s = q0 + row;
                bool valid = (32 * n + 31 <= s);
                Pm[row * 132 + n] = valid ? c[rg] * SCALE : NEGF;
            }
        }
    }
    __syncthreads();

    {
        int r = tid >> 2;
        int l4 = tid & 3;
        float m = NEGF;
        for (int c = l4; c < ncols; c += 4) m = fmaxf(m, Pm[r * 132 + c]);
        m = fmaxf(m, __shfl_xor(m, 1));
        m = fmaxf(m, __shfl_xor(m, 2));
        float sum = 0.f;
        if (m > NEGF * 0.5f) {
            for (int c = l4; c < ncols; c += 4) {
                float sv = Pm[r * 132 + c];
                float p = (sv <= NEGF * 0.5f) ? 0.f : __expf(sv - m);
                Pm[r * 132 + c] = p;
                sum += p;
            }
        } else {
            for (int c = l4; c < ncols; c += 4) Pm[r * 132 + c] = 0.f;
        }
        sum += __shfl_xor(sum, 1);
        sum += __shfl_xor(sum, 2);
        float inv = (sum > 0.f) ? 1.f / sum : 0.f;
        for (int c = l4; c < ncols; c += 4) Pm[r * 132 + c] *= inv;
    }
    __syncthreads();

    {
        float part = 0.f;
#pragma unroll
        for (int rr = 0; rr < 16; ++rr) {
            int qq = w * 16 + rr;
            int c = 2 * l;
            if (c < ncols) {
                float2 pv2 = *(const float2*)&Pm[qq * 132 + c];
                part += pv2.x + pv2.y;
            }
        }
        red2[w * 64 + l] = part;
    }
    __syncthreads();
    if (tid < 64) {
        float tot = red2[tid] + red2[64 + tid] + red2[128 + tid] + red2[192 + tid];
        impb[((size_t)bh * NSs + qb) * NSs + tid] = tot;
    }

    f32x4 oacc[4];
#pragma unroll
    for (int dt = 0; dt < 4; ++dt) oacc[dt] = (f32x4){0.f, 0.f, 0.f, 0.f};
    char* Ps = U + 8192 + w * 2048;
    for (int ct = 0; ct < NCT; ++ct) {
        __syncthreads();
#pragma unroll
        for (int p = 0; p < 2; ++p) {
            int idx = tid + p * 256;
            int row = idx >> 3;           // d 0..63
            int c8 = idx & 7;
            size_t src = ((size_t)bh * HDd + row) * NCc + ct * 64 + c8 * 8;
            *(f16x8*)(U + swz(row, row * 128 + c8 * 16)) = *(const f16x8*)(vct + src);
        }
        {
            int r = l >> 2;
            int c0 = (l & 3) * 16;
            const float* pr = &Pm[(w * 16 + r) * 132 + ct * 64 + c0];
            float4 p0 = *(const float4*)(pr);
            float4 p1 = *(const float4*)(pr + 4);
            float4 p2 = *(const float4*)(pr + 8);
            float4 p3 = *(const float4*)(pr + 12);
            f16x8 h0, h1;
            h0[0] = (_Float16)p0.x; h0[1] = (_Float16)p0.y; h0[2] = (_Float16)p0.z; h0[3] = (_Float16)p0.w;
            h0[4] = (_Float16)p1.x; h0[5] = (_Float16)p1.y; h0[6] = (_Float16)p1.z; h0[7] = (_Float16)p1.w;
            h1[0] = (_Float16)p2.x; h1[1] = (_Float16)p2.y; h1[2] = (_Float16)p2.z; h1[3] = (_Float16)p2.w;
            h1[4] = (_Float16)p3.x; h1[5] = (_Float16)p3.y; h1[6] = (_Float16)p3.z; h1[7] = (_Float16)p3.w;
            *(f16x8*)(Ps + swz(r, r * 128 + c0 * 2)) = h0;
            *(f16x8*)(Ps + swz(r, r * 128 + c0 * 2 + 16)) = h1;
        }
        __syncthreads();
        f16x8 pa0 = *(const f16x8*)(Ps + swz(lr, lr * 128 + lg * 16));
        f16x8 pa1 = *(const f16x8*)(Ps + swz(lr, lr * 128 + lg * 16 + 64));
#pragma unroll
        for (int dt = 0; dt < 4; ++dt) {
            int vrow = dt * 16 + lr;
            f16x8 vb0 = *(const f16x8*)(U + swz(vrow, vrow * 128 + lg * 16));
            f16x8 vb1 = *(const f16x8*)(U + swz(vrow, vrow * 128 + lg * 16 + 64));
            oacc[dt] = __builtin_amdgcn_mfma_f32_16x16x32_f16(pa0, vb0, oacc[dt], 0, 0, 0);
            oacc[dt] = __builtin_amdgcn_mfma_f32_16x16x32_f16(pa1, vb1, oacc[dt], 0, 0, 0);
        }
    }

#pragma unroll
    for (int rg = 0; rg < 4; ++rg) {
        int row = w * 16 + 4 * lg + rg;
        int s = q0 + row;
        float g0 = g[((size_t)(b * Ss + s)) * 3 + 0];
#pragma unroll
        for (int dt = 0; dt < 4; ++dt)
            o[((size_t)(b * Ss + s)) * DMm + h * HDd + dt * 16 + lr] = g0 * oacc[dt][rg];
    }
}

// -------------------- K5: top-k selection -------------------------------------
__global__ __launch_bounds__(256) void k_topk(const float* __restrict__ impb,
        int* __restrict__ sel)
{
    int row = blockIdx.x * 256 + threadIdx.x;  // B*H*NS = 1024 rows
    if (row >= Bb * Hh * NSs) return;
    int qb = row & 63;
    float v[64];
    for (int j = 0; j < 64; ++j) {
        float t = impb[(size_t)row * 64 + j];
        if (j > qb) t = NEGF;
        if (j == qb) t += 1e9f;
        v[j] = t;
    }
    for (int t = 0; t < TOPKk; ++t) {
        int bi = 0; float bv = v[0];
        for (int j = 1; j < 64; ++j) {
            if (v[j] > bv) { bv = v[j]; bi = j; }
        }
        sel[(size_t)row * TOPKk + t] = bi;
        v[bi] = -3e38f;
    }
}

// -------------------- K6: merged MFMA attention (selected + window) -----------
// Swapped-operand QK^T: S^T = mfma(K, Q) puts each lane's P values on its OWN
// q-row (q = lr), keys kt*16+4*lg+rg -- exactly the A-fragment layout of
// mfma_f32_16x16x16f16 (k = 4*lg+j). PV thus runs with P packed in-register:
// no P LDS buffer, no f16 scatter stores, no P re-read. lsum is one scalar per
// lane, reduced across lg (shfl_xor 16/32) once per phase.
// XCD-aware (qb,bh) mapping: XCD c = bid%8 sees only bh in {2c,2c+1} -> 2MB
// K/V working set fits the 4MB per-XCD L2 (was 16MB -> 140MB HBM over-fetch).
__global__ __launch_bounds__(256) void k_attn2(const f16* __restrict__ qh,
        const f16* __restrict__ kh, const f16* __restrict__ vt,
        const int* __restrict__ sel, const float* __restrict__ g,
        float* __restrict__ o)
{
    const int bid = blockIdx.x + 64 * blockIdx.y;   // 0..1023
    const int bh = ((bid & 7) << 1) | ((bid >> 3) & 1);
    const int qb = bid >> 4;
    const int b = bh >> 3, h = bh & 7;
    const int q0 = qb * 64;
    const int tid = threadIdx.x;
    const int w  = tid >> 6;      // wave 0..3
    const int l  = tid & 63;
    const int lr = l & 15;
    const int lg = l >> 4;

    __shared__ __align__(16) char smem[32768];
    // K dbuf: [0,8K) [8K,16K); V dbuf: [16K,24K) [24K,32K)

    f16x8 qf0, qf1;
    {
        const f16* qptr = qh + ((size_t)bh * Ss + q0 + w * 16 + lr) * HDd + lg * 8;
        qf0 = *(const f16x8*)(qptr);
        qf1 = *(const f16x8*)(qptr + 32);
    }

    const int W0 = (qb < 8) ? (8 - qb) : 0;
    const int NT = 25 - W0;             // 16 selected + (9-W0) window
    const int* selrow = sel + ((size_t)bh * NSs + qb) * TOPKk;

    float lsum = 0.f;
    f32x4 oacc[4], osel[4];
#pragma unroll
    for (int dt = 0; dt < 4; ++dt) {
        oacc[dt] = (f32x4){0.f, 0.f, 0.f, 0.f};
        osel[dt] = (f32x4){0.f, 0.f, 0.f, 0.f};
    }

    const int srow0 = tid >> 3, sc8 = tid & 7;
    const int srow1 = (tid + 256) >> 3;
    f16x8 pk0, pk1, pv0, pv1;

    // prologue: stage tile 0 into buf 0
    int kb_cur = selrow[0];
    {
        size_t kbase = (size_t)bh * Ss + kb_cur * 64;
        pk0 = *(const f16x8*)(kh + (kbase + srow0) * HDd + sc8 * 8);
        pk1 = *(const f16x8*)(kh + (kbase + srow1) * HDd + sc8 * 8);
        pv0 = *(const f16x8*)(vt + ((size_t)bh * HDd + srow0) * Ss + kb_cur * 64 + sc8 * 8);
        pv1 = *(const f16x8*)(vt + ((size_t)bh * HDd + srow1) * Ss + kb_cur * 64 + sc8 * 8);
        *(f16x8*)(smem + swz(srow0, srow0 * 128 + sc8 * 16)) = pk0;
        *(f16x8*)(smem + swz(srow1, srow1 * 128 + sc8 * 16)) = pk1;
        *(f16x8*)(smem + 16384 + swz(srow0, srow0 * 128 + sc8 * 16)) = pv0;
        *(f16x8*)(smem + 16384 + swz(srow1, srow1 * 128 + sc8 * 16)) = pv1;
    }
    __syncthreads();

    int cur = 0;
    for (int t = 0; t < NT; ++t) {
        // ---- prefetch issue (next tile -> regs) -----------------------------
        int kb_nxt = 0;
        const bool hasNext = (t + 1 < NT);
        if (hasNext) {
            kb_nxt = (t + 1 < 16) ? selrow[t + 1] : (qb - 8 + W0 + (t + 1 - 16));
            size_t kbase = (size_t)bh * Ss + kb_nxt * 64;
            pk0 = *(const f16x8*)(kh + (kbase + srow0) * HDd + sc8 * 8);
            pk1 = *(const f16x8*)(kh + (kbase + srow1) * HDd + sc8 * 8);
            pv0 = *(const f16x8*)(vt + ((size_t)bh * HDd + srow0) * Ss + kb_nxt * 64 + sc8 * 8);
            pv1 = *(const f16x8*)(vt + ((size_t)bh * HDd + srow1) * Ss + kb_nxt * 64 + sc8 * 8);
        }
        const char* Kc = smem + (cur ? 8192 : 0);
        const char* Vc = smem + 16384 + (cur ? 8192 : 0);
        const bool isw = (t >= 16);
        const int kbase = kb_cur * 64;

        // ---- swapped QK^T + softmax-lite: P stays in registers --------------
        f16x4 pa[4];
        const int qpos = q0 + w * 16 + lr;
#pragma unroll
        for (int kt = 0; kt < 4; ++kt) {
            int krow = kt * 16 + lr;
            f16x8 kb0 = *(const f16x8*)(Kc + swz(krow, krow * 128 + lg * 16));
            f16x8 kb1 = *(const f16x8*)(Kc + swz(krow, krow * 128 + lg * 16 + 64));
            f32x4 c = (f32x4){0.f, 0.f, 0.f, 0.f};
            c = __builtin_amdgcn_mfma_f32_16x16x32_f16(kb0, qf0, c, 0, 0, 0);
            c = __builtin_amdgcn_mfma_f32_16x16x32_f16(kb1, qf1, c, 0, 0, 0);
#pragma unroll
            for (int rg = 0; rg < 4; ++rg) {
                int kpos = kbase + kt * 16 + 4 * lg + rg;
                bool valid = (kpos <= qpos);
                if (isw) valid = valid && (kpos > qpos - WINSZ);
                float p = valid ? __expf(c[rg] * SCALE) : 0.f;
                lsum += p;
                pa[kt][rg] = (_Float16)p;
            }
        }

        // ---- PV: A = in-register P (k = 4*lg+j), B = V^T, 16x16x16 ---------
#pragma unroll
        for (int dt = 0; dt < 4; ++dt) {
            int vrow = dt * 16 + lr;
#pragma unroll
            for (int kt = 0; kt < 4; ++kt) {
                f16x4 vb = *(const f16x4*)(Vc + swz(vrow, vrow * 128 + kt * 32 + lg * 8));
                oacc[dt] = __builtin_amdgcn_mfma_f32_16x16x16f16(pa[kt], vb, oacc[dt], 0, 0, 0);
            }
        }

        // ---- phase boundary: snapshot selected result, reset ----------------
        if (t == 15) {
            float s = lsum;
            s += __shfl_xor(s, 16);
            s += __shfl_xor(s, 32);
            float inv = 1.f / s;
#pragma unroll
            for (int rg = 0; rg < 4; ++rg) {
                float invq = __shfl(inv, 4 * lg + rg);
#pragma unroll
                for (int dt = 0; dt < 4; ++dt) osel[dt][rg] = oacc[dt][rg] * invq;
            }
#pragma unroll
            for (int dt = 0; dt < 4; ++dt) oacc[dt] = (f32x4){0.f, 0.f, 0.f, 0.f};
            lsum = 0.f;
        }

        // ---- write prefetched tile into the other buffer --------------------
        if (hasNext) {
            char* Kn = smem + (cur ? 0 : 8192);
            char* Vn = smem + 16384 + (cur ? 0 : 8192);
            *(f16x8*)(Kn + swz(srow0, srow0 * 128 + sc8 * 16)) = pk0;
            *(f16x8*)(Kn + swz(srow1, srow1 * 128 + sc8 * 16)) = pk1;
            *(f16x8*)(Vn + swz(srow0, srow0 * 128 + sc8 * 16)) = pv0;
            *(f16x8*)(Vn + swz(srow1, srow1 * 128 + sc8 * 16)) = pv1;
        }
        __syncthreads();
        cur ^= 1;
        kb_cur = kb_nxt;
    }

    // ---- epilogue: combine phases, gate, single coalesced RMW ---------------
    float* Os = (float*)smem;
    {
        float s = lsum;
        s += __shfl_xor(s, 16);
        s += __shfl_xor(s, 32);
        float inv = 1.f / s;
#pragma unroll
        for (int rg = 0; rg < 4; ++rg) {
            float invq = __shfl(inv, 4 * lg + rg);
            int row = w * 16 + 4 * lg + rg;
            int sq = q0 + row;
            float g1 = g[((size_t)(b * Ss + sq)) * 3 + 1];
            float g2 = g[((size_t)(b * Ss + sq)) * 3 + 2];
#pragma unroll
            for (int dt = 0; dt < 4; ++dt)
                Os[row * 68 + dt * 16 + lr] = g1 * osel[dt][rg] + g2 * oacc[dt][rg] * invq;
        }
    }
    __syncthreads();
    {
        int row = tid >> 2;
        int c0 = (tid & 3) * 16;
        int s = q0 + row;
        float* op = o + ((size_t)(b * Ss + s)) * DMm + h * HDd + c0;
#pragma unroll
        for (int j = 0; j < 4; ++j) {
            float4 val = *(const float4*)&Os[row * 68 + c0 + j * 4];
            float4 cur4 = *(const float4*)&op[j * 4];
            cur4.x += val.x; cur4.y += val.y;
            cur4.z += val.z; cur4.w += val.w;
            *(float4*)&op[j * 4] = cur4;
        }
    }
}

// -------------------- constant emitter (host-side contract checks) ------------
__global__ __launch_bounds__(256) void k_const(float* __restrict__ y, float val)
{
    int i = blockIdx.x * 256 + threadIdx.x;
    y[i] = val;
}

// -------------------- launch --------------------------------------------------
extern "C" void kernel_launch(void* const* d_in, const int* in_sizes, int n_in,
                              void* d_out, int out_size, void* d_ws, size_t ws_size,
                              hipStream_t stream) {
    float* y = (float*)d_out;
    if (n_in != 6) {
        k_const<<<dim3(16384), 256, 0, stream>>>(y, 88888.f);
        return;
    }
    if (in_sizes[0] != 4194304 || in_sizes[1] != 262144 || in_sizes[2] != 262144 ||
        in_sizes[3] != 262144 || in_sizes[4] != 262144 || in_sizes[5] != 1536) {
        k_const<<<dim3(16384), 256, 0, stream>>>(y, 77777.f);
        return;
    }
    if (ws_size < WS_FLOATS * sizeof(float)) {
        k_const<<<dim3(16384), 256, 0, stream>>>(y, 66666.f);
        return;
    }

    const float* x  = (const float*)d_in[0];
    const float* Wq = (const float*)d_in[1];
    const float* Wk = (const float*)d_in[2];
    const float* Wv = (const float*)d_in[3];
    const float* Wo = (const float*)d_in[4];
    const float* Wg = (const float*)d_in[5];
    float* ws = (float*)d_ws;

    float* kw   = ws + OFF_K;
    float* vw   = ws + OFF_V;
    float* ow   = ws + OFF_O;
    float* gw   = ws + OFF_G;
    float* impw = ws + OFF_IMPB;
    int*   selw = (int*)(ws + OFF_SEL);
    f16*   qhw  = (f16*)(ws + OFF_QH);
    f16*   qlw  = (f16*)(ws + OFF_QL);
    f16*   khw  = (f16*)(ws + OFF_KH);
    f16*   vtw  = (f16*)(ws + OFF_VT);
    f16*   kchw = (f16*)(ws + OFF_KCH);
    f16*   kclw = (f16*)(ws + OFF_KCL);
    f16*   vctw = (f16*)(ws + OFF_VCT);
    f16*   xhw  = (f16*)(ws + OFF_XH);   // aliases o region (freed before k_cmp)
    f16*   xlw  = (f16*)(ws + OFF_XL);
    f16*   wqh  = (f16*)(ws + OFF_WT);
    f16*   wql  = (f16*)(ws + OFF_WT + 131072);
    f16*   wkh  = (f16*)(ws + OFF_WT + 262144);
    f16*   wkl  = (f16*)(ws + OFF_WT + 393216);
    f16*   wvh  = (f16*)(ws + OFF_WT + 524288);
    f16*   wvl  = (f16*)(ws + OFF_WT + 655360);
    f16*   woh  = (f16*)(ws + OFF_WT + 786432);

    k_prep_x<<<dim3(2048), 256, 0, stream>>>(x, xhw, xlw);
    k_prep_w<<<dim3(8, 8, 4), 256, 0, stream>>>(Wq, Wk, Wv, Wo,
            wqh, wql, wkh, wkl, wvh, wvl, woh);
    k_gemm<1, 0, 0><<<dim3(64, 8), 256, 0, stream>>>(xhw, xlw, (const float*)0,
            wqh, wql, (float*)0, qhw, qlw);
    k_gemm<1, 0, 0><<<dim3(64, 8), 256, 0, stream>>>(xhw, xlw, (const float*)0,
            wkh, wkl, kw, khw, (f16*)0);
    k_gemm<1, 0, 0><<<dim3(64, 8), 256, 0, stream>>>(xhw, xlw, (const float*)0,
            wvh, wvl, vw, (f16*)0, (f16*)0);
    k_gate<<<dim3(32), 256, 0, stream>>>(x, Wg, gw);
    k_cvt_vt<<<dim3(64, 16), 256, 0, stream>>>(vw, vtw);
    k_pool<<<dim3(512), 256, 0, stream>>>(kw, vw, kchw, kclw, vctw);
    k_cmp<<<dim3(64, 16), 256, 0, stream>>>(qhw, qlw, kchw, kclw, vctw, gw, impw, ow);
    k_topk<<<dim3(4), 256, 0, stream>>>(impw, selw);
    k_attn2<<<dim3(64, 16), 256, 0, stream>>>(qhw, khw, vtw, selw, gw, ow);
    k_gemm<0, 1, 1><<<dim3(64, 8), 256, 0, stream>>>((const f16*)0, (const f16*)0,
            ow, woh, (const f16*)0, y, (f16*)0, (f16*)0);
}

// Round 8
// 295.466 us; speedup vs baseline: 4.8780x; 1.1808x over previous
//
#include <hip/hip_runtime.h>

// Problem constants
#define Hh    8
#define DMm   512
#define HDd   64
#define CBc   32
#define SBs   64
#define WINSZ 512
#define TOPKk 16
#define NEGF  (-1e30f)
#define Bb    2
#define Ss    4096
#define NCc   128   // S/CB
#define NSs   64    // S/SB
#define SCALE 0.125f
#define PSC   0.18033688011112042f   // SCALE * log2(e): q pre-scale -> exp2 softmax

// Workspace layout (float offsets)
#define OFF_Q    ((size_t)0)          // (unused fp32 q region, kept for layout stability)
#define OFF_K    ((size_t)4194304)
#define OFF_V    ((size_t)8388608)
#define OFF_O    ((size_t)12582912)   // ALIASED: x_hi/x_lo live here until k_cmp writes o
#define OFF_G    ((size_t)16777216)   // B*S*3 = 24576
#define OFF_KC   ((size_t)16801792)   // kc_hi/kc_lo f16 (2 x 131072 halves)
#define OFF_VC   ((size_t)16932864)   // vc^T f16 (131072 halves)
#define OFF_IMPB ((size_t)17063936)   // B*H*NS*NS = 65536
#define OFF_SEL  ((size_t)17129472)   // B*H*NS*TOPK ints = 16384
#define OFF_QH   ((size_t)17145856)   // f16 q  [bh][s][d] (pre-scaled by PSC)
#define OFF_KH   ((size_t)19243008)   // f16 k  [bh][s][d]
#define OFF_VT   ((size_t)21340160)   // f16 v^T [bh][d][s]
#define OFF_WT   ((size_t)23437312)   // 7 x 131072 floats of f16 W^T (hi/lo)
#define OFF_QL   ((size_t)24354816)   // f16 q_lo [bh][s][d] (pre-scaled by PSC)
#define WS_FLOATS ((size_t)25403392)

// x_hi/x_lo alias the o region (o first written by k_cmp, after GEMMs)
#define OFF_XH   (OFF_O)
#define OFF_XL   (OFF_O + 2097152)

#define OFF_KCH  (OFF_KC)
#define OFF_KCL  (OFF_KC + 65536)
#define OFF_VCT  (OFF_VC)

typedef _Float16 f16;
typedef _Float16 f16x4 __attribute__((ext_vector_type(4)));
typedef _Float16 f16x8 __attribute__((ext_vector_type(8)));
typedef float    f32x4 __attribute__((ext_vector_type(4)));

__device__ __forceinline__ int swz(int row, int byteoff) {
    return byteoff ^ ((row & 7) << 4);   // spreads stride-128B rows across banks
}
__device__ __forceinline__ float fexp2(float x) {
    return __builtin_amdgcn_exp2f(x);    // v_exp_f32: D = 2^S0
}

// V LDS layout: per 32-key block, quads interleaved as {4lg, 16+4lg} so that a
// single b128 read at [ktp*64 + lg*16] yields keys {ktp*32+4lg+0..3, +16+0..3}
// (matches in-register P order for mfma_16x16x32). Write side: 2 x b64.
#define STAGE_V(Vbase, vd, row, c8) do {                                     \
    int q0_ = ((c8) & 3) * 2, q1_ = q0_ + 1;                                 \
    int col0_ = ((c8) >> 2) * 64 + (q0_ & 3) * 16 + (q0_ >> 2) * 8;          \
    int col1_ = ((c8) >> 2) * 64 + (q1_ & 3) * 16 + (q1_ >> 2) * 8;          \
    f16x4 lo_ = { (vd)[0], (vd)[1], (vd)[2], (vd)[3] };                      \
    f16x4 hi_ = { (vd)[4], (vd)[5], (vd)[6], (vd)[7] };                      \
    *(f16x4*)((Vbase) + swz(row, (row) * 128 + col0_)) = lo_;                \
    *(f16x4*)((Vbase) + swz(row, (row) * 128 + col1_)) = hi_;                \
} while (0)

// -------------------- K0a: x -> x_hi, x_lo (f16 split) ------------------------
__global__ __launch_bounds__(256) void k_prep_x(const float* __restrict__ x,
        f16* __restrict__ xh, f16* __restrict__ xl)
{
    size_t base = ((size_t)blockIdx.x * 256 + threadIdx.x) * 8;   // covers 4194304
    float4 a = *(const float4*)(x + base);
    float4 b = *(const float4*)(x + base + 4);
    f16x8 h, l;
    h[0] = (_Float16)a.x; l[0] = (_Float16)(a.x - (float)h[0]);
    h[1] = (_Float16)a.y; l[1] = (_Float16)(a.y - (float)h[1]);
    h[2] = (_Float16)a.z; l[2] = (_Float16)(a.z - (float)h[2]);
    h[3] = (_Float16)a.w; l[3] = (_Float16)(a.w - (float)h[3]);
    h[4] = (_Float16)b.x; l[4] = (_Float16)(b.x - (float)h[4]);
    h[5] = (_Float16)b.y; l[5] = (_Float16)(b.y - (float)h[5]);
    h[6] = (_Float16)b.z; l[6] = (_Float16)(b.z - (float)h[6]);
    h[7] = (_Float16)b.w; l[7] = (_Float16)(b.w - (float)h[7]);
    *(f16x8*)(xh + base) = h;
    *(f16x8*)(xl + base) = l;
}

// -------------------- K0b: W -> W^T hi/lo (f16) -------------------------------
__global__ __launch_bounds__(256) void k_prep_w(
        const float* __restrict__ Wq, const float* __restrict__ Wk,
        const float* __restrict__ Wv, const float* __restrict__ Wo,
        f16* __restrict__ wqh, f16* __restrict__ wql,
        f16* __restrict__ wkh, f16* __restrict__ wkl,
        f16* __restrict__ wvh, f16* __restrict__ wvl,
        f16* __restrict__ woh)
{
    const int k0 = blockIdx.x * 64;
    const int n0 = blockIdx.y * 64;
    const int z = blockIdx.z;
    const float* W = (z == 0) ? Wq : ((z == 1) ? Wk : ((z == 2) ? Wv : Wo));
    f16* dh = (z == 0) ? wqh : ((z == 1) ? wkh : ((z == 2) ? wvh : woh));
    f16* dl = (z == 0) ? wql : ((z == 1) ? wkl : ((z == 2) ? wvl : (f16*)0));
    __shared__ float T[64][68];
    const int tid = threadIdx.x;
    {
        int r = tid >> 2;
        int c16 = (tid & 3) * 16;
#pragma unroll
        for (int j = 0; j < 4; ++j) {
            float4 w4 = *(const float4*)(W + (size_t)(k0 + r) * DMm + n0 + c16 + j * 4);
            *(float4*)&T[r][c16 + j * 4] = w4;
        }
    }
    __syncthreads();
    {
        int n = tid >> 2;
        int k16 = (tid & 3) * 16;
        f16x8 h0, h1, l0, l1;
#pragma unroll
        for (int j = 0; j < 8; ++j) {
            float wv = T[k16 + j][n];
            h0[j] = (_Float16)wv; l0[j] = (_Float16)(wv - (float)h0[j]);
        }
#pragma unroll
        for (int j = 0; j < 8; ++j) {
            float wv = T[k16 + 8 + j][n];
            h1[j] = (_Float16)wv; l1[j] = (_Float16)(wv - (float)h1[j]);
        }
        size_t o = (size_t)(n0 + n) * DMm + k0 + k16;
        *(f16x8*)(dh + o) = h0;
        *(f16x8*)(dh + o + 8) = h1;
        if (dl) { *(f16x8*)(dl + o) = l0; *(f16x8*)(dl + o + 8) = l1; }
    }
}

// -------------------- K1: MFMA GEMM (128x64 tile, BK=32) ----------------------
// cscale applies to the f16 hi/lo output only (q pre-scaling for exp2 softmax).
template <int SPLIT, int AF32, int OUTM>
__global__ __launch_bounds__(256) void k_gemm(
        const f16* __restrict__ Ah, const f16* __restrict__ Al,
        const float* __restrict__ Af,
        const f16* __restrict__ Bh, const f16* __restrict__ Bl,
        float* __restrict__ Cf, f16* __restrict__ Ch, f16* __restrict__ Cl,
        float cscale)
{
    const int m0 = blockIdx.x * 128;
    const int n0 = blockIdx.y * 64;
    const int tid = threadIdx.x;
    const int w = tid >> 6, l = tid & 63;
    const int lr = l & 15, lg = l >> 4;
    const int wm = w >> 1, wn = w & 1;

    __shared__ f16 As[SPLIT ? 2 : 1][128 * 40];
    __shared__ f16 Bs[SPLIT ? 2 : 1][64 * 40];

    f32x4 acc[4][2];
#pragma unroll
    for (int mf = 0; mf < 4; ++mf)
#pragma unroll
        for (int nf = 0; nf < 2; ++nf) acc[mf][nf] = (f32x4){0.f, 0.f, 0.f, 0.f};

    const int ar = tid >> 1, ac = (tid & 1) * 16;
    const int bn = tid >> 2, bc = (tid & 3) * 8;

    for (int k0 = 0; k0 < DMm; k0 += 32) {
        if (AF32) {
            const float* src = Af + (size_t)(m0 + ar) * DMm + k0 + ac;
            float4 a0 = *(const float4*)(src);
            float4 a1 = *(const float4*)(src + 4);
            float4 a2 = *(const float4*)(src + 8);
            float4 a3 = *(const float4*)(src + 12);
            f16x8 h0, h1;
            h0[0] = (_Float16)a0.x; h0[1] = (_Float16)a0.y; h0[2] = (_Float16)a0.z; h0[3] = (_Float16)a0.w;
            h0[4] = (_Float16)a1.x; h0[5] = (_Float16)a1.y; h0[6] = (_Float16)a1.z; h0[7] = (_Float16)a1.w;
            h1[0] = (_Float16)a2.x; h1[1] = (_Float16)a2.y; h1[2] = (_Float16)a2.z; h1[3] = (_Float16)a2.w;
            h1[4] = (_Float16)a3.x; h1[5] = (_Float16)a3.y; h1[6] = (_Float16)a3.z; h1[7] = (_Float16)a3.w;
            *(f16x8*)&As[0][ar * 40 + ac] = h0;
            *(f16x8*)&As[0][ar * 40 + ac + 8] = h1;
        } else {
            const f16* src = Ah + (size_t)(m0 + ar) * DMm + k0 + ac;
            *(f16x8*)&As[0][ar * 40 + ac] = *(const f16x8*)src;
            *(f16x8*)&As[0][ar * 40 + ac + 8] = *(const f16x8*)(src + 8);
            if (SPLIT) {
                const f16* src2 = Al + (size_t)(m0 + ar) * DMm + k0 + ac;
                *(f16x8*)&As[SPLIT ? 1 : 0][ar * 40 + ac] = *(const f16x8*)src2;
                *(f16x8*)&As[SPLIT ? 1 : 0][ar * 40 + ac + 8] = *(const f16x8*)(src2 + 8);
            }
        }
        {
            const f16* src = Bh + (size_t)(n0 + bn) * DMm + k0 + bc;
            *(f16x8*)&Bs[0][bn * 40 + bc] = *(const f16x8*)src;
            if (SPLIT) {
                const f16* src2 = Bl + (size_t)(n0 + bn) * DMm + k0 + bc;
                *(f16x8*)&Bs[SPLIT ? 1 : 0][bn * 40 + bc] = *(const f16x8*)src2;
            }
        }
        __syncthreads();

        f16x8 ahf[4], alf[4], bhf[2], blf[2];
#pragma unroll
        for (int mf = 0; mf < 4; ++mf) {
            int row = wm * 64 + mf * 16 + lr;
            ahf[mf] = *(const f16x8*)&As[0][row * 40 + lg * 8];
            if (SPLIT) alf[mf] = *(const f16x8*)&As[SPLIT ? 1 : 0][row * 40 + lg * 8];
        }
#pragma unroll
        for (int nf = 0; nf < 2; ++nf) {
            int row = wn * 32 + nf * 16 + lr;
            bhf[nf] = *(const f16x8*)&Bs[0][row * 40 + lg * 8];
            if (SPLIT) blf[nf] = *(const f16x8*)&Bs[SPLIT ? 1 : 0][row * 40 + lg * 8];
        }
#pragma unroll
        for (int mf = 0; mf < 4; ++mf)
#pragma unroll
            for (int nf = 0; nf < 2; ++nf) {
                acc[mf][nf] = __builtin_amdgcn_mfma_f32_16x16x32_f16(ahf[mf], bhf[nf], acc[mf][nf], 0, 0, 0);
                if (SPLIT) {
                    acc[mf][nf] = __builtin_amdgcn_mfma_f32_16x16x32_f16(ahf[mf], blf[nf], acc[mf][nf], 0, 0, 0);
                    acc[mf][nf] = __builtin_amdgcn_mfma_f32_16x16x32_f16(alf[mf], bhf[nf], acc[mf][nf], 0, 0, 0);
                }
            }
        __syncthreads();
    }

#pragma unroll
    for (int mf = 0; mf < 4; ++mf)
#pragma unroll
        for (int nf = 0; nf < 2; ++nf)
#pragma unroll
            for (int rg = 0; rg < 4; ++rg) {
                int m = m0 + wm * 64 + mf * 16 + 4 * lg + rg;
                int n = n0 + wn * 32 + nf * 16 + lr;
                float val = acc[mf][nf][rg];
                if (OUTM == 0) {
                    int b = m >> 12, s = m & 4095;
                    int h = n >> 6, d = n & 63;
                    size_t o = (((size_t)(b * Hh + h)) * Ss + s) * HDd + d;
                    if (Cf) Cf[o] = val;
                    if (Ch) {
                        float vs = val * cscale;
                        f16 hv = (f16)vs;
                        Ch[o] = hv;
                        if (Cl) Cl[o] = (f16)(vs - (float)hv);
                    }
                } else {
                    Cf[(size_t)m * DMm + n] = val;
                }
            }
}

// -------------------- K2: gate = sigmoid(x @ Wg), wave-per-row ----------------
__global__ __launch_bounds__(256) void k_gate(const float* __restrict__ x,
        const float* __restrict__ Wg, float* __restrict__ g)
{
    const int row = blockIdx.x * 4 + (threadIdx.x >> 6);   // 2048 blocks x 4 waves
    const int l = threadIdx.x & 63;
    const int d0 = l * 8;
    const float* xr = x + (size_t)row * DMm + d0;
    float4 a = *(const float4*)(xr);
    float4 b = *(const float4*)(xr + 4);
    float xv[8] = { a.x, a.y, a.z, a.w, b.x, b.y, b.z, b.w };
    float s0 = 0.f, s1 = 0.f, s2 = 0.f;
#pragma unroll
    for (int j = 0; j < 8; ++j) {
        const float* wr = Wg + (size_t)(d0 + j) * 3;
        s0 += xv[j] * wr[0];
        s1 += xv[j] * wr[1];
        s2 += xv[j] * wr[2];
    }
#pragma unroll
    for (int off = 1; off < 64; off <<= 1) {
        s0 += __shfl_xor(s0, off);
        s1 += __shfl_xor(s1, off);
        s2 += __shfl_xor(s2, off);
    }
    if (l == 0) {
        g[(size_t)row * 3 + 0] = 1.f / (1.f + expf(-s0));
        g[(size_t)row * 3 + 1] = 1.f / (1.f + expf(-s1));
        g[(size_t)row * 3 + 2] = 1.f / (1.f + expf(-s2));
    }
}

// -------------------- K2c: fp32 v [bh][s][d] -> f16 vt [bh][d][s] -------------
__global__ __launch_bounds__(256) void k_cvt_vt(const float* __restrict__ v,
        f16* __restrict__ vt)
{
    const int s0 = blockIdx.x * 64;
    const int bh = blockIdx.y;
    __shared__ _Float16 tile[64][72];
    const int tid = threadIdx.x;
    const int r = tid >> 4;            // 0..15
    const int d0 = (tid & 15) * 4;
#pragma unroll
    for (int p = 0; p < 4; ++p) {
        int rr = r + p * 16;
        float4 t4 = *(const float4*)(v + ((size_t)bh * Ss + s0 + rr) * HDd + d0);
        tile[d0 + 0][rr] = (_Float16)t4.x;
        tile[d0 + 1][rr] = (_Float16)t4.y;
        tile[d0 + 2][rr] = (_Float16)t4.z;
        tile[d0 + 3][rr] = (_Float16)t4.w;
    }
    __syncthreads();
    const int d = tid >> 2;
    const int c0 = (tid & 3) * 16;
    f16* dst = vt + ((size_t)bh * HDd + d) * Ss + s0 + c0;
    *(f16x8*)(dst)     = *(const f16x8*)&tile[d][c0];
    *(f16x8*)(dst + 8) = *(const f16x8*)&tile[d][c0 + 8];
}

// -------------------- K3: mean-pool k,v -> f16 kc_hi/kc_lo [n][d], vc^T [d][n] -
__global__ __launch_bounds__(256) void k_pool(const float* __restrict__ kk,
        const float* __restrict__ vv, f16* __restrict__ kch,
        f16* __restrict__ kcl, f16* __restrict__ vct)
{
    int idx = blockIdx.x * 256 + threadIdx.x;  // B*H*NC*HD = 131072
    int d = idx & 63;
    int n = (idx >> 6) & 127;
    int bh = idx >> 13;
    const float* kp = kk + ((size_t)bh * Ss + n * CBc) * HDd + d;
    const float* vp = vv + ((size_t)bh * Ss + n * CBc) * HDd + d;
    float sk = 0.f, sv = 0.f;
    for (int t = 0; t < CBc; ++t) { sk += kp[(size_t)t * HDd]; sv += vp[(size_t)t * HDd]; }
    float mk = sk * (1.f / CBc);
    float mv = sv * (1.f / CBc);
    f16 h = (f16)mk;
    kch[idx] = h;
    kcl[idx] = (f16)(mk - (float)h);
    vct[((size_t)bh * HDd + d) * NCc + n] = (f16)mv;
}

// -------------------- K4: compressed attention + importance (split-f16 MFMA) --
// q pre-scaled by PSC -> scores in log2 domain -> exp2 softmax (equivalent).
__global__ __launch_bounds__(256) void k_cmp(const f16* __restrict__ qh,
        const f16* __restrict__ ql, const f16* __restrict__ kch,
        const f16* __restrict__ kcl, const f16* __restrict__ vct,
        const float* __restrict__ g, float* __restrict__ impb, float* __restrict__ o)
{
    const int qb = blockIdx.x;   // 0..63
    const int bh = blockIdx.y;   // 0..15
    const int b = bh >> 3, h = bh & 7;
    const int q0 = qb * 64;
    const int tid = threadIdx.x;
    const int w = tid >> 6, l = tid & 63;
    const int lr = l & 15, lg = l >> 4;

    __shared__ __align__(16) char smem[51200];
    float* Pm = (float*)smem;                       // [64][132] fp32 scores/probs
    char* U = smem + 33792;                         // 16KB union: {KCh,KCl} / {VCt,Ps}
    float* red2 = (float*)(smem + 33792 + 16384);   // 256 floats

    const int NCT = (qb <= 30) ? 1 : 2;
    const int ncols = NCT * 64;

    f16x8 qfh0, qfh1, qfl0, qfl1;
    {
        size_t qoff = ((size_t)bh * Ss + q0 + w * 16 + lr) * HDd + lg * 8;
        qfh0 = *(const f16x8*)(qh + qoff);
        qfh1 = *(const f16x8*)(qh + qoff + 32);
        qfl0 = *(const f16x8*)(ql + qoff);
        qfl1 = *(const f16x8*)(ql + qoff + 32);
    }

    for (int ct = 0; ct < NCT; ++ct) {
        __syncthreads();
#pragma unroll
        for (int p = 0; p < 2; ++p) {
            int idx = tid + p * 256;
            int row = idx >> 3;           // chunk 0..63
            int c8 = idx & 7;
            size_t src = ((size_t)bh * NCc + ct * 64 + row) * HDd + c8 * 8;
            *(f16x8*)(U + swz(row, row * 128 + c8 * 16)) = *(const f16x8*)(kch + src);
            *(f16x8*)(U + 8192 + swz(row, row * 128 + c8 * 16)) = *(const f16x8*)(kcl + src);
        }
        __syncthreads();
#pragma unroll
        for (int kt = 0; kt < 4; ++kt) {
            int krow = kt * 16 + lr;
            f16x8 bh0 = *(const f16x8*)(U + swz(krow, krow * 128 + lg * 16));
            f16x8 bh1 = *(const f16x8*)(U + swz(krow, krow * 128 + lg * 16 + 64));
            f16x8 bl0 = *(const f16x8*)(U + 8192 + swz(krow, krow * 128 + lg * 16));
            f16x8 bl1 = *(const f16x8*)(U + 8192 + swz(krow, krow * 128 + lg * 16 + 64));
            f32x4 c = (f32x4){0.f, 0.f, 0.f, 0.f};
            c = __builtin_amdgcn_mfma_f32_16x16x32_f16(qfh0, bh0, c, 0, 0, 0);
            c = __builtin_amdgcn_mfma_f32_16x16x32_f16(qfh1, bh1, c, 0, 0, 0);
            c = __builtin_amdgcn_mfma_f32_16x16x32_f16(qfh0, bl0, c, 0, 0, 0);
            c = __builtin_amdgcn_mfma_f32_16x16x32_f16(qfh1, bl1, c, 0, 0, 0);
            c = __builtin_amdgcn_mfma_f32_16x16x32_f16(qfl0, bh0, c, 0, 0, 0);
            c = __builtin_amdgcn_mfma_f32_16x16x32_f16(qfl1, bh1, c, 0, 0, 0);
            int n = ct * 64 + kt * 16 + lr;
#pragma unroll
            for (int rg = 0; rg < 4; ++rg) {
                int row = w * 16 + 4 * lg + rg;
                int s = q0 + row;
                bool valid = (32 * n + 31 <= s);
                Pm[row * 132 + n] = valid ? c[rg] : NEGF;   // log2-domain score
            }
        }
    }
    __syncthreads();

    {
        int r = tid >> 2;
        int l4 = tid & 3;
        float m = NEGF;
        for (int c = l4; c < ncols; c += 4) m = fmaxf(m, Pm[r * 132 + c]);
        m = fmaxf(m, __shfl_xor(m, 1));
        m = fmaxf(m, __shfl_xor(m, 2));
        float sum = 0.f;
        if (m > NEGF * 0.5f) {
            for (int c = l4; c < ncols; c += 4) {
                float sv = Pm[r * 132 + c];
                float p = (sv <= NEGF * 0.5f) ? 0.f : fexp2(sv - m);
                Pm[r * 132 + c] = p;
                sum += p;
            }
        } else {
            for (int c = l4; c < ncols; c += 4) Pm[r * 132 + c] = 0.f;
        }
        sum += __shfl_xor(sum, 1);
        sum += __shfl_xor(sum, 2);
        float inv = (sum > 0.f) ? 1.f / sum : 0.f;
        for (int c = l4; c < ncols; c += 4) Pm[r * 132 + c] *= inv;
    }
    __syncthreads();

    {
        float part = 0.f;
#pragma unroll
        for (int rr = 0; rr < 16; ++rr) {
            int qq = w * 16 + rr;
            int c = 2 * l;
            if (c < ncols) {
                float2 pv2 = *(const float2*)&Pm[qq * 132 + c];
                part += pv2.x + pv2.y;
            }
        }
        red2[w * 64 + l] = part;
    }
    __syncthreads();
    if (tid < 64) {
        float tot = red2[tid] + red2[64 + tid] + red2[128 + tid] + red2[192 + tid];
        impb[((size_t)bh * NSs + qb) * NSs + tid] = tot;
    }

    f32x4 oacc[4];
#pragma unroll
    for (int dt = 0; dt < 4; ++dt) oacc[dt] = (f32x4){0.f, 0.f, 0.f, 0.f};
    char* Ps = U + 8192 + w * 2048;
    for (int ct = 0; ct < NCT; ++ct) {
        __syncthreads();
#pragma unroll
        for (int p = 0; p < 2; ++p) {
            int idx = tid + p * 256;
            int row = idx >> 3;           // d 0..63
            int c8 = idx & 7;
            size_t src = ((size_t)bh * HDd + row) * NCc + ct * 64 + c8 * 8;
            *(f16x8*)(U + swz(row, row * 128 + c8 * 16)) = *(const f16x8*)(vct + src);
        }
        {
            int r = l >> 2;
            int c0 = (l & 3) * 16;
            const float* pr = &Pm[(w * 16 + r) * 132 + ct * 64 + c0];
            float4 p0 = *(const float4*)(pr);
            float4 p1 = *(const float4*)(pr + 4);
            float4 p2 = *(const float4*)(pr + 8);
            float4 p3 = *(const float4*)(pr + 12);
            f16x8 h0, h1;
            h0[0] = (_Float16)p0.x; h0[1] = (_Float16)p0.y; h0[2] = (_Float16)p0.z; h0[3] = (_Float16)p0.w;
            h0[4] = (_Float16)p1.x; h0[5] = (_Float16)p1.y; h0[6] = (_Float16)p1.z; h0[7] = (_Float16)p1.w;
            h1[0] = (_Float16)p2.x; h1[1] = (_Float16)p2.y; h1[2] = (_Float16)p2.z; h1[3] = (_Float16)p2.w;
            h1[4] = (_Float16)p3.x; h1[5] = (_Float16)p3.y; h1[6] = (_Float16)p3.z; h1[7] = (_Float16)p3.w;
            *(f16x8*)(Ps + swz(r, r * 128 + c0 * 2)) = h0;
            *(f16x8*)(Ps + swz(r, r * 128 + c0 * 2 + 16)) = h1;
        }
        __syncthreads();
        f16x8 pa0 = *(const f16x8*)(Ps + swz(lr, lr * 128 + lg * 16));
        f16x8 pa1 = *(const f16x8*)(Ps + swz(lr, lr * 128 + lg * 16 + 64));
#pragma unroll
        for (int dt = 0; dt < 4; ++dt) {
            int vrow = dt * 16 + lr;
            f16x8 vb0 = *(const f16x8*)(U + swz(vrow, vrow * 128 + lg * 16));
            f16x8 vb1 = *(const f16x8*)(U + swz(vrow, vrow * 128 + lg * 16 + 64));
            oacc[dt] = __builtin_amdgcn_mfma_f32_16x16x32_f16(pa0, vb0, oacc[dt], 0, 0, 0);
            oacc[dt] = __builtin_amdgcn_mfma_f32_16x16x32_f16(pa1, vb1, oacc[dt], 0, 0, 0);
        }
    }

#pragma unroll
    for (int rg = 0; rg < 4; ++rg) {
        int row = w * 16 + 4 * lg + rg;
        int s = q0 + row;
        float g0 = g[((size_t)(b * Ss + s)) * 3 + 0];
#pragma unroll
        for (int dt = 0; dt < 4; ++dt)
            o[((size_t)(b * Ss + s)) * DMm + h * HDd + dt * 16 + lr] = g0 * oacc[dt][rg];
    }
}

// -------------------- K5: top-k selection -------------------------------------
__global__ __launch_bounds__(64) void k_topk(const float* __restrict__ impb,
        int* __restrict__ sel)
{
    int row = blockIdx.x * 64 + threadIdx.x;  // 16 blocks x 64 -> 1024 rows
    if (row >= Bb * Hh * NSs) return;
    int qb = row & 63;
    float v[64];
    for (int j = 0; j < 64; ++j) {
        float t = impb[(size_t)row * 64 + j];
        if (j > qb) t = NEGF;
        if (j == qb) t += 1e9f;
        v[j] = t;
    }
    for (int t = 0; t < TOPKk; ++t) {
        int bi = 0; float bv = v[0];
        for (int j = 1; j < 64; ++j) {
            if (v[j] > bv) { bv = v[j]; bi = j; }
        }
        sel[(size_t)row * TOPKk + t] = bi;
        v[bi] = -3e38f;
    }
}

// -------------------- K6: merged MFMA attention (selected + window) -----------
// Swapped QK^T (P on own q-row), exp2 softmax-lite (q pre-scaled), P packed
// in-register as 2 x f16x8; PV = 8 x mfma_16x16x32 with quad-interleaved V
// (b128 reads, same conflict-free pattern as K). XCD-aware block mapping.
__global__ __launch_bounds__(256) void k_attn2(const f16* __restrict__ qh,
        const f16* __restrict__ kh, const f16* __restrict__ vt,
        const int* __restrict__ sel, const float* __restrict__ g,
        float* __restrict__ o)
{
    const int bid = blockIdx.x + 64 * blockIdx.y;   // 0..1023
    const int bh = ((bid & 7) << 1) | ((bid >> 3) & 1);
    const int qb = bid >> 4;
    const int b = bh >> 3, h = bh & 7;
    const int q0 = qb * 64;
    const int tid = threadIdx.x;
    const int w  = tid >> 6;      // wave 0..3
    const int l  = tid & 63;
    const int lr = l & 15;
    const int lg = l >> 4;

    __shared__ __align__(16) char smem[32768];
    // K dbuf: [0,8K) [8K,16K); V dbuf: [16K,24K) [24K,32K)

    f16x8 qf0, qf1;
    {
        const f16* qptr = qh + ((size_t)bh * Ss + q0 + w * 16 + lr) * HDd + lg * 8;
        qf0 = *(const f16x8*)(qptr);
        qf1 = *(const f16x8*)(qptr + 32);
    }

    const int W0 = (qb < 8) ? (8 - qb) : 0;
    const int NT = 25 - W0;             // 16 selected + (9-W0) window
    const int* selrow = sel + ((size_t)bh * NSs + qb) * TOPKk;

    float lsum = 0.f;
    f32x4 oacc[4], osel[4];
#pragma unroll
    for (int dt = 0; dt < 4; ++dt) {
        oacc[dt] = (f32x4){0.f, 0.f, 0.f, 0.f};
        osel[dt] = (f32x4){0.f, 0.f, 0.f, 0.f};
    }

    const int srow0 = tid >> 3, sc8 = tid & 7;
    const int srow1 = (tid + 256) >> 3;
    f16x8 pk0, pk1, pv0, pv1;

    // prologue: stage tile 0 into buf 0
    int kb_cur = selrow[0];
    {
        size_t kbase = (size_t)bh * Ss + kb_cur * 64;
        pk0 = *(const f16x8*)(kh + (kbase + srow0) * HDd + sc8 * 8);
        pk1 = *(const f16x8*)(kh + (kbase + srow1) * HDd + sc8 * 8);
        pv0 = *(const f16x8*)(vt + ((size_t)bh * HDd + srow0) * Ss + kb_cur * 64 + sc8 * 8);
        pv1 = *(const f16x8*)(vt + ((size_t)bh * HDd + srow1) * Ss + kb_cur * 64 + sc8 * 8);
        *(f16x8*)(smem + swz(srow0, srow0 * 128 + sc8 * 16)) = pk0;
        *(f16x8*)(smem + swz(srow1, srow1 * 128 + sc8 * 16)) = pk1;
        STAGE_V(smem + 16384, pv0, srow0, sc8);
        STAGE_V(smem + 16384, pv1, srow1, sc8);
    }
    __syncthreads();

    int cur = 0;
    for (int t = 0; t < NT; ++t) {
        // ---- prefetch issue (next tile -> regs) -----------------------------
        int kb_nxt = 0;
        const bool hasNext = (t + 1 < NT);
        if (hasNext) {
            kb_nxt = (t + 1 < 16) ? selrow[t + 1] : (qb - 8 + W0 + (t + 1 - 16));
            size_t kbase = (size_t)bh * Ss + kb_nxt * 64;
            pk0 = *(const f16x8*)(kh + (kbase + srow0) * HDd + sc8 * 8);
            pk1 = *(const f16x8*)(kh + (kbase + srow1) * HDd + sc8 * 8);
            pv0 = *(const f16x8*)(vt + ((size_t)bh * HDd + srow0) * Ss + kb_nxt * 64 + sc8 * 8);
            pv1 = *(const f16x8*)(vt + ((size_t)bh * HDd + srow1) * Ss + kb_nxt * 64 + sc8 * 8);
        }
        const char* Kc = smem + (cur ? 8192 : 0);
        const char* Vc = smem + 16384 + (cur ? 8192 : 0);
        const bool isw = (t >= 16);
        const int kbase = kb_cur * 64;

        // ---- swapped QK^T + exp2 softmax-lite: P packed in registers --------
        f16x8 pa8[2];
        const int qpos = q0 + w * 16 + lr;
#pragma unroll
        for (int kt = 0; kt < 4; ++kt) {
            int krow = kt * 16 + lr;
            f16x8 kb0 = *(const f16x8*)(Kc + swz(krow, krow * 128 + lg * 16));
            f16x8 kb1 = *(const f16x8*)(Kc + swz(krow, krow * 128 + lg * 16 + 64));
            f32x4 c = (f32x4){0.f, 0.f, 0.f, 0.f};
            c = __builtin_amdgcn_mfma_f32_16x16x32_f16(kb0, qf0, c, 0, 0, 0);
            c = __builtin_amdgcn_mfma_f32_16x16x32_f16(kb1, qf1, c, 0, 0, 0);
#pragma unroll
            for (int rg = 0; rg < 4; ++rg) {
                int kpos = kbase + kt * 16 + 4 * lg + rg;
                bool valid = (kpos <= qpos);
                if (isw) valid = valid && (kpos > qpos - WINSZ);
                float p = fexp2(valid ? c[rg] : NEGF);   // score already log2-scaled
                lsum += p;
                pa8[kt >> 1][(kt & 1) * 4 + rg] = (_Float16)p;
            }
        }

        // ---- PV: A = packed P, B = quad-interleaved V^T (b128, conflict-free)
#pragma unroll
        for (int dt = 0; dt < 4; ++dt) {
            int vrow = dt * 16 + lr;
#pragma unroll
            for (int ktp = 0; ktp < 2; ++ktp) {
                f16x8 vb = *(const f16x8*)(Vc + swz(vrow, vrow * 128 + ktp * 64 + lg * 16));
                oacc[dt] = __builtin_amdgcn_mfma_f32_16x16x32_f16(pa8[ktp], vb, oacc[dt], 0, 0, 0);
            }
        }

        // ---- phase boundary: snapshot selected result, reset ----------------
        if (t == 15) {
            float s = lsum;
            s += __shfl_xor(s, 16);
            s += __shfl_xor(s, 32);
            float inv = 1.f / s;
#pragma unroll
            for (int rg = 0; rg < 4; ++rg) {
                float invq = __shfl(inv, 4 * lg + rg);
#pragma unroll
                for (int dt = 0; dt < 4; ++dt) osel[dt][rg] = oacc[dt][rg] * invq;
            }
#pragma unroll
            for (int dt = 0; dt < 4; ++dt) oacc[dt] = (f32x4){0.f, 0.f, 0.f, 0.f};
            lsum = 0.f;
        }

        // ---- write prefetched tile into the other buffer --------------------
        if (hasNext) {
            char* Kn = smem + (cur ? 0 : 8192);
            char* Vn = smem + 16384 + (cur ? 0 : 8192);
            *(f16x8*)(Kn + swz(srow0, srow0 * 128 + sc8 * 16)) = pk0;
            *(f16x8*)(Kn + swz(srow1, srow1 * 128 + sc8 * 16)) = pk1;
            STAGE_V(Vn, pv0, srow0, sc8);
            STAGE_V(Vn, pv1, srow1, sc8);
        }
        __syncthreads();
        cur ^= 1;
        kb_cur = kb_nxt;
    }

    // ---- epilogue: combine phases, gate, single coalesced RMW ---------------
    float* Os = (float*)smem;
    {
        float s = lsum;
        s += __shfl_xor(s, 16);
        s += __shfl_xor(s, 32);
        float inv = 1.f / s;
#pragma unroll
        for (int rg = 0; rg < 4; ++rg) {
            float invq = __shfl(inv, 4 * lg + rg);
            int row = w * 16 + 4 * lg + rg;
            int sq = q0 + row;
            float g1 = g[((size_t)(b * Ss + sq)) * 3 + 1];
            float g2 = g[((size_t)(b * Ss + sq)) * 3 + 2];
#pragma unroll
            for (int dt = 0; dt < 4; ++dt)
                Os[row * 68 + dt * 16 + lr] = g1 * osel[dt][rg] + g2 * oacc[dt][rg] * invq;
        }
    }
    __syncthreads();
    {
        int row = tid >> 2;
        int c0 = (tid & 3) * 16;
        int s = q0 + row;
        float* op = o + ((size_t)(b * Ss + s)) * DMm + h * HDd + c0;
#pragma unroll
        for (int j = 0; j < 4; ++j) {
            float4 val = *(const float4*)&Os[row * 68 + c0 + j * 4];
            float4 cur4 = *(const float4*)&op[j * 4];
            cur4.x += val.x; cur4.y += val.y;
            cur4.z += val.z; cur4.w += val.w;
            *(float4*)&op[j * 4] = cur4;
        }
    }
}

// -------------------- constant emitter (host-side contract checks) ------------
__global__ __launch_bounds__(256) void k_const(float* __restrict__ y, float val)
{
    int i = blockIdx.x * 256 + threadIdx.x;
    y[i] = val;
}

// -------------------- launch --------------------------------------------------
extern "C" void kernel_launch(void* const* d_in, const int* in_sizes, int n_in,
                              void* d_out, int out_size, void* d_ws, size_t ws_size,
                              hipStream_t stream) {
    float* y = (float*)d_out;
    if (n_in != 6) {
        k_const<<<dim3(16384), 256, 0, stream>>>(y, 88888.f);
        return;
    }
    if (in_sizes[0] != 4194304 || in_sizes[1] != 262144 || in_sizes[2] != 262144 ||
        in_sizes[3] != 262144 || in_sizes[4] != 262144 || in_sizes[5] != 1536) {
        k_const<<<dim3(16384), 256, 0, stream>>>(y, 77777.f);
        return;
    }
    if (ws_size < WS_FLOATS * sizeof(float)) {
        k_const<<<dim3(16384), 256, 0, stream>>>(y, 66666.f);
        return;
    }

    const float* x  = (const float*)d_in[0];
    const float* Wq = (const float*)d_in[1];
    const float* Wk = (const float*)d_in[2];
    const float* Wv = (const float*)d_in[3];
    const float* Wo = (const float*)d_in[4];
    const float* Wg = (const float*)d_in[5];
    float* ws = (float*)d_ws;

    float* kw   = ws + OFF_K;
    float* vw   = ws + OFF_V;
    float* ow   = ws + OFF_O;
    float* gw   = ws + OFF_G;
    float* impw = ws + OFF_IMPB;
    int*   selw = (int*)(ws + OFF_SEL);
    f16*   qhw  = (f16*)(ws + OFF_QH);
    f16*   qlw  = (f16*)(ws + OFF_QL);
    f16*   khw  = (f16*)(ws + OFF_KH);
    f16*   vtw  = (f16*)(ws + OFF_VT);
    f16*   kchw = (f16*)(ws + OFF_KCH);
    f16*   kclw = (f16*)(ws + OFF_KCL);
    f16*   vctw = (f16*)(ws + OFF_VCT);
    f16*   xhw  = (f16*)(ws + OFF_XH);   // aliases o region (freed before k_cmp)
    f16*   xlw  = (f16*)(ws + OFF_XL);
    f16*   wqh  = (f16*)(ws + OFF_WT);
    f16*   wql  = (f16*)(ws + OFF_WT + 131072);
    f16*   wkh  = (f16*)(ws + OFF_WT + 262144);
    f16*   wkl  = (f16*)(ws + OFF_WT + 393216);
    f16*   wvh  = (f16*)(ws + OFF_WT + 524288);
    f16*   wvl  = (f16*)(ws + OFF_WT + 655360);
    f16*   woh  = (f16*)(ws + OFF_WT + 786432);

    k_prep_x<<<dim3(2048), 256, 0, stream>>>(x, xhw, xlw);
    k_prep_w<<<dim3(8, 8, 4), 256, 0, stream>>>(Wq, Wk, Wv, Wo,
            wqh, wql, wkh, wkl, wvh, wvl, woh);
    // q: split GEMM -> f16 hi/lo pre-scaled by PSC (log2-domain softmax)
    k_gemm<1, 0, 0><<<dim3(64, 8), 256, 0, stream>>>(xhw, xlw, (const float*)0,
            wqh, wql, (float*)0, qhw, qlw, PSC);
    // k: split GEMM -> fp32 (for pooling) + f16 hi (selection-safe)
    k_gemm<1, 0, 0><<<dim3(64, 8), 256, 0, stream>>>(xhw, xlw, (const float*)0,
            wkh, wkl, kw, khw, (f16*)0, 1.f);
    // v: PLAIN f16 GEMM (V never affects selection; f16 quantized downstream)
    k_gemm<0, 0, 0><<<dim3(64, 8), 256, 0, stream>>>(xhw, (const f16*)0, (const float*)0,
            wvh, (const f16*)0, vw, (f16*)0, (f16*)0, 1.f);
    k_gate<<<dim3(2048), 256, 0, stream>>>(x, Wg, gw);
    k_cvt_vt<<<dim3(64, 16), 256, 0, stream>>>(vw, vtw);
    k_pool<<<dim3(512), 256, 0, stream>>>(kw, vw, kchw, kclw, vctw);
    k_cmp<<<dim3(64, 16), 256, 0, stream>>>(qhw, qlw, kchw, kclw, vctw, gw, impw, ow);
    k_topk<<<dim3(16), 64, 0, stream>>>(impw, selw);
    k_attn2<<<dim3(64, 16), 256, 0, stream>>>(qhw, khw, vtw, selw, gw, ow);
    k_gemm<0, 1, 1><<<dim3(64, 8), 256, 0, stream>>>((const f16*)0, (const f16*)0,
            ow, woh, (const f16*)0, y, (f16*)0, (f16*)0, 1.f);
}

// Round 9
// 260.885 us; speedup vs baseline: 5.5246x; 1.1326x over previous
//
#include <hip/hip_runtime.h>

// Problem constants
#define Hh    8
#define DMm   512
#define HDd   64
#define CBc   32
#define SBs   64
#define WINSZ 512
#define TOPKk 16
#define NEGF  (-1e30f)
#define Bb    2
#define Ss    4096
#define NCc   128   // S/CB
#define NSs   64    // S/SB
#define SCALE 0.125f
#define PSC   0.18033688011112042f   // SCALE * log2(e): q pre-scale -> exp2 softmax

// Workspace layout (float offsets)
#define OFF_KL   ((size_t)4194304)    // f16 k_lo [bh][s][d] (reuses old fp32-k region)
#define OFF_O    ((size_t)12582912)   // ALIASED: x_hi/x_lo live here until k_cmp writes o
#define OFF_G    ((size_t)16777216)   // B*S*3 = 24576
#define OFF_KC   ((size_t)16801792)   // kc_hi/kc_lo f16 (2 x 131072 halves)
#define OFF_VC   ((size_t)16932864)   // vc^T f16 (131072 halves)
#define OFF_IMPB ((size_t)17063936)   // B*H*NS*NS = 65536
#define OFF_SEL  ((size_t)17129472)   // B*H*NS*TOPK ints = 16384
#define OFF_QH   ((size_t)17145856)   // f16 q  [bh][s][d] (pre-scaled by PSC)
#define OFF_KH   ((size_t)19243008)   // f16 k_hi [bh][s][d]
#define OFF_VT   ((size_t)21340160)   // f16 v^T [bh][d][s]
#define OFF_WT   ((size_t)23437312)   // 7 x 131072 floats of f16 W^T (hi/lo)
#define OFF_QL   ((size_t)24354816)   // f16 q_lo [bh][s][d] (pre-scaled by PSC)
#define WS_FLOATS ((size_t)25403392)

// x_hi/x_lo alias the o region (o first written by k_cmp, after GEMMs)
#define OFF_XH   (OFF_O)
#define OFF_XL   (OFF_O + 2097152)

#define OFF_KCH  (OFF_KC)
#define OFF_KCL  (OFF_KC + 65536)
#define OFF_VCT  (OFF_VC)

typedef _Float16 f16;
typedef _Float16 f16x4 __attribute__((ext_vector_type(4)));
typedef _Float16 f16x8 __attribute__((ext_vector_type(8)));
typedef float    f32x4 __attribute__((ext_vector_type(4)));

__device__ __forceinline__ int swz(int row, int byteoff) {
    return byteoff ^ ((row & 7) << 4);   // spreads stride-128B rows across banks
}
__device__ __forceinline__ float fexp2(float x) {
    return __builtin_amdgcn_exp2f(x);    // v_exp_f32: D = 2^S0
}

// V LDS layout: per 32-key block, quads interleaved as {4lg, 16+4lg} so that a
// single b128 read at [ktp*64 + lg*16] yields keys {ktp*32+4lg+0..3, +16+0..3}
// (matches in-register P order for mfma_16x16x32). Write side: 2 x b64.
#define STAGE_V(Vbase, vd, row, c8) do {                                     \
    int q0_ = ((c8) & 3) * 2, q1_ = q0_ + 1;                                 \
    int col0_ = ((c8) >> 2) * 64 + (q0_ & 3) * 16 + (q0_ >> 2) * 8;          \
    int col1_ = ((c8) >> 2) * 64 + (q1_ & 3) * 16 + (q1_ >> 2) * 8;          \
    f16x4 lo_ = { (vd)[0], (vd)[1], (vd)[2], (vd)[3] };                      \
    f16x4 hi_ = { (vd)[4], (vd)[5], (vd)[6], (vd)[7] };                      \
    *(f16x4*)((Vbase) + swz(row, (row) * 128 + col0_)) = lo_;                \
    *(f16x4*)((Vbase) + swz(row, (row) * 128 + col1_)) = hi_;                \
} while (0)

// -------------------- K0a: x -> x_hi, x_lo (f16 split) ------------------------
__global__ __launch_bounds__(256) void k_prep_x(const float* __restrict__ x,
        f16* __restrict__ xh, f16* __restrict__ xl)
{
    size_t base = ((size_t)blockIdx.x * 256 + threadIdx.x) * 8;   // covers 4194304
    float4 a = *(const float4*)(x + base);
    float4 b = *(const float4*)(x + base + 4);
    f16x8 h, l;
    h[0] = (_Float16)a.x; l[0] = (_Float16)(a.x - (float)h[0]);
    h[1] = (_Float16)a.y; l[1] = (_Float16)(a.y - (float)h[1]);
    h[2] = (_Float16)a.z; l[2] = (_Float16)(a.z - (float)h[2]);
    h[3] = (_Float16)a.w; l[3] = (_Float16)(a.w - (float)h[3]);
    h[4] = (_Float16)b.x; l[4] = (_Float16)(b.x - (float)h[4]);
    h[5] = (_Float16)b.y; l[5] = (_Float16)(b.y - (float)h[5]);
    h[6] = (_Float16)b.z; l[6] = (_Float16)(b.z - (float)h[6]);
    h[7] = (_Float16)b.w; l[7] = (_Float16)(b.w - (float)h[7]);
    *(f16x8*)(xh + base) = h;
    *(f16x8*)(xl + base) = l;
}

// -------------------- K0b: W -> W^T hi/lo (f16) -------------------------------
__global__ __launch_bounds__(256) void k_prep_w(
        const float* __restrict__ Wq, const float* __restrict__ Wk,
        const float* __restrict__ Wv, const float* __restrict__ Wo,
        f16* __restrict__ wqh, f16* __restrict__ wql,
        f16* __restrict__ wkh, f16* __restrict__ wkl,
        f16* __restrict__ wvh, f16* __restrict__ wvl,
        f16* __restrict__ woh)
{
    const int k0 = blockIdx.x * 64;
    const int n0 = blockIdx.y * 64;
    const int z = blockIdx.z;
    const float* W = (z == 0) ? Wq : ((z == 1) ? Wk : ((z == 2) ? Wv : Wo));
    f16* dh = (z == 0) ? wqh : ((z == 1) ? wkh : ((z == 2) ? wvh : woh));
    f16* dl = (z == 0) ? wql : ((z == 1) ? wkl : ((z == 2) ? wvl : (f16*)0));
    __shared__ float T[64][68];
    const int tid = threadIdx.x;
    {
        int r = tid >> 2;
        int c16 = (tid & 3) * 16;
#pragma unroll
        for (int j = 0; j < 4; ++j) {
            float4 w4 = *(const float4*)(W + (size_t)(k0 + r) * DMm + n0 + c16 + j * 4);
            *(float4*)&T[r][c16 + j * 4] = w4;
        }
    }
    __syncthreads();
    {
        int n = tid >> 2;
        int k16 = (tid & 3) * 16;
        f16x8 h0, h1, l0, l1;
#pragma unroll
        for (int j = 0; j < 8; ++j) {
            float wv = T[k16 + j][n];
            h0[j] = (_Float16)wv; l0[j] = (_Float16)(wv - (float)h0[j]);
        }
#pragma unroll
        for (int j = 0; j < 8; ++j) {
            float wv = T[k16 + 8 + j][n];
            h1[j] = (_Float16)wv; l1[j] = (_Float16)(wv - (float)h1[j]);
        }
        size_t o = (size_t)(n0 + n) * DMm + k0 + k16;
        *(f16x8*)(dh + o) = h0;
        *(f16x8*)(dh + o + 8) = h1;
        if (dl) { *(f16x8*)(dl + o) = l0; *(f16x8*)(dl + o + 8) = l1; }
    }
}

// -------------------- K1: MFMA GEMM (128x64 tile, BK=32) ----------------------
// cscale applies to the f16 hi/lo output only (q pre-scaling for exp2 softmax).
template <int SPLIT, int AF32, int OUTM>
__global__ __launch_bounds__(256) void k_gemm(
        const f16* __restrict__ Ah, const f16* __restrict__ Al,
        const float* __restrict__ Af,
        const f16* __restrict__ Bh, const f16* __restrict__ Bl,
        float* __restrict__ Cf, f16* __restrict__ Ch, f16* __restrict__ Cl,
        float cscale)
{
    const int m0 = blockIdx.x * 128;
    const int n0 = blockIdx.y * 64;
    const int tid = threadIdx.x;
    const int w = tid >> 6, l = tid & 63;
    const int lr = l & 15, lg = l >> 4;
    const int wm = w >> 1, wn = w & 1;

    __shared__ f16 As[SPLIT ? 2 : 1][128 * 40];
    __shared__ f16 Bs[SPLIT ? 2 : 1][64 * 40];

    f32x4 acc[4][2];
#pragma unroll
    for (int mf = 0; mf < 4; ++mf)
#pragma unroll
        for (int nf = 0; nf < 2; ++nf) acc[mf][nf] = (f32x4){0.f, 0.f, 0.f, 0.f};

    const int ar = tid >> 1, ac = (tid & 1) * 16;
    const int bn = tid >> 2, bc = (tid & 3) * 8;

    for (int k0 = 0; k0 < DMm; k0 += 32) {
        if (AF32) {
            const float* src = Af + (size_t)(m0 + ar) * DMm + k0 + ac;
            float4 a0 = *(const float4*)(src);
            float4 a1 = *(const float4*)(src + 4);
            float4 a2 = *(const float4*)(src + 8);
            float4 a3 = *(const float4*)(src + 12);
            f16x8 h0, h1;
            h0[0] = (_Float16)a0.x; h0[1] = (_Float16)a0.y; h0[2] = (_Float16)a0.z; h0[3] = (_Float16)a0.w;
            h0[4] = (_Float16)a1.x; h0[5] = (_Float16)a1.y; h0[6] = (_Float16)a1.z; h0[7] = (_Float16)a1.w;
            h1[0] = (_Float16)a2.x; h1[1] = (_Float16)a2.y; h1[2] = (_Float16)a2.z; h1[3] = (_Float16)a2.w;
            h1[4] = (_Float16)a3.x; h1[5] = (_Float16)a3.y; h1[6] = (_Float16)a3.z; h1[7] = (_Float16)a3.w;
            *(f16x8*)&As[0][ar * 40 + ac] = h0;
            *(f16x8*)&As[0][ar * 40 + ac + 8] = h1;
        } else {
            const f16* src = Ah + (size_t)(m0 + ar) * DMm + k0 + ac;
            *(f16x8*)&As[0][ar * 40 + ac] = *(const f16x8*)src;
            *(f16x8*)&As[0][ar * 40 + ac + 8] = *(const f16x8*)(src + 8);
            if (SPLIT) {
                const f16* src2 = Al + (size_t)(m0 + ar) * DMm + k0 + ac;
                *(f16x8*)&As[SPLIT ? 1 : 0][ar * 40 + ac] = *(const f16x8*)src2;
                *(f16x8*)&As[SPLIT ? 1 : 0][ar * 40 + ac + 8] = *(const f16x8*)(src2 + 8);
            }
        }
        {
            const f16* src = Bh + (size_t)(n0 + bn) * DMm + k0 + bc;
            *(f16x8*)&Bs[0][bn * 40 + bc] = *(const f16x8*)src;
            if (SPLIT) {
                const f16* src2 = Bl + (size_t)(n0 + bn) * DMm + k0 + bc;
                *(f16x8*)&Bs[SPLIT ? 1 : 0][bn * 40 + bc] = *(const f16x8*)src2;
            }
        }
        __syncthreads();

        f16x8 ahf[4], alf[4], bhf[2], blf[2];
#pragma unroll
        for (int mf = 0; mf < 4; ++mf) {
            int row = wm * 64 + mf * 16 + lr;
            ahf[mf] = *(const f16x8*)&As[0][row * 40 + lg * 8];
            if (SPLIT) alf[mf] = *(const f16x8*)&As[SPLIT ? 1 : 0][row * 40 + lg * 8];
        }
#pragma unroll
        for (int nf = 0; nf < 2; ++nf) {
            int row = wn * 32 + nf * 16 + lr;
            bhf[nf] = *(const f16x8*)&Bs[0][row * 40 + lg * 8];
            if (SPLIT) blf[nf] = *(const f16x8*)&Bs[SPLIT ? 1 : 0][row * 40 + lg * 8];
        }
#pragma unroll
        for (int mf = 0; mf < 4; ++mf)
#pragma unroll
            for (int nf = 0; nf < 2; ++nf) {
                acc[mf][nf] = __builtin_amdgcn_mfma_f32_16x16x32_f16(ahf[mf], bhf[nf], acc[mf][nf], 0, 0, 0);
                if (SPLIT) {
                    acc[mf][nf] = __builtin_amdgcn_mfma_f32_16x16x32_f16(ahf[mf], blf[nf], acc[mf][nf], 0, 0, 0);
                    acc[mf][nf] = __builtin_amdgcn_mfma_f32_16x16x32_f16(alf[mf], bhf[nf], acc[mf][nf], 0, 0, 0);
                }
            }
        __syncthreads();
    }

#pragma unroll
    for (int mf = 0; mf < 4; ++mf)
#pragma unroll
        for (int nf = 0; nf < 2; ++nf)
#pragma unroll
            for (int rg = 0; rg < 4; ++rg) {
                int m = m0 + wm * 64 + mf * 16 + 4 * lg + rg;
                int n = n0 + wn * 32 + nf * 16 + lr;
                float val = acc[mf][nf][rg];
                if (OUTM == 0) {
                    int b = m >> 12, s = m & 4095;
                    int h = n >> 6, d = n & 63;
                    size_t o = (((size_t)(b * Hh + h)) * Ss + s) * HDd + d;
                    if (Cf) Cf[o] = val;
                    if (Ch) {
                        float vs = val * cscale;
                        f16 hv = (f16)vs;
                        Ch[o] = hv;
                        if (Cl) Cl[o] = (f16)(vs - (float)hv);
                    }
                } else {
                    Cf[(size_t)m * DMm + n] = val;
                }
            }
}

// -------------------- K1b: swapped-operand GEMM -> vt f16 [bh][d][s] ----------
// mfma(B,A): C row-axis (4lg+rg) = B rows (n/d), col-axis (lr) = A rows (m/s)
// -> transposed output with s-contiguous (coalesced) stores. Plain f16.
__global__ __launch_bounds__(256) void k_gemm_tv(const f16* __restrict__ Ah,
        const f16* __restrict__ Bh, f16* __restrict__ vt)
{
    const int m0 = blockIdx.x * 128;   // s-dim (8192 rows incl batch)
    const int n0 = blockIdx.y * 64;    // d-dim (one head)
    const int tid = threadIdx.x;
    const int w = tid >> 6, l = tid & 63;
    const int lr = l & 15, lg = l >> 4;
    const int wm = w >> 1, wn = w & 1;

    __shared__ f16 As[128 * 40];
    __shared__ f16 Bs[64 * 40];

    f32x4 acc[4][2];
#pragma unroll
    for (int mf = 0; mf < 4; ++mf)
#pragma unroll
        for (int nf = 0; nf < 2; ++nf) acc[mf][nf] = (f32x4){0.f, 0.f, 0.f, 0.f};

    const int ar = tid >> 1, ac = (tid & 1) * 16;
    const int bn = tid >> 2, bc = (tid & 3) * 8;

    for (int k0 = 0; k0 < DMm; k0 += 32) {
        {
            const f16* src = Ah + (size_t)(m0 + ar) * DMm + k0 + ac;
            *(f16x8*)&As[ar * 40 + ac] = *(const f16x8*)src;
            *(f16x8*)&As[ar * 40 + ac + 8] = *(const f16x8*)(src + 8);
            const f16* srcb = Bh + (size_t)(n0 + bn) * DMm + k0 + bc;
            *(f16x8*)&Bs[bn * 40 + bc] = *(const f16x8*)srcb;
        }
        __syncthreads();
        f16x8 ahf[4], bhf[2];
#pragma unroll
        for (int mf = 0; mf < 4; ++mf)
            ahf[mf] = *(const f16x8*)&As[(wm * 64 + mf * 16 + lr) * 40 + lg * 8];
#pragma unroll
        for (int nf = 0; nf < 2; ++nf)
            bhf[nf] = *(const f16x8*)&Bs[(wn * 32 + nf * 16 + lr) * 40 + lg * 8];
#pragma unroll
        for (int mf = 0; mf < 4; ++mf)
#pragma unroll
            for (int nf = 0; nf < 2; ++nf)
                acc[mf][nf] = __builtin_amdgcn_mfma_f32_16x16x32_f16(bhf[nf], ahf[mf], acc[mf][nf], 0, 0, 0);
        __syncthreads();
    }
    const int h = n0 >> 6;
#pragma unroll
    for (int mf = 0; mf < 4; ++mf)
#pragma unroll
        for (int nf = 0; nf < 2; ++nf)
#pragma unroll
            for (int rg = 0; rg < 4; ++rg) {
                int n = n0 + wn * 32 + nf * 16 + 4 * lg + rg;   // d (global)
                int m = m0 + wm * 64 + mf * 16 + lr;            // s (incl batch)
                int b = m >> 12, s = m & 4095;
                vt[(((size_t)(b * Hh + h)) * HDd + (n & 63)) * Ss + s] =
                    (f16)acc[mf][nf][rg];
            }
}

// -------------------- K2: gate = sigmoid(x @ Wg), wave-per-row ----------------
__global__ __launch_bounds__(256) void k_gate(const float* __restrict__ x,
        const float* __restrict__ Wg, float* __restrict__ g)
{
    const int row = blockIdx.x * 4 + (threadIdx.x >> 6);   // 2048 blocks x 4 waves
    const int l = threadIdx.x & 63;
    const int d0 = l * 8;
    const float* xr = x + (size_t)row * DMm + d0;
    float4 a = *(const float4*)(xr);
    float4 b = *(const float4*)(xr + 4);
    float xv[8] = { a.x, a.y, a.z, a.w, b.x, b.y, b.z, b.w };
    float s0 = 0.f, s1 = 0.f, s2 = 0.f;
#pragma unroll
    for (int j = 0; j < 8; ++j) {
        const float* wr = Wg + (size_t)(d0 + j) * 3;
        s0 += xv[j] * wr[0];
        s1 += xv[j] * wr[1];
        s2 += xv[j] * wr[2];
    }
#pragma unroll
    for (int off = 1; off < 64; off <<= 1) {
        s0 += __shfl_xor(s0, off);
        s1 += __shfl_xor(s1, off);
        s2 += __shfl_xor(s2, off);
    }
    if (l == 0) {
        g[(size_t)row * 3 + 0] = 1.f / (1.f + expf(-s0));
        g[(size_t)row * 3 + 1] = 1.f / (1.f + expf(-s1));
        g[(size_t)row * 3 + 2] = 1.f / (1.f + expf(-s2));
    }
}

// -------------------- K3: mean-pool from f16 k_hi/k_lo and vt -----------------
// kc = mean over 32 rows of (k_hi + k_lo) in fp32 (selection-grade, ~2^-22 err).
// vc pooled from vt [bh][d][s]: 64B-contiguous reads, fully coalesced.
__global__ __launch_bounds__(256) void k_pool(const f16* __restrict__ kh,
        const f16* __restrict__ kl, const f16* __restrict__ vt,
        f16* __restrict__ kch, f16* __restrict__ kcl, f16* __restrict__ vct)
{
    int idx = blockIdx.x * 256 + threadIdx.x;  // B*H*NC*HD = 131072
    int bh = idx >> 13;
    {
        int d = idx & 63;
        int n = (idx >> 6) & 127;
        const f16* kp = kh + ((size_t)bh * Ss + n * CBc) * HDd + d;
        const f16* lp = kl + ((size_t)bh * Ss + n * CBc) * HDd + d;
        float sk = 0.f;
        for (int t = 0; t < CBc; ++t)
            sk += (float)kp[(size_t)t * HDd] + (float)lp[(size_t)t * HDd];
        float mk = sk * (1.f / CBc);
        f16 h = (f16)mk;
        kch[idx] = h;
        kcl[idx] = (f16)(mk - (float)h);
    }
    {
        int vd = (idx >> 7) & 63;
        int vn = idx & 127;
        const f16* vp = vt + ((size_t)bh * HDd + vd) * Ss + vn * CBc;
        float sv = 0.f;
#pragma unroll
        for (int j = 0; j < 4; ++j) {
            f16x8 v8 = *(const f16x8*)(vp + j * 8);
#pragma unroll
            for (int e = 0; e < 8; ++e) sv += (float)v8[e];
        }
        vct[((size_t)bh * HDd + vd) * NCc + vn] = (f16)(sv * (1.f / CBc));
    }
}

// -------------------- K4: compressed attention + importance (split-f16 MFMA) --
// q pre-scaled by PSC -> scores in log2 domain -> exp2 softmax (equivalent).
__global__ __launch_bounds__(256) void k_cmp(const f16* __restrict__ qh,
        const f16* __restrict__ ql, const f16* __restrict__ kch,
        const f16* __restrict__ kcl, const f16* __restrict__ vct,
        const float* __restrict__ g, float* __restrict__ impb, float* __restrict__ o)
{
    const int qb = blockIdx.x;   // 0..63
    const int bh = blockIdx.y;   // 0..15
    const int b = bh >> 3, h = bh & 7;
    const int q0 = qb * 64;
    const int tid = threadIdx.x;
    const int w = tid >> 6, l = tid & 63;
    const int lr = l & 15, lg = l >> 4;

    __shared__ __align__(16) char smem[51200];
    float* Pm = (float*)smem;                       // [64][132] fp32 scores/probs
    char* U = smem + 33792;                         // 16KB union: {KCh,KCl} / {VCt,Ps}
    float* red2 = (float*)(smem + 33792 + 16384);   // 256 floats

    const int NCT = (qb <= 30) ? 1 : 2;
    const int ncols = NCT * 64;

    f16x8 qfh0, qfh1, qfl0, qfl1;
    {
        size_t qoff = ((size_t)bh * Ss + q0 + w * 16 + lr) * HDd + lg * 8;
        qfh0 = *(const f16x8*)(qh + qoff);
        qfh1 = *(const f16x8*)(qh + qoff + 32);
        qfl0 = *(const f16x8*)(ql + qoff);
        qfl1 = *(const f16x8*)(ql + qoff + 32);
    }

    for (int ct = 0; ct < NCT; ++ct) {
        __syncthreads();
#pragma unroll
        for (int p = 0; p < 2; ++p) {
            int idx = tid + p * 256;
            int row = idx >> 3;           // chunk 0..63
            int c8 = idx & 7;
            size_t src = ((size_t)bh * NCc + ct * 64 + row) * HDd + c8 * 8;
            *(f16x8*)(U + swz(row, row * 128 + c8 * 16)) = *(const f16x8*)(kch + src);
            *(f16x8*)(U + 8192 + swz(row, row * 128 + c8 * 16)) = *(const f16x8*)(kcl + src);
        }
        __syncthreads();
#pragma unroll
        for (int kt = 0; kt < 4; ++kt) {
            int krow = kt * 16 + lr;
            f16x8 bh0 = *(const f16x8*)(U + swz(krow, krow * 128 + lg * 16));
            f16x8 bh1 = *(const f16x8*)(U + swz(krow, krow * 128 + lg * 16 + 64));
            f16x8 bl0 = *(const f16x8*)(U + 8192 + swz(krow, krow * 128 + lg * 16));
            f16x8 bl1 = *(const f16x8*)(U + 8192 + swz(krow, krow * 128 + lg * 16 + 64));
            f32x4 c = (f32x4){0.f, 0.f, 0.f, 0.f};
            c = __builtin_amdgcn_mfma_f32_16x16x32_f16(qfh0, bh0, c, 0, 0, 0);
            c = __builtin_amdgcn_mfma_f32_16x16x32_f16(qfh1, bh1, c, 0, 0, 0);
            c = __builtin_amdgcn_mfma_f32_16x16x32_f16(qfh0, bl0, c, 0, 0, 0);
            c = __builtin_amdgcn_mfma_f32_16x16x32_f16(qfh1, bl1, c, 0, 0, 0);
            c = __builtin_amdgcn_mfma_f32_16x16x32_f16(qfl0, bh0, c, 0, 0, 0);
            c = __builtin_amdgcn_mfma_f32_16x16x32_f16(qfl1, bh1, c, 0, 0, 0);
            int n = ct * 64 + kt * 16 + lr;
#pragma unroll
            for (int rg = 0; rg < 4; ++rg) {
                int row = w * 16 + 4 * lg + rg;
                int s = q0 + row;
                bool valid = (32 * n + 31 <= s);
                Pm[row * 132 + n] = valid ? c[rg] : NEGF;   // log2-domain score
            }
        }
    }
    __syncthreads();

    {
        int r = tid >> 2;
        int l4 = tid & 3;
        float m = NEGF;
        for (int c = l4; c < ncols; c += 4) m = fmaxf(m, Pm[r * 132 + c]);
        m = fmaxf(m, __shfl_xor(m, 1));
        m = fmaxf(m, __shfl_xor(m, 2));
        float sum = 0.f;
        if (m > NEGF * 0.5f) {
            for (int c = l4; c < ncols; c += 4) {
                float sv = Pm[r * 132 + c];
                float p = (sv <= NEGF * 0.5f) ? 0.f : fexp2(sv - m);
                Pm[r * 132 + c] = p;
                sum += p;
            }
        } else {
            for (int c = l4; c < ncols; c += 4) Pm[r * 132 + c] = 0.f;
        }
        sum += __shfl_xor(sum, 1);
        sum += __shfl_xor(sum, 2);
        float inv = (sum > 0.f) ? 1.f / sum : 0.f;
        for (int c = l4; c < ncols; c += 4) Pm[r * 132 + c] *= inv;
    }
    __syncthreads();

    {
        float part = 0.f;
#pragma unroll
        for (int rr = 0; rr < 16; ++rr) {
            int qq = w * 16 + rr;
            int c = 2 * l;
            if (c < ncols) {
                float2 pv2 = *(const float2*)&Pm[qq * 132 + c];
                part += pv2.x + pv2.y;
            }
        }
        red2[w * 64 + l] = part;
    }
    __syncthreads();
    if (tid < 64) {
        float tot = red2[tid] + red2[64 + tid] + red2[128 + tid] + red2[192 + tid];
        impb[((size_t)bh * NSs + qb) * NSs + tid] = tot;
    }

    f32x4 oacc[4];
#pragma unroll
    for (int dt = 0; dt < 4; ++dt) oacc[dt] = (f32x4){0.f, 0.f, 0.f, 0.f};
    char* Ps = U + 8192 + w * 2048;
    for (int ct = 0; ct < NCT; ++ct) {
        __syncthreads();
#pragma unroll
        for (int p = 0; p < 2; ++p) {
            int idx = tid + p * 256;
            int row = idx >> 3;           // d 0..63
            int c8 = idx & 7;
            size_t src = ((size_t)bh * HDd + row) * NCc + ct * 64 + c8 * 8;
            *(f16x8*)(U + swz(row, row * 128 + c8 * 16)) = *(const f16x8*)(vct + src);
        }
        {
            int r = l >> 2;
            int c0 = (l & 3) * 16;
            const float* pr = &Pm[(w * 16 + r) * 132 + ct * 64 + c0];
            float4 p0 = *(const float4*)(pr);
            float4 p1 = *(const float4*)(pr + 4);
            float4 p2 = *(const float4*)(pr + 8);
            float4 p3 = *(const float4*)(pr + 12);
            f16x8 h0, h1;
            h0[0] = (_Float16)p0.x; h0[1] = (_Float16)p0.y; h0[2] = (_Float16)p0.z; h0[3] = (_Float16)p0.w;
            h0[4] = (_Float16)p1.x; h0[5] = (_Float16)p1.y; h0[6] = (_Float16)p1.z; h0[7] = (_Float16)p1.w;
            h1[0] = (_Float16)p2.x; h1[1] = (_Float16)p2.y; h1[2] = (_Float16)p2.z; h1[3] = (_Float16)p2.w;
            h1[4] = (_Float16)p3.x; h1[5] = (_Float16)p3.y; h1[6] = (_Float16)p3.z; h1[7] = (_Float16)p3.w;
            *(f16x8*)(Ps + swz(r, r * 128 + c0 * 2)) = h0;
            *(f16x8*)(Ps + swz(r, r * 128 + c0 * 2 + 16)) = h1;
        }
        __syncthreads();
        f16x8 pa0 = *(const f16x8*)(Ps + swz(lr, lr * 128 + lg * 16));
        f16x8 pa1 = *(const f16x8*)(Ps + swz(lr, lr * 128 + lg * 16 + 64));
#pragma unroll
        for (int dt = 0; dt < 4; ++dt) {
            int vrow = dt * 16 + lr;
            f16x8 vb0 = *(const f16x8*)(U + swz(vrow, vrow * 128 + lg * 16));
            f16x8 vb1 = *(const f16x8*)(U + swz(vrow, vrow * 128 + lg * 16 + 64));
            oacc[dt] = __builtin_amdgcn_mfma_f32_16x16x32_f16(pa0, vb0, oacc[dt], 0, 0, 0);
            oacc[dt] = __builtin_amdgcn_mfma_f32_16x16x32_f16(pa1, vb1, oacc[dt], 0, 0, 0);
        }
    }

#pragma unroll
    for (int rg = 0; rg < 4; ++rg) {
        int row = w * 16 + 4 * lg + rg;
        int s = q0 + row;
        float g0 = g[((size_t)(b * Ss + s)) * 3 + 0];
#pragma unroll
        for (int dt = 0; dt < 4; ++dt)
            o[((size_t)(b * Ss + s)) * DMm + h * HDd + dt * 16 + lr] = g0 * oacc[dt][rg];
    }
}

// -------------------- K5: top-k selection -------------------------------------
__global__ __launch_bounds__(64) void k_topk(const float* __restrict__ impb,
        int* __restrict__ sel)
{
    int row = blockIdx.x * 64 + threadIdx.x;  // 16 blocks x 64 -> 1024 rows
    if (row >= Bb * Hh * NSs) return;
    int qb = row & 63;
    float v[64];
    for (int j = 0; j < 64; ++j) {
        float t = impb[(size_t)row * 64 + j];
        if (j > qb) t = NEGF;
        if (j == qb) t += 1e9f;
        v[j] = t;
    }
    for (int t = 0; t < TOPKk; ++t) {
        int bi = 0; float bv = v[0];
        for (int j = 1; j < 64; ++j) {
            if (v[j] > bv) { bv = v[j]; bi = j; }
        }
        sel[(size_t)row * TOPKk + t] = bi;
        v[bi] = -3e38f;
    }
}

// -------------------- K6: merged MFMA attention (selected + window) -----------
// Swapped QK^T, exp2 softmax-lite. NEW: (a) row-sum denominators via ones-MFMA
// (oacc5 rows == oacc rows -> inv needs NO shuffles); (b) mask specialization:
// only kb==qb (causal j<=r, tiles t==0 & t==NT-1) and kb==qb-8 (anti j>r) need
// masks -- all other live tiles are maskless; selected tiles with kb>qb (topk
// garbage for small qb) are skipped entirely (block-uniform branch).
__global__ __launch_bounds__(256) void k_attn2(const f16* __restrict__ qh,
        const f16* __restrict__ kh, const f16* __restrict__ vt,
        const int* __restrict__ sel, const float* __restrict__ g,
        float* __restrict__ o)
{
    const int bid = blockIdx.x + 64 * blockIdx.y;   // 0..1023
    const int bh = ((bid & 7) << 1) | ((bid >> 3) & 1);
    const int qb = bid >> 4;
    const int b = bh >> 3, h = bh & 7;
    const int q0 = qb * 64;
    const int tid = threadIdx.x;
    const int w  = tid >> 6;      // wave 0..3
    const int l  = tid & 63;
    const int lr = l & 15;
    const int lg = l >> 4;

    __shared__ __align__(16) char smem[32768];
    // K dbuf: [0,8K) [8K,16K); V dbuf: [16K,24K) [24K,32K)

    f16x8 qf0, qf1;
    {
        const f16* qptr = qh + ((size_t)bh * Ss + q0 + w * 16 + lr) * HDd + lg * 8;
        qf0 = *(const f16x8*)(qptr);
        qf1 = *(const f16x8*)(qptr + 32);
    }
    f16x8 kone;
#pragma unroll
    for (int j = 0; j < 8; ++j) kone[j] = (_Float16)1.f;

    const int W0 = (qb < 8) ? (8 - qb) : 0;
    const int NT = 25 - W0;             // 16 selected + (9-W0) window
    const int* selrow = sel + ((size_t)bh * NSs + qb) * TOPKk;

    f32x4 oacc[4], osel[4], oacc5;
#pragma unroll
    for (int dt = 0; dt < 4; ++dt) {
        oacc[dt] = (f32x4){0.f, 0.f, 0.f, 0.f};
        osel[dt] = (f32x4){0.f, 0.f, 0.f, 0.f};
    }
    oacc5 = (f32x4){0.f, 0.f, 0.f, 0.f};

    const int srow0 = tid >> 3, sc8 = tid & 7;
    const int srow1 = (tid + 256) >> 3;
    f16x8 pk0, pk1, pv0, pv1;

    // prologue: stage tile 0 into buf 0
    int kb_cur = __builtin_amdgcn_readfirstlane(selrow[0]);
    {
        size_t kbase = (size_t)bh * Ss + kb_cur * 64;
        pk0 = *(const f16x8*)(kh + (kbase + srow0) * HDd + sc8 * 8);
        pk1 = *(const f16x8*)(kh + (kbase + srow1) * HDd + sc8 * 8);
        pv0 = *(const f16x8*)(vt + ((size_t)bh * HDd + srow0) * Ss + kb_cur * 64 + sc8 * 8);
        pv1 = *(const f16x8*)(vt + ((size_t)bh * HDd + srow1) * Ss + kb_cur * 64 + sc8 * 8);
        *(f16x8*)(smem + swz(srow0, srow0 * 128 + sc8 * 16)) = pk0;
        *(f16x8*)(smem + swz(srow1, srow1 * 128 + sc8 * 16)) = pk1;
        STAGE_V(smem + 16384, pv0, srow0, sc8);
        STAGE_V(smem + 16384, pv1, srow1, sc8);
    }
    __syncthreads();

    int cur = 0;
    for (int t = 0; t < NT; ++t) {
        // ---- prefetch issue (next tile -> regs) -----------------------------
        int kb_nxt = 0;
        const bool hasNext = (t + 1 < NT);
        if (hasNext) {
            kb_nxt = (t + 1 < 16) ? __builtin_amdgcn_readfirstlane(selrow[t + 1])
                                  : (qb - 8 + W0 + (t + 1 - 16));
            size_t kbase = (size_t)bh * Ss + kb_nxt * 64;
            pk0 = *(const f16x8*)(kh + (kbase + srow0) * HDd + sc8 * 8);
            pk1 = *(const f16x8*)(kh + (kbase + srow1) * HDd + sc8 * 8);
            pv0 = *(const f16x8*)(vt + ((size_t)bh * HDd + srow0) * Ss + kb_nxt * 64 + sc8 * 8);
            pv1 = *(const f16x8*)(vt + ((size_t)bh * HDd + srow1) * Ss + kb_nxt * 64 + sc8 * 8);
        }
        const char* Kc = smem + (cur ? 8192 : 0);
        const char* Vc = smem + 16384 + (cur ? 8192 : 0);

        // ---- mask mode (block-uniform): 0 none, 1 causal, 2 anti; skip ------
        int mm = 0;
        bool skip = false;
        if (t == 0 || t == NT - 1) mm = 1;                 // kb == qb: diagonal causal
        else if (t < 16) { if (kb_cur > qb) skip = true; } // garbage sel (qb<16)
        else if (W0 == 0 && t == 16) mm = 2;               // kb == qb-8: anti j>r

        if (!skip) {
            // ---- swapped QK^T + exp2 softmax-lite ---------------------------
            f16x8 pa8[2];
#pragma unroll
            for (int kt = 0; kt < 4; ++kt) {
                int krow = kt * 16 + lr;
                f16x8 kb0 = *(const f16x8*)(Kc + swz(krow, krow * 128 + lg * 16));
                f16x8 kb1 = *(const f16x8*)(Kc + swz(krow, krow * 128 + lg * 16 + 64));
                f32x4 c = (f32x4){0.f, 0.f, 0.f, 0.f};
                c = __builtin_amdgcn_mfma_f32_16x16x32_f16(kb0, qf0, c, 0, 0, 0);
                c = __builtin_amdgcn_mfma_f32_16x16x32_f16(kb1, qf1, c, 0, 0, 0);
#pragma unroll
                for (int rg = 0; rg < 4; ++rg) {
                    float sc = c[rg];
                    if (mm == 1) {
                        if (kt * 16 + 4 * lg + rg > w * 16 + lr) sc = NEGF;
                    } else if (mm == 2) {
                        if (kt * 16 + 4 * lg + rg <= w * 16 + lr) sc = NEGF;
                    }
                    float p = fexp2(sc);
                    pa8[kt >> 1][(kt & 1) * 4 + rg] = (_Float16)p;
                }
            }
            // row-sum denominators on the matrix pipe (rows match oacc's rows)
            oacc5 = __builtin_amdgcn_mfma_f32_16x16x32_f16(pa8[0], kone, oacc5, 0, 0, 0);
            oacc5 = __builtin_amdgcn_mfma_f32_16x16x32_f16(pa8[1], kone, oacc5, 0, 0, 0);

            // ---- PV: quad-interleaved V^T, b128 conflict-free ---------------
#pragma unroll
            for (int dt = 0; dt < 4; ++dt) {
                int vrow = dt * 16 + lr;
#pragma unroll
                for (int ktp = 0; ktp < 2; ++ktp) {
                    f16x8 vb = *(const f16x8*)(Vc + swz(vrow, vrow * 128 + ktp * 64 + lg * 16));
                    oacc[dt] = __builtin_amdgcn_mfma_f32_16x16x32_f16(pa8[ktp], vb, oacc[dt], 0, 0, 0);
                }
            }
        }

        // ---- phase boundary: snapshot selected result, reset ----------------
        if (t == 15) {
#pragma unroll
            for (int rg = 0; rg < 4; ++rg) {
                float inv = 1.f / oacc5[rg];
#pragma unroll
                for (int dt = 0; dt < 4; ++dt) osel[dt][rg] = oacc[dt][rg] * inv;
            }
#pragma unroll
            for (int dt = 0; dt < 4; ++dt) oacc[dt] = (f32x4){0.f, 0.f, 0.f, 0.f};
            oacc5 = (f32x4){0.f, 0.f, 0.f, 0.f};
        }

        // ---- write prefetched tile into the other buffer --------------------
        if (hasNext) {
            char* Kn = smem + (cur ? 0 : 8192);
            char* Vn = smem + 16384 + (cur ? 0 : 8192);
            *(f16x8*)(Kn + swz(srow0, srow0 * 128 + sc8 * 16)) = pk0;
            *(f16x8*)(Kn + swz(srow1, srow1 * 128 + sc8 * 16)) = pk1;
            STAGE_V(Vn, pv0, srow0, sc8);
            STAGE_V(Vn, pv1, srow1, sc8);
        }
        __syncthreads();
        cur ^= 1;
        kb_cur = kb_nxt;
    }

    // ---- epilogue: combine phases, gate, single coalesced RMW ---------------
    float* Os = (float*)smem;
#pragma unroll
    for (int rg = 0; rg < 4; ++rg) {
        float inv = 1.f / oacc5[rg];
        int row = w * 16 + 4 * lg + rg;
        int sq = q0 + row;
        float g1 = g[((size_t)(b * Ss + sq)) * 3 + 1];
        float g2 = g[((size_t)(b * Ss + sq)) * 3 + 2];
#pragma unroll
        for (int dt = 0; dt < 4; ++dt)
            Os[row * 68 + dt * 16 + lr] = g1 * osel[dt][rg] + g2 * oacc[dt][rg] * inv;
    }
    __syncthreads();
    {
        int row = tid >> 2;
        int c0 = (tid & 3) * 16;
        int s = q0 + row;
        float* op = o + ((size_t)(b * Ss + s)) * DMm + h * HDd + c0;
#pragma unroll
        for (int j = 0; j < 4; ++j) {
            float4 val = *(const float4*)&Os[row * 68 + c0 + j * 4];
            float4 cur4 = *(const float4*)&op[j * 4];
            cur4.x += val.x; cur4.y += val.y;
            cur4.z += val.z; cur4.w += val.w;
            *(float4*)&op[j * 4] = cur4;
        }
    }
}

// -------------------- constant emitter (host-side contract checks) ------------
__global__ __launch_bounds__(256) void k_const(float* __restrict__ y, float val)
{
    int i = blockIdx.x * 256 + threadIdx.x;
    y[i] = val;
}

// -------------------- launch --------------------------------------------------
extern "C" void kernel_launch(void* const* d_in, const int* in_sizes, int n_in,
                              void* d_out, int out_size, void* d_ws, size_t ws_size,
                              hipStream_t stream) {
    float* y = (float*)d_out;
    if (n_in != 6) {
        k_const<<<dim3(16384), 256, 0, stream>>>(y, 88888.f);
        return;
    }
    if (in_sizes[0] != 4194304 || in_sizes[1] != 262144 || in_sizes[2] != 262144 ||
        in_sizes[3] != 262144 || in_sizes[4] != 262144 || in_sizes[5] != 1536) {
        k_const<<<dim3(16384), 256, 0, stream>>>(y, 77777.f);
        return;
    }
    if (ws_size < WS_FLOATS * sizeof(float)) {
        k_const<<<dim3(16384), 256, 0, stream>>>(y, 66666.f);
        return;
    }

    const float* x  = (const float*)d_in[0];
    const float* Wq = (const float*)d_in[1];
    const float* Wk = (const float*)d_in[2];
    const float* Wv = (const float*)d_in[3];
    const float* Wo = (const float*)d_in[4];
    const float* Wg = (const float*)d_in[5];
    float* ws = (float*)d_ws;

    float* ow   = ws + OFF_O;
    float* gw   = ws + OFF_G;
    float* impw = ws + OFF_IMPB;
    int*   selw = (int*)(ws + OFF_SEL);
    f16*   qhw  = (f16*)(ws + OFF_QH);
    f16*   qlw  = (f16*)(ws + OFF_QL);
    f16*   khw  = (f16*)(ws + OFF_KH);
    f16*   klw  = (f16*)(ws + OFF_KL);
    f16*   vtw  = (f16*)(ws + OFF_VT);
    f16*   kchw = (f16*)(ws + OFF_KCH);
    f16*   kclw = (f16*)(ws + OFF_KCL);
    f16*   vctw = (f16*)(ws + OFF_VCT);
    f16*   xhw  = (f16*)(ws + OFF_XH);   // aliases o region (freed before k_cmp)
    f16*   xlw  = (f16*)(ws + OFF_XL);
    f16*   wqh  = (f16*)(ws + OFF_WT);
    f16*   wql  = (f16*)(ws + OFF_WT + 131072);
    f16*   wkh  = (f16*)(ws + OFF_WT + 262144);
    f16*   wkl  = (f16*)(ws + OFF_WT + 393216);
    f16*   wvh  = (f16*)(ws + OFF_WT + 524288);
    f16*   wvl  = (f16*)(ws + OFF_WT + 655360);
    f16*   woh  = (f16*)(ws + OFF_WT + 786432);

    k_prep_x<<<dim3(2048), 256, 0, stream>>>(x, xhw, xlw);
    k_prep_w<<<dim3(8, 8, 4), 256, 0, stream>>>(Wq, Wk, Wv, Wo,
            wqh, wql, wkh, wkl, wvh, wvl, woh);
    // q: split GEMM -> f16 hi/lo pre-scaled by PSC (log2-domain softmax)
    k_gemm<1, 0, 0><<<dim3(64, 8), 256, 0, stream>>>(xhw, xlw, (const float*)0,
            wqh, wql, (float*)0, qhw, qlw, PSC);
    // k: split GEMM -> f16 hi/lo (selection-safe; no fp32 intermediate)
    k_gemm<1, 0, 0><<<dim3(64, 8), 256, 0, stream>>>(xhw, xlw, (const float*)0,
            wkh, wkl, (float*)0, khw, klw, 1.f);
    // v: plain f16 swapped-operand GEMM -> vt [bh][d][s] directly
    k_gemm_tv<<<dim3(64, 8), 256, 0, stream>>>(xhw, wvh, vtw);
    k_gate<<<dim3(2048), 256, 0, stream>>>(x, Wg, gw);
    k_pool<<<dim3(512), 256, 0, stream>>>(khw, klw, vtw, kchw, kclw, vctw);
    k_cmp<<<dim3(64, 16), 256, 0, stream>>>(qhw, qlw, kchw, kclw, vctw, gw, impw, ow);
    k_topk<<<dim3(16), 64, 0, stream>>>(impw, selw);
    k_attn2<<<dim3(64, 16), 256, 0, stream>>>(qhw, khw, vtw, selw, gw, ow);
    k_gemm<0, 1, 1><<<dim3(64, 8), 256, 0, stream>>>((const f16*)0, (const f16*)0,
            ow, woh, (const f16*)0, y, (f16*)0, (f16*)0, 1.f);
}

// Round 10
// 245.594 us; speedup vs baseline: 5.8686x; 1.0623x over previous
//
#include <hip/hip_runtime.h>

// Problem constants
#define Hh    8
#define DMm   512
#define HDd   64
#define CBc   32
#define SBs   64
#define WINSZ 512
#define TOPKk 16
#define NEGF  (-1e30f)
#define Bb    2
#define Ss    4096
#define NCc   128   // S/CB
#define NSs   64    // S/SB
#define SCALE 0.125f
#define PSC   0.18033688011112042f   // SCALE * log2(e): q pre-scale -> exp2 softmax

// Workspace layout (float offsets)
#define OFF_KL   ((size_t)4194304)    // f16 k_lo [bh][s][d]
#define OFF_O    ((size_t)12582912)   // ALIASED: x_hi/x_lo live here until k_cmp writes o
#define OFF_G    ((size_t)16777216)   // B*S*3 = 24576
#define OFF_KC   ((size_t)16801792)   // kc_hi/kc_lo f16 (2 x 131072 halves)
#define OFF_VC   ((size_t)16932864)   // vc^T f16 (131072 halves)
#define OFF_IMPB ((size_t)17063936)   // B*H*NS*NS = 65536
#define OFF_SEL  ((size_t)17129472)   // B*H*NS*TOPK ints = 16384
#define OFF_QH   ((size_t)17145856)   // f16 q  [bh][s][d] (pre-scaled by PSC)
#define OFF_KH   ((size_t)19243008)   // f16 k_hi [bh][s][d]
#define OFF_VT   ((size_t)21340160)   // f16 v^T [bh][d][s]
#define OFF_WT   ((size_t)23437312)   // 7 x 131072 floats of f16 W^T (hi/lo)
#define OFF_QL   ((size_t)24354816)   // f16 q_lo [bh][s][d] (pre-scaled by PSC)
#define WS_FLOATS ((size_t)25403392)

// x_hi/x_lo alias the o region (o first written by k_cmp, after GEMMs)
#define OFF_XH   (OFF_O)
#define OFF_XL   (OFF_O + 2097152)

#define OFF_KCH  (OFF_KC)
#define OFF_KCL  (OFF_KC + 65536)
#define OFF_VCT  (OFF_VC)

typedef _Float16 f16;
typedef _Float16 f16x4 __attribute__((ext_vector_type(4)));
typedef _Float16 f16x8 __attribute__((ext_vector_type(8)));
typedef float    f32x4 __attribute__((ext_vector_type(4)));

__device__ __forceinline__ int swz(int row, int byteoff) {
    return byteoff ^ ((row & 7) << 4);   // spreads stride-128B rows across banks
}
__device__ __forceinline__ float fexp2(float x) {
    return __builtin_amdgcn_exp2f(x);    // v_exp_f32: D = 2^S0
}

// V LDS layout: per 32-key block, quads interleaved as {4lg, 16+4lg} so that a
// single b128 read at [ktp*64 + lg*16] yields keys {ktp*32+4lg+0..3, +16+0..3}
// (matches in-register P order for mfma_16x16x32). Write side: 2 x b64.
#define STAGE_V(Vbase, vd, row, c8) do {                                     \
    int q0_ = ((c8) & 3) * 2, q1_ = q0_ + 1;                                 \
    int col0_ = ((c8) >> 2) * 64 + (q0_ & 3) * 16 + (q0_ >> 2) * 8;          \
    int col1_ = ((c8) >> 2) * 64 + (q1_ & 3) * 16 + (q1_ >> 2) * 8;          \
    f16x4 lo_ = { (vd)[0], (vd)[1], (vd)[2], (vd)[3] };                      \
    f16x4 hi_ = { (vd)[4], (vd)[5], (vd)[6], (vd)[7] };                      \
    *(f16x4*)((Vbase) + swz(row, (row) * 128 + col0_)) = lo_;                \
    *(f16x4*)((Vbase) + swz(row, (row) * 128 + col1_)) = hi_;                \
} while (0)

// -------------------- K0a: fused x -> x_hi/x_lo + gate ------------------------
// Wave per row: same registers feed the f16 split AND the 3-way gate dot.
__global__ __launch_bounds__(256) void k_prep_xg(const float* __restrict__ x,
        const float* __restrict__ Wg, f16* __restrict__ xh, f16* __restrict__ xl,
        float* __restrict__ g)
{
    const int w = threadIdx.x >> 6, l = threadIdx.x & 63;
    const int row = blockIdx.x * 4 + w;        // 0..8191
    const int d0 = l * 8;
    const float* xr = x + (size_t)row * DMm + d0;
    float4 a = *(const float4*)(xr);
    float4 b = *(const float4*)(xr + 4);
    float xv[8] = { a.x, a.y, a.z, a.w, b.x, b.y, b.z, b.w };
    f16x8 h, lo;
#pragma unroll
    for (int j = 0; j < 8; ++j) {
        h[j] = (_Float16)xv[j];
        lo[j] = (_Float16)(xv[j] - (float)h[j]);
    }
    size_t base = (size_t)row * DMm + d0;
    *(f16x8*)(xh + base) = h;
    *(f16x8*)(xl + base) = lo;
    float s0 = 0.f, s1 = 0.f, s2 = 0.f;
#pragma unroll
    for (int j = 0; j < 8; ++j) {
        const float* wr = Wg + (size_t)(d0 + j) * 3;
        s0 += xv[j] * wr[0];
        s1 += xv[j] * wr[1];
        s2 += xv[j] * wr[2];
    }
#pragma unroll
    for (int off = 1; off < 64; off <<= 1) {
        s0 += __shfl_xor(s0, off);
        s1 += __shfl_xor(s1, off);
        s2 += __shfl_xor(s2, off);
    }
    if (l == 0) {
        g[(size_t)row * 3 + 0] = 1.f / (1.f + expf(-s0));
        g[(size_t)row * 3 + 1] = 1.f / (1.f + expf(-s1));
        g[(size_t)row * 3 + 2] = 1.f / (1.f + expf(-s2));
    }
}

// -------------------- K0b: W -> W^T hi/lo (f16) -------------------------------
__global__ __launch_bounds__(256) void k_prep_w(
        const float* __restrict__ Wq, const float* __restrict__ Wk,
        const float* __restrict__ Wv, const float* __restrict__ Wo,
        f16* __restrict__ wqh, f16* __restrict__ wql,
        f16* __restrict__ wkh, f16* __restrict__ wkl,
        f16* __restrict__ wvh, f16* __restrict__ wvl,
        f16* __restrict__ woh)
{
    const int k0 = blockIdx.x * 64;
    const int n0 = blockIdx.y * 64;
    const int z = blockIdx.z;
    const float* W = (z == 0) ? Wq : ((z == 1) ? Wk : ((z == 2) ? Wv : Wo));
    f16* dh = (z == 0) ? wqh : ((z == 1) ? wkh : ((z == 2) ? wvh : woh));
    f16* dl = (z == 0) ? wql : ((z == 1) ? wkl : ((z == 2) ? wvl : (f16*)0));
    __shared__ float T[64][68];
    const int tid = threadIdx.x;
    {
        int r = tid >> 2;
        int c16 = (tid & 3) * 16;
#pragma unroll
        for (int j = 0; j < 4; ++j) {
            float4 w4 = *(const float4*)(W + (size_t)(k0 + r) * DMm + n0 + c16 + j * 4);
            *(float4*)&T[r][c16 + j * 4] = w4;
        }
    }
    __syncthreads();
    {
        int n = tid >> 2;
        int k16 = (tid & 3) * 16;
        f16x8 h0, h1, l0, l1;
#pragma unroll
        for (int j = 0; j < 8; ++j) {
            float wv = T[k16 + j][n];
            h0[j] = (_Float16)wv; l0[j] = (_Float16)(wv - (float)h0[j]);
        }
#pragma unroll
        for (int j = 0; j < 8; ++j) {
            float wv = T[k16 + 8 + j][n];
            h1[j] = (_Float16)wv; l1[j] = (_Float16)(wv - (float)h1[j]);
        }
        size_t o = (size_t)(n0 + n) * DMm + k0 + k16;
        *(f16x8*)(dh + o) = h0;
        *(f16x8*)(dh + o + 8) = h1;
        if (dl) { *(f16x8*)(dl + o) = l0; *(f16x8*)(dl + o + 8) = l1; }
    }
}

// -------------------- K1: merged q/k/v projection GEMMs -----------------------
// z=0: q split-f16 (PSC-scaled hi/lo out); z=1: k split-f16 (hi/lo out);
// z=2: v plain f16 swapped-operand -> vt [bh][d][s]. One dispatch: 1536 blocks
// co-schedule instead of 3 serialized 512-block launches.
__global__ __launch_bounds__(256) void k_gemm3(
        const f16* __restrict__ xh, const f16* __restrict__ xl,
        const f16* __restrict__ wqh, const f16* __restrict__ wql,
        const f16* __restrict__ wkh, const f16* __restrict__ wkl,
        const f16* __restrict__ wvh,
        f16* __restrict__ qh, f16* __restrict__ ql,
        f16* __restrict__ kh, f16* __restrict__ kl,
        f16* __restrict__ vt)
{
    const int z = blockIdx.z;
    const int m0 = blockIdx.x * 128;
    const int n0 = blockIdx.y * 64;
    const int tid = threadIdx.x;
    const int w = tid >> 6, l = tid & 63;
    const int lr = l & 15, lg = l >> 4;
    const int wm = w >> 1, wn = w & 1;

    __shared__ f16 As[2][128 * 40];
    __shared__ f16 Bs[2][64 * 40];

    f32x4 acc[4][2];
#pragma unroll
    for (int mf = 0; mf < 4; ++mf)
#pragma unroll
        for (int nf = 0; nf < 2; ++nf) acc[mf][nf] = (f32x4){0.f, 0.f, 0.f, 0.f};

    const int ar = tid >> 1, ac = (tid & 1) * 16;
    const int bn = tid >> 2, bc = (tid & 3) * 8;

    if (z == 2) {
        // ---- v path: plain f16, swapped-operand MFMA -> transposed out ------
        for (int k0 = 0; k0 < DMm; k0 += 32) {
            {
                const f16* src = xh + (size_t)(m0 + ar) * DMm + k0 + ac;
                *(f16x8*)&As[0][ar * 40 + ac] = *(const f16x8*)src;
                *(f16x8*)&As[0][ar * 40 + ac + 8] = *(const f16x8*)(src + 8);
                const f16* srcb = wvh + (size_t)(n0 + bn) * DMm + k0 + bc;
                *(f16x8*)&Bs[0][bn * 40 + bc] = *(const f16x8*)srcb;
            }
            __syncthreads();
            f16x8 ahf[4], bhf[2];
#pragma unroll
            for (int mf = 0; mf < 4; ++mf)
                ahf[mf] = *(const f16x8*)&As[0][(wm * 64 + mf * 16 + lr) * 40 + lg * 8];
#pragma unroll
            for (int nf = 0; nf < 2; ++nf)
                bhf[nf] = *(const f16x8*)&Bs[0][(wn * 32 + nf * 16 + lr) * 40 + lg * 8];
#pragma unroll
            for (int mf = 0; mf < 4; ++mf)
#pragma unroll
                for (int nf = 0; nf < 2; ++nf)
                    acc[mf][nf] = __builtin_amdgcn_mfma_f32_16x16x32_f16(bhf[nf], ahf[mf], acc[mf][nf], 0, 0, 0);
            __syncthreads();
        }
        const int h = n0 >> 6;
#pragma unroll
        for (int mf = 0; mf < 4; ++mf)
#pragma unroll
            for (int nf = 0; nf < 2; ++nf)
#pragma unroll
                for (int rg = 0; rg < 4; ++rg) {
                    int n = n0 + wn * 32 + nf * 16 + 4 * lg + rg;   // d (global)
                    int m = m0 + wm * 64 + mf * 16 + lr;            // s (incl batch)
                    int b = m >> 12, s = m & 4095;
                    vt[(((size_t)(b * Hh + h)) * HDd + (n & 63)) * Ss + s] =
                        (f16)acc[mf][nf][rg];
                }
        return;
    }

    // ---- q/k path: split-f16 (3-product, fp32-grade) ------------------------
    const f16* Bh = z ? wkh : wqh;
    const f16* Bl = z ? wkl : wql;
    f16* Ch = z ? kh : qh;
    f16* Cl = z ? kl : ql;
    const float cscale = z ? 1.f : PSC;

    for (int k0 = 0; k0 < DMm; k0 += 32) {
        {
            const f16* src = xh + (size_t)(m0 + ar) * DMm + k0 + ac;
            *(f16x8*)&As[0][ar * 40 + ac] = *(const f16x8*)src;
            *(f16x8*)&As[0][ar * 40 + ac + 8] = *(const f16x8*)(src + 8);
            const f16* src2 = xl + (size_t)(m0 + ar) * DMm + k0 + ac;
            *(f16x8*)&As[1][ar * 40 + ac] = *(const f16x8*)src2;
            *(f16x8*)&As[1][ar * 40 + ac + 8] = *(const f16x8*)(src2 + 8);
        }
        {
            const f16* src = Bh + (size_t)(n0 + bn) * DMm + k0 + bc;
            *(f16x8*)&Bs[0][bn * 40 + bc] = *(const f16x8*)src;
            const f16* src2 = Bl + (size_t)(n0 + bn) * DMm + k0 + bc;
            *(f16x8*)&Bs[1][bn * 40 + bc] = *(const f16x8*)src2;
        }
        __syncthreads();

        f16x8 ahf[4], alf[4], bhf[2], blf[2];
#pragma unroll
        for (int mf = 0; mf < 4; ++mf) {
            int row = wm * 64 + mf * 16 + lr;
            ahf[mf] = *(const f16x8*)&As[0][row * 40 + lg * 8];
            alf[mf] = *(const f16x8*)&As[1][row * 40 + lg * 8];
        }
#pragma unroll
        for (int nf = 0; nf < 2; ++nf) {
            int row = wn * 32 + nf * 16 + lr;
            bhf[nf] = *(const f16x8*)&Bs[0][row * 40 + lg * 8];
            blf[nf] = *(const f16x8*)&Bs[1][row * 40 + lg * 8];
        }
#pragma unroll
        for (int mf = 0; mf < 4; ++mf)
#pragma unroll
            for (int nf = 0; nf < 2; ++nf) {
                acc[mf][nf] = __builtin_amdgcn_mfma_f32_16x16x32_f16(ahf[mf], bhf[nf], acc[mf][nf], 0, 0, 0);
                acc[mf][nf] = __builtin_amdgcn_mfma_f32_16x16x32_f16(ahf[mf], blf[nf], acc[mf][nf], 0, 0, 0);
                acc[mf][nf] = __builtin_amdgcn_mfma_f32_16x16x32_f16(alf[mf], bhf[nf], acc[mf][nf], 0, 0, 0);
            }
        __syncthreads();
    }

#pragma unroll
    for (int mf = 0; mf < 4; ++mf)
#pragma unroll
        for (int nf = 0; nf < 2; ++nf)
#pragma unroll
            for (int rg = 0; rg < 4; ++rg) {
                int m = m0 + wm * 64 + mf * 16 + 4 * lg + rg;
                int n = n0 + wn * 32 + nf * 16 + lr;
                int b = m >> 12, s = m & 4095;
                int h = n >> 6, d = n & 63;
                size_t o = (((size_t)(b * Hh + h)) * Ss + s) * HDd + d;
                float vs = acc[mf][nf][rg] * cscale;
                f16 hv = (f16)vs;
                Ch[o] = hv;
                Cl[o] = (f16)(vs - (float)hv);
            }
}

// -------------------- K1c: outproj GEMM (fp32 A staged, plain f16) ------------
__global__ __launch_bounds__(256) void k_outproj(const float* __restrict__ Af,
        const f16* __restrict__ Bh, float* __restrict__ Cf)
{
    const int m0 = blockIdx.x * 128;
    const int n0 = blockIdx.y * 64;
    const int tid = threadIdx.x;
    const int w = tid >> 6, l = tid & 63;
    const int lr = l & 15, lg = l >> 4;
    const int wm = w >> 1, wn = w & 1;

    __shared__ f16 As[128 * 40];
    __shared__ f16 Bs[64 * 40];

    f32x4 acc[4][2];
#pragma unroll
    for (int mf = 0; mf < 4; ++mf)
#pragma unroll
        for (int nf = 0; nf < 2; ++nf) acc[mf][nf] = (f32x4){0.f, 0.f, 0.f, 0.f};

    const int ar = tid >> 1, ac = (tid & 1) * 16;
    const int bn = tid >> 2, bc = (tid & 3) * 8;

    for (int k0 = 0; k0 < DMm; k0 += 32) {
        {
            const float* src = Af + (size_t)(m0 + ar) * DMm + k0 + ac;
            float4 a0 = *(const float4*)(src);
            float4 a1 = *(const float4*)(src + 4);
            float4 a2 = *(const float4*)(src + 8);
            float4 a3 = *(const float4*)(src + 12);
            f16x8 h0, h1;
            h0[0] = (_Float16)a0.x; h0[1] = (_Float16)a0.y; h0[2] = (_Float16)a0.z; h0[3] = (_Float16)a0.w;
            h0[4] = (_Float16)a1.x; h0[5] = (_Float16)a1.y; h0[6] = (_Float16)a1.z; h0[7] = (_Float16)a1.w;
            h1[0] = (_Float16)a2.x; h1[1] = (_Float16)a2.y; h1[2] = (_Float16)a2.z; h1[3] = (_Float16)a2.w;
            h1[4] = (_Float16)a3.x; h1[5] = (_Float16)a3.y; h1[6] = (_Float16)a3.z; h1[7] = (_Float16)a3.w;
            *(f16x8*)&As[ar * 40 + ac] = h0;
            *(f16x8*)&As[ar * 40 + ac + 8] = h1;
            const f16* srcb = Bh + (size_t)(n0 + bn) * DMm + k0 + bc;
            *(f16x8*)&Bs[bn * 40 + bc] = *(const f16x8*)srcb;
        }
        __syncthreads();
        f16x8 ahf[4], bhf[2];
#pragma unroll
        for (int mf = 0; mf < 4; ++mf)
            ahf[mf] = *(const f16x8*)&As[(wm * 64 + mf * 16 + lr) * 40 + lg * 8];
#pragma unroll
        for (int nf = 0; nf < 2; ++nf)
            bhf[nf] = *(const f16x8*)&Bs[(wn * 32 + nf * 16 + lr) * 40 + lg * 8];
#pragma unroll
        for (int mf = 0; mf < 4; ++mf)
#pragma unroll
            for (int nf = 0; nf < 2; ++nf)
                acc[mf][nf] = __builtin_amdgcn_mfma_f32_16x16x32_f16(ahf[mf], bhf[nf], acc[mf][nf], 0, 0, 0);
        __syncthreads();
    }
#pragma unroll
    for (int mf = 0; mf < 4; ++mf)
#pragma unroll
        for (int nf = 0; nf < 2; ++nf)
#pragma unroll
            for (int rg = 0; rg < 4; ++rg) {
                int m = m0 + wm * 64 + mf * 16 + 4 * lg + rg;
                int n = n0 + wn * 32 + nf * 16 + lr;
                Cf[(size_t)m * DMm + n] = acc[mf][nf][rg];
            }
}

// -------------------- K3: mean-pool from f16 k_hi/k_lo and vt -----------------
__global__ __launch_bounds__(256) void k_pool(const f16* __restrict__ kh,
        const f16* __restrict__ kl, const f16* __restrict__ vt,
        f16* __restrict__ kch, f16* __restrict__ kcl, f16* __restrict__ vct)
{
    int idx = blockIdx.x * 256 + threadIdx.x;  // B*H*NC*HD = 131072
    int bh = idx >> 13;
    {
        int d = idx & 63;
        int n = (idx >> 6) & 127;
        const f16* kp = kh + ((size_t)bh * Ss + n * CBc) * HDd + d;
        const f16* lp = kl + ((size_t)bh * Ss + n * CBc) * HDd + d;
        float sk = 0.f;
        for (int t = 0; t < CBc; ++t)
            sk += (float)kp[(size_t)t * HDd] + (float)lp[(size_t)t * HDd];
        float mk = sk * (1.f / CBc);
        f16 h = (f16)mk;
        kch[idx] = h;
        kcl[idx] = (f16)(mk - (float)h);
    }
    {
        int vd = (idx >> 7) & 63;
        int vn = idx & 127;
        const f16* vp = vt + ((size_t)bh * HDd + vd) * Ss + vn * CBc;
        float sv = 0.f;
#pragma unroll
        for (int j = 0; j < 4; ++j) {
            f16x8 v8 = *(const f16x8*)(vp + j * 8);
#pragma unroll
            for (int e = 0; e < 8; ++e) sv += (float)v8[e];
        }
        vct[((size_t)bh * HDd + vd) * NCc + vn] = (f16)(sv * (1.f / CBc));
    }
}

// -------------------- K4: compressed attention + importance (split-f16 MFMA) --
// Unnormalized exp2 values stay in Pm; per-row 1/sum in rinv[]; normalization
// folded into importance and PV conversion (one fewer LDS RMW pass).
__global__ __launch_bounds__(256) void k_cmp(const f16* __restrict__ qh,
        const f16* __restrict__ ql, const f16* __restrict__ kch,
        const f16* __restrict__ kcl, const f16* __restrict__ vct,
        const float* __restrict__ g, float* __restrict__ impb, float* __restrict__ o)
{
    const int qb = blockIdx.x;   // 0..63
    const int bh = blockIdx.y;   // 0..15
    const int b = bh >> 3, h = bh & 7;
    const int q0 = qb * 64;
    const int tid = threadIdx.x;
    const int w = tid >> 6, l = tid & 63;
    const int lr = l & 15, lg = l >> 4;

    __shared__ __align__(16) char smem[51456];
    float* Pm = (float*)smem;                       // [64][132] fp32 exp2 values
    char* U = smem + 33792;                         // 16KB union: {KCh,KCl} / {VCt,Ps}
    float* red2 = (float*)(smem + 33792 + 16384);   // 256 floats
    float* rinv = (float*)(smem + 51200);           // 64 floats

    const int NCT = (qb <= 30) ? 1 : 2;
    const int ncols = NCT * 64;

    f16x8 qfh0, qfh1, qfl0, qfl1;
    {
        size_t qoff = ((size_t)bh * Ss + q0 + w * 16 + lr) * HDd + lg * 8;
        qfh0 = *(const f16x8*)(qh + qoff);
        qfh1 = *(const f16x8*)(qh + qoff + 32);
        qfl0 = *(const f16x8*)(ql + qoff);
        qfl1 = *(const f16x8*)(ql + qoff + 32);
    }

    for (int ct = 0; ct < NCT; ++ct) {
        __syncthreads();
#pragma unroll
        for (int p = 0; p < 2; ++p) {
            int idx = tid + p * 256;
            int row = idx >> 3;           // chunk 0..63
            int c8 = idx & 7;
            size_t src = ((size_t)bh * NCc + ct * 64 + row) * HDd + c8 * 8;
            *(f16x8*)(U + swz(row, row * 128 + c8 * 16)) = *(const f16x8*)(kch + src);
            *(f16x8*)(U + 8192 + swz(row, row * 128 + c8 * 16)) = *(const f16x8*)(kcl + src);
        }
        __syncthreads();
#pragma unroll
        for (int kt = 0; kt < 4; ++kt) {
            int krow = kt * 16 + lr;
            f16x8 bh0 = *(const f16x8*)(U + swz(krow, krow * 128 + lg * 16));
            f16x8 bh1 = *(const f16x8*)(U + swz(krow, krow * 128 + lg * 16 + 64));
            f16x8 bl0 = *(const f16x8*)(U + 8192 + swz(krow, krow * 128 + lg * 16));
            f16x8 bl1 = *(const f16x8*)(U + 8192 + swz(krow, krow * 128 + lg * 16 + 64));
            f32x4 c = (f32x4){0.f, 0.f, 0.f, 0.f};
            c = __builtin_amdgcn_mfma_f32_16x16x32_f16(qfh0, bh0, c, 0, 0, 0);
            c = __builtin_amdgcn_mfma_f32_16x16x32_f16(qfh1, bh1, c, 0, 0, 0);
            c = __builtin_amdgcn_mfma_f32_16x16x32_f16(qfh0, bl0, c, 0, 0, 0);
            c = __builtin_amdgcn_mfma_f32_16x16x32_f16(qfh1, bl1, c, 0, 0, 0);
            c = __builtin_amdgcn_mfma_f32_16x16x32_f16(qfl0, bh0, c, 0, 0, 0);
            c = __builtin_amdgcn_mfma_f32_16x16x32_f16(qfl1, bh1, c, 0, 0, 0);
            int n = ct * 64 + kt * 16 + lr;
#pragma unroll
            for (int rg = 0; rg < 4; ++rg) {
                int row = w * 16 + 4 * lg + rg;
                int s = q0 + row;
                bool valid = (32 * n + 31 <= s);
                Pm[row * 132 + n] = valid ? c[rg] : NEGF;   // log2-domain score
            }
        }
    }
    __syncthreads();

    {
        int r = tid >> 2;
        int l4 = tid & 3;
        float m = NEGF;
        for (int c = l4; c < ncols; c += 4) m = fmaxf(m, Pm[r * 132 + c]);
        m = fmaxf(m, __shfl_xor(m, 1));
        m = fmaxf(m, __shfl_xor(m, 2));
        float sum = 0.f;
        if (m > NEGF * 0.5f) {
            for (int c = l4; c < ncols; c += 4) {
                float sv = Pm[r * 132 + c];
                float p = (sv <= NEGF * 0.5f) ? 0.f : fexp2(sv - m);
                Pm[r * 132 + c] = p;    // unnormalized
                sum += p;
            }
        } else {
            for (int c = l4; c < ncols; c += 4) Pm[r * 132 + c] = 0.f;
        }
        sum += __shfl_xor(sum, 1);
        sum += __shfl_xor(sum, 2);
        if (l4 == 0) rinv[r] = (sum > 0.f) ? 1.f / sum : 0.f;
    }
    __syncthreads();

    {
        float part = 0.f;
#pragma unroll
        for (int rr = 0; rr < 16; ++rr) {
            int qq = w * 16 + rr;
            int c = 2 * l;
            if (c < ncols) {
                float2 pv2 = *(const float2*)&Pm[qq * 132 + c];
                part += (pv2.x + pv2.y) * rinv[qq];
            }
        }
        red2[w * 64 + l] = part;
    }
    __syncthreads();
    if (tid < 64) {
        float tot = red2[tid] + red2[64 + tid] + red2[128 + tid] + red2[192 + tid];
        impb[((size_t)bh * NSs + qb) * NSs + tid] = tot;
    }

    f32x4 oacc[4];
#pragma unroll
    for (int dt = 0; dt < 4; ++dt) oacc[dt] = (f32x4){0.f, 0.f, 0.f, 0.f};
    char* Ps = U + 8192 + w * 2048;
    for (int ct = 0; ct < NCT; ++ct) {
        __syncthreads();
#pragma unroll
        for (int p = 0; p < 2; ++p) {
            int idx = tid + p * 256;
            int row = idx >> 3;           // d 0..63
            int c8 = idx & 7;
            size_t src = ((size_t)bh * HDd + row) * NCc + ct * 64 + c8 * 8;
            *(f16x8*)(U + swz(row, row * 128 + c8 * 16)) = *(const f16x8*)(vct + src);
        }
        {
            int r = l >> 2;
            int c0 = (l & 3) * 16;
            float ri = rinv[w * 16 + r];
            const float* pr = &Pm[(w * 16 + r) * 132 + ct * 64 + c0];
            float4 p0 = *(const float4*)(pr);
            float4 p1 = *(const float4*)(pr + 4);
            float4 p2 = *(const float4*)(pr + 8);
            float4 p3 = *(const float4*)(pr + 12);
            f16x8 h0, h1;
            h0[0] = (_Float16)(p0.x * ri); h0[1] = (_Float16)(p0.y * ri);
            h0[2] = (_Float16)(p0.z * ri); h0[3] = (_Float16)(p0.w * ri);
            h0[4] = (_Float16)(p1.x * ri); h0[5] = (_Float16)(p1.y * ri);
            h0[6] = (_Float16)(p1.z * ri); h0[7] = (_Float16)(p1.w * ri);
            h1[0] = (_Float16)(p2.x * ri); h1[1] = (_Float16)(p2.y * ri);
            h1[2] = (_Float16)(p2.z * ri); h1[3] = (_Float16)(p2.w * ri);
            h1[4] = (_Float16)(p3.x * ri); h1[5] = (_Float16)(p3.y * ri);
            h1[6] = (_Float16)(p3.z * ri); h1[7] = (_Float16)(p3.w * ri);
            *(f16x8*)(Ps + swz(r, r * 128 + c0 * 2)) = h0;
            *(f16x8*)(Ps + swz(r, r * 128 + c0 * 2 + 16)) = h1;
        }
        __syncthreads();
        f16x8 pa0 = *(const f16x8*)(Ps + swz(lr, lr * 128 + lg * 16));
        f16x8 pa1 = *(const f16x8*)(Ps + swz(lr, lr * 128 + lg * 16 + 64));
#pragma unroll
        for (int dt = 0; dt < 4; ++dt) {
            int vrow = dt * 16 + lr;
            f16x8 vb0 = *(const f16x8*)(U + swz(vrow, vrow * 128 + lg * 16));
            f16x8 vb1 = *(const f16x8*)(U + swz(vrow, vrow * 128 + lg * 16 + 64));
            oacc[dt] = __builtin_amdgcn_mfma_f32_16x16x32_f16(pa0, vb0, oacc[dt], 0, 0, 0);
            oacc[dt] = __builtin_amdgcn_mfma_f32_16x16x32_f16(pa1, vb1, oacc[dt], 0, 0, 0);
        }
    }

#pragma unroll
    for (int rg = 0; rg < 4; ++rg) {
        int row = w * 16 + 4 * lg + rg;
        int s = q0 + row;
        float g0 = g[((size_t)(b * Ss + s)) * 3 + 0];
#pragma unroll
        for (int dt = 0; dt < 4; ++dt)
            o[((size_t)(b * Ss + s)) * DMm + h * HDd + dt * 16 + lr] = g0 * oacc[dt][rg];
    }
}

// -------------------- K5: top-k selection -------------------------------------
__global__ __launch_bounds__(64) void k_topk(const float* __restrict__ impb,
        int* __restrict__ sel)
{
    int row = blockIdx.x * 64 + threadIdx.x;  // 16 blocks x 64 -> 1024 rows
    if (row >= Bb * Hh * NSs) return;
    int qb = row & 63;
    float v[64];
    for (int j = 0; j < 64; ++j) {
        float t = impb[(size_t)row * 64 + j];
        if (j > qb) t = NEGF;
        if (j == qb) t += 1e9f;
        v[j] = t;
    }
    for (int t = 0; t < TOPKk; ++t) {
        int bi = 0; float bv = v[0];
        for (int j = 1; j < 64; ++j) {
            if (v[j] > bv) { bv = v[j]; bi = j; }
        }
        sel[(size_t)row * TOPKk + t] = bi;
        v[bi] = -3e38f;
    }
}

// -------------------- K6: merged MFMA attention (selected + window) -----------
__global__ __launch_bounds__(256) void k_attn2(const f16* __restrict__ qh,
        const f16* __restrict__ kh, const f16* __restrict__ vt,
        const int* __restrict__ sel, const float* __restrict__ g,
        float* __restrict__ o)
{
    const int bid = blockIdx.x + 64 * blockIdx.y;   // 0..1023
    const int bh = ((bid & 7) << 1) | ((bid >> 3) & 1);
    const int qb = bid >> 4;
    const int b = bh >> 3, h = bh & 7;
    const int q0 = qb * 64;
    const int tid = threadIdx.x;
    const int w  = tid >> 6;      // wave 0..3
    const int l  = tid & 63;
    const int lr = l & 15;
    const int lg = l >> 4;

    __shared__ __align__(16) char smem[32768];
    // K dbuf: [0,8K) [8K,16K); V dbuf: [16K,24K) [24K,32K)

    f16x8 qf0, qf1;
    {
        const f16* qptr = qh + ((size_t)bh * Ss + q0 + w * 16 + lr) * HDd + lg * 8;
        qf0 = *(const f16x8*)(qptr);
        qf1 = *(const f16x8*)(qptr + 32);
    }
    f16x8 kone;
#pragma unroll
    for (int j = 0; j < 8; ++j) kone[j] = (_Float16)1.f;

    const int W0 = (qb < 8) ? (8 - qb) : 0;
    const int NT = 25 - W0;             // 16 selected + (9-W0) window
    const int* selrow = sel + ((size_t)bh * NSs + qb) * TOPKk;

    f32x4 oacc[4], osel[4], oacc5;
#pragma unroll
    for (int dt = 0; dt < 4; ++dt) {
        oacc[dt] = (f32x4){0.f, 0.f, 0.f, 0.f};
        osel[dt] = (f32x4){0.f, 0.f, 0.f, 0.f};
    }
    oacc5 = (f32x4){0.f, 0.f, 0.f, 0.f};

    const int srow0 = tid >> 3, sc8 = tid & 7;
    const int srow1 = (tid + 256) >> 3;
    f16x8 pk0, pk1, pv0, pv1;

    // prologue: stage tile 0 into buf 0
    int kb_cur = __builtin_amdgcn_readfirstlane(selrow[0]);
    {
        size_t kbase = (size_t)bh * Ss + kb_cur * 64;
        pk0 = *(const f16x8*)(kh + (kbase + srow0) * HDd + sc8 * 8);
        pk1 = *(const f16x8*)(kh + (kbase + srow1) * HDd + sc8 * 8);
        pv0 = *(const f16x8*)(vt + ((size_t)bh * HDd + srow0) * Ss + kb_cur * 64 + sc8 * 8);
        pv1 = *(const f16x8*)(vt + ((size_t)bh * HDd + srow1) * Ss + kb_cur * 64 + sc8 * 8);
        *(f16x8*)(smem + swz(srow0, srow0 * 128 + sc8 * 16)) = pk0;
        *(f16x8*)(smem + swz(srow1, srow1 * 128 + sc8 * 16)) = pk1;
        STAGE_V(smem + 16384, pv0, srow0, sc8);
        STAGE_V(smem + 16384, pv1, srow1, sc8);
    }
    __syncthreads();

    int cur = 0;
    for (int t = 0; t < NT; ++t) {
        // ---- prefetch issue (next tile -> regs) -----------------------------
        int kb_nxt = 0;
        const bool hasNext = (t + 1 < NT);
        if (hasNext) {
            kb_nxt = (t + 1 < 16) ? __builtin_amdgcn_readfirstlane(selrow[t + 1])
                                  : (qb - 8 + W0 + (t + 1 - 16));
            size_t kbase = (size_t)bh * Ss + kb_nxt * 64;
            pk0 = *(const f16x8*)(kh + (kbase + srow0) * HDd + sc8 * 8);
            pk1 = *(const f16x8*)(kh + (kbase + srow1) * HDd + sc8 * 8);
            pv0 = *(const f16x8*)(vt + ((size_t)bh * HDd + srow0) * Ss + kb_nxt * 64 + sc8 * 8);
            pv1 = *(const f16x8*)(vt + ((size_t)bh * HDd + srow1) * Ss + kb_nxt * 64 + sc8 * 8);
        }
        const char* Kc = smem + (cur ? 8192 : 0);
        const char* Vc = smem + 16384 + (cur ? 8192 : 0);

        // ---- mask mode (block-uniform): 0 none, 1 causal, 2 anti; skip ------
        int mm = 0;
        bool skip = false;
        if (t == 0 || t == NT - 1) mm = 1;                 // kb == qb: diagonal causal
        else if (t < 16) { if (kb_cur > qb) skip = true; } // garbage sel (qb<16)
        else if (W0 == 0 && t == 16) mm = 2;               // kb == qb-8: anti j>r

        if (!skip) {
            __builtin_amdgcn_s_setprio(1);
            // ---- swapped QK^T + exp2 softmax-lite ---------------------------
            f16x8 pa8[2];
#pragma unroll
            for (int kt = 0; kt < 4; ++kt) {
                int krow = kt * 16 + lr;
                f16x8 kb0 = *(const f16x8*)(Kc + swz(krow, krow * 128 + lg * 16));
                f16x8 kb1 = *(const f16x8*)(Kc + swz(krow, krow * 128 + lg * 16 + 64));
                f32x4 c = (f32x4){0.f, 0.f, 0.f, 0.f};
                c = __builtin_amdgcn_mfma_f32_16x16x32_f16(kb0, qf0, c, 0, 0, 0);
                c = __builtin_amdgcn_mfma_f32_16x16x32_f16(kb1, qf1, c, 0, 0, 0);
#pragma unroll
                for (int rg = 0; rg < 4; ++rg) {
                    float sc = c[rg];
                    if (mm == 1) {
                        if (kt * 16 + 4 * lg + rg > w * 16 + lr) sc = NEGF;
                    } else if (mm == 2) {
                        if (kt * 16 + 4 * lg + rg <= w * 16 + lr) sc = NEGF;
                    }
                    float p = fexp2(sc);
                    pa8[kt >> 1][(kt & 1) * 4 + rg] = (_Float16)p;
                }
            }
            // row-sum denominators on the matrix pipe (rows match oacc's rows)
            oacc5 = __builtin_amdgcn_mfma_f32_16x16x32_f16(pa8[0], kone, oacc5, 0, 0, 0);
            oacc5 = __builtin_amdgcn_mfma_f32_16x16x32_f16(pa8[1], kone, oacc5, 0, 0, 0);

            // ---- PV: quad-interleaved V^T, b128 conflict-free ---------------
#pragma unroll
            for (int dt = 0; dt < 4; ++dt) {
                int vrow = dt * 16 + lr;
#pragma unroll
                for (int ktp = 0; ktp < 2; ++ktp) {
                    f16x8 vb = *(const f16x8*)(Vc + swz(vrow, vrow * 128 + ktp * 64 + lg * 16));
                    oacc[dt] = __builtin_amdgcn_mfma_f32_16x16x32_f16(pa8[ktp], vb, oacc[dt], 0, 0, 0);
                }
            }
            __builtin_amdgcn_s_setprio(0);
        }

        // ---- phase boundary: snapshot selected result, reset ----------------
        if (t == 15) {
#pragma unroll
            for (int rg = 0; rg < 4; ++rg) {
                float inv = 1.f / oacc5[rg];
#pragma unroll
                for (int dt = 0; dt < 4; ++dt) osel[dt][rg] = oacc[dt][rg] * inv;
            }
#pragma unroll
            for (int dt = 0; dt < 4; ++dt) oacc[dt] = (f32x4){0.f, 0.f, 0.f, 0.f};
            oacc5 = (f32x4){0.f, 0.f, 0.f, 0.f};
        }

        // ---- write prefetched tile into the other buffer --------------------
        if (hasNext) {
            char* Kn = smem + (cur ? 0 : 8192);
            char* Vn = smem + 16384 + (cur ? 0 : 8192);
            *(f16x8*)(Kn + swz(srow0, srow0 * 128 + sc8 * 16)) = pk0;
            *(f16x8*)(Kn + swz(srow1, srow1 * 128 + sc8 * 16)) = pk1;
            STAGE_V(Vn, pv0, srow0, sc8);
            STAGE_V(Vn, pv1, srow1, sc8);
        }
        __syncthreads();
        cur ^= 1;
        kb_cur = kb_nxt;
    }

    // ---- epilogue: combine phases, gate, single coalesced RMW ---------------
    float* Os = (float*)smem;
#pragma unroll
    for (int rg = 0; rg < 4; ++rg) {
        float inv = 1.f / oacc5[rg];
        int row = w * 16 + 4 * lg + rg;
        int sq = q0 + row;
        float g1 = g[((size_t)(b * Ss + sq)) * 3 + 1];
        float g2 = g[((size_t)(b * Ss + sq)) * 3 + 2];
#pragma unroll
        for (int dt = 0; dt < 4; ++dt)
            Os[row * 68 + dt * 16 + lr] = g1 * osel[dt][rg] + g2 * oacc[dt][rg] * inv;
    }
    __syncthreads();
    {
        int row = tid >> 2;
        int c0 = (tid & 3) * 16;
        int s = q0 + row;
        float* op = o + ((size_t)(b * Ss + s)) * DMm + h * HDd + c0;
#pragma unroll
        for (int j = 0; j < 4; ++j) {
            float4 val = *(const float4*)&Os[row * 68 + c0 + j * 4];
            float4 cur4 = *(const float4*)&op[j * 4];
            cur4.x += val.x; cur4.y += val.y;
            cur4.z += val.z; cur4.w += val.w;
            *(float4*)&op[j * 4] = cur4;
        }
    }
}

// -------------------- constant emitter (host-side contract checks) ------------
__global__ __launch_bounds__(256) void k_const(float* __restrict__ y, float val)
{
    int i = blockIdx.x * 256 + threadIdx.x;
    y[i] = val;
}

// -------------------- launch --------------------------------------------------
extern "C" void kernel_launch(void* const* d_in, const int* in_sizes, int n_in,
                              void* d_out, int out_size, void* d_ws, size_t ws_size,
                              hipStream_t stream) {
    float* y = (float*)d_out;
    if (n_in != 6) {
        k_const<<<dim3(16384), 256, 0, stream>>>(y, 88888.f);
        return;
    }
    if (in_sizes[0] != 4194304 || in_sizes[1] != 262144 || in_sizes[2] != 262144 ||
        in_sizes[3] != 262144 || in_sizes[4] != 262144 || in_sizes[5] != 1536) {
        k_const<<<dim3(16384), 256, 0, stream>>>(y, 77777.f);
        return;
    }
    if (ws_size < WS_FLOATS * sizeof(float)) {
        k_const<<<dim3(16384), 256, 0, stream>>>(y, 66666.f);
        return;
    }

    const float* x  = (const float*)d_in[0];
    const float* Wq = (const float*)d_in[1];
    const float* Wk = (const float*)d_in[2];
    const float* Wv = (const float*)d_in[3];
    const float* Wo = (const float*)d_in[4];
    const float* Wg = (const float*)d_in[5];
    float* ws = (float*)d_ws;

    float* ow   = ws + OFF_O;
    float* gw   = ws + OFF_G;
    float* impw = ws + OFF_IMPB;
    int*   selw = (int*)(ws + OFF_SEL);
    f16*   qhw  = (f16*)(ws + OFF_QH);
    f16*   qlw  = (f16*)(ws + OFF_QL);
    f16*   khw  = (f16*)(ws + OFF_KH);
    f16*   klw  = (f16*)(ws + OFF_KL);
    f16*   vtw  = (f16*)(ws + OFF_VT);
    f16*   kchw = (f16*)(ws + OFF_KCH);
    f16*   kclw = (f16*)(ws + OFF_KCL);
    f16*   vctw = (f16*)(ws + OFF_VCT);
    f16*   xhw  = (f16*)(ws + OFF_XH);   // aliases o region (freed before k_cmp)
    f16*   xlw  = (f16*)(ws + OFF_XL);
    f16*   wqh  = (f16*)(ws + OFF_WT);
    f16*   wql  = (f16*)(ws + OFF_WT + 131072);
    f16*   wkh  = (f16*)(ws + OFF_WT + 262144);
    f16*   wkl  = (f16*)(ws + OFF_WT + 393216);
    f16*   wvh  = (f16*)(ws + OFF_WT + 524288);
    f16*   wvl  = (f16*)(ws + OFF_WT + 655360);
    f16*   woh  = (f16*)(ws + OFF_WT + 786432);

    k_prep_xg<<<dim3(2048), 256, 0, stream>>>(x, Wg, xhw, xlw, gw);
    k_prep_w<<<dim3(8, 8, 4), 256, 0, stream>>>(Wq, Wk, Wv, Wo,
            wqh, wql, wkh, wkl, wvh, wvl, woh);
    // q/k/v projections in ONE dispatch (z=0 q-split, z=1 k-split, z=2 v-tv)
    k_gemm3<<<dim3(64, 8, 3), 256, 0, stream>>>(xhw, xlw,
            wqh, wql, wkh, wkl, wvh, qhw, qlw, khw, klw, vtw);
    k_pool<<<dim3(512), 256, 0, stream>>>(khw, klw, vtw, kchw, kclw, vctw);
    k_cmp<<<dim3(64, 16), 256, 0, stream>>>(qhw, qlw, kchw, kclw, vctw, gw, impw, ow);
    k_topk<<<dim3(16), 64, 0, stream>>>(impw, selw);
    k_attn2<<<dim3(64, 16), 256, 0, stream>>>(qhw, khw, vtw, selw, gw, ow);
    k_outproj<<<dim3(64, 8), 256, 0, stream>>>(ow, woh, y);
}